// Round 5
// baseline (1083.051 us; speedup 1.0000x reference)
//
#include <hip/hip_runtime.h>

#define H_ 4
#define O_ 32
#define HO 128
#define M_ 128
#define M2 256
#define D_ 16
#define B_ 1024
#define JIT 1e-4f

typedef unsigned short ushort_t;
typedef __bf16 v8bf __attribute__((ext_vector_type(8)));
typedef float v16f __attribute__((ext_vector_type(16)));
typedef unsigned short v8us __attribute__((ext_vector_type(8)));
typedef unsigned short v4us __attribute__((ext_vector_type(4)));

__device__ inline void splitbf(float v, ushort_t& hb, ushort_t& lb) {
    unsigned int u = __float_as_uint(v);
    hb = (ushort_t)(u >> 16);
    float hf = __uint_as_float((unsigned int)hb << 16);
    float r = v - hf;
    lb = (ushort_t)(__float_as_uint(r) >> 16);
}

// ---------------------------------------------------------------------------
__global__ void k_prep(const float* __restrict__ theta, float* __restrict__ LSI,
                       float* __restrict__ SF2) {
    int t = threadIdx.x;
    if (t < H_ * D_) {
        int h = t / D_, d = t % D_;
        LSI[h * D_ + d] = __expf(-theta[h * (D_ + 1) + 1 + d]);
    }
    if (t < H_) SF2[t] = __expf(theta[t * (D_ + 1)]);
}

__global__ void k_scale_x(const float* __restrict__ x, const float* __restrict__ LSI,
                          float* __restrict__ XS, float* __restrict__ XN) {
    int idx = blockIdx.x * 256 + threadIdx.x;
    if (idx >= H_ * B_) return;
    int h = idx / B_, b = idx % B_;
    float s = 0.f;
#pragma unroll
    for (int d = 0; d < D_; d++) {
        float v = x[b * D_ + d] * LSI[h * D_ + d];
        XS[(long)idx * D_ + d] = v;
        s += v * v;
    }
    XN[idx] = s;
}

__global__ void k_scale_z(const float* __restrict__ z, const float* __restrict__ z_old,
                          const float* __restrict__ LSI, float* __restrict__ ZS,
                          float* __restrict__ ZN) {
    int idx = blockIdx.x * 256 + threadIdx.x;
    int i = idx & 255;
    int pair = idx >> 8;
    int h = pair >> 5, o = pair & 31;
    const float* src = (i < M_) ? (z_old + ((long)o * M_ + i) * D_)
                                : (z + ((long)o * M_ + (i - M_)) * D_);
    float s = 0.f;
#pragma unroll
    for (int d = 0; d < D_; d++) {
        float v = src[d] * LSI[h * D_ + d];
        ZS[(long)idx * D_ + d] = v;
        s += v * v;
    }
    ZN[idx] = s;
}

__global__ void k_unpack(const float* __restrict__ vec, float* __restrict__ UT) {
    long idx = (long)blockIdx.x * 256 + threadIdx.x;
    int o = (int)(idx >> 14);
    int e = (int)(idx & 16383);
    int i = e >> 7, j = e & 127;
    float v = (j <= i) ? vec[(long)o * (M_ * (M_ + 1) / 2) + i * (i + 1) / 2 + j] : 0.f;
    UT[idx] = v;
}

__global__ __launch_bounds__(256) void k_kuu2(const float* __restrict__ ZS,
                                              const float* __restrict__ ZN,
                                              const float* __restrict__ SF2,
                                              float* __restrict__ K2) {
    int pair = blockIdx.x;
    int h = pair >> 5;
    int t = threadIdx.x;
    __shared__ float zs[M2][D_];
    __shared__ float zn[M2];
    for (int e = t; e < M2 * D_; e += 256) zs[e / D_][e % D_] = ZS[(long)pair * M2 * D_ + e];
    zn[t] = ZN[pair * M2 + t];
    __syncthreads();
    float sf2 = SF2[h];
    float my[D_];
#pragma unroll
    for (int d = 0; d < D_; d++) my[d] = zs[t][d];
    float myn = zn[t];
    for (int q = 0; q < M2; q++) {
        float dot = 0.f;
#pragma unroll
        for (int d = 0; d < D_; d++) dot += zs[q][d] * my[d];
        float d2 = fmaxf(zn[q] + myn - 2.f * dot, 0.f);
        float v = sf2 * __expf(-0.5f * d2);
        if (q == t) v += JIT;
        K2[(long)pair * M2 * M2 + (long)q * M2 + t] = v;
    }
}

// blocked (BK=32) in-LDS Cholesky of a 128x128 block, 256 threads.
__global__ __launch_bounds__(256) void k_chol128(const float* __restrict__ src, long sps, int ldsrc,
                                                 float* __restrict__ dst, long spd, int lddst) {
    int pair = blockIdx.x, t = threadIdx.x;
    __shared__ float Ap[M_ * (M_ + 1) / 2];
    __shared__ float rsq[32];
    const float* S = src + (long)pair * sps;
    for (int e = t; e < M_ * (M_ + 1) / 2; e += 256) {
        int i = (int)((sqrtf(8.f * e + 1.f) - 1.f) * 0.5f);
        while ((i + 1) * (i + 2) / 2 <= e) i++;
        while (i * (i + 1) / 2 > e) i--;
        int j = e - i * (i + 1) / 2;
        Ap[e] = S[(long)i * ldsrc + j];
    }
    int pi[3], pj[3];
#pragma unroll
    for (int u = 0; u < 3; u++) {
        int p = t + u * 256;
        if (p < 528) {
            int i = (int)((sqrtf(8.f * p + 1.f) - 1.f) * 0.5f);
            while ((i + 1) * (i + 2) / 2 <= p) i++;
            while (i * (i + 1) / 2 > p) i--;
            pi[u] = i;
            pj[u] = p - i * (i + 1) / 2;
        } else {
            pi[u] = -1;
            pj[u] = 0;
        }
    }
    __syncthreads();

    for (int kb = 0; kb < 4; kb++) {
        int c0 = kb * 32;
        for (int k = 0; k < 32; k++) {
            int kc = c0 + k;
            float rd = 1.f / Ap[kc * (kc + 1) / 2 + kc];
#pragma unroll
            for (int u = 0; u < 3; u++) {
                int i = pi[u], j = pj[u];
                if (i > k && j > k) {
                    int gi = c0 + i, gj = c0 + j;
                    Ap[gi * (gi + 1) / 2 + gj] -=
                        Ap[gi * (gi + 1) / 2 + kc] * Ap[gj * (gj + 1) / 2 + kc] * rd;
                }
            }
            __syncthreads();
        }
        if (t < 32) {
            int g = c0 + t;
            rsq[t] = rsqrtf(Ap[g * (g + 1) / 2 + g]);
        }
        __syncthreads();
#pragma unroll
        for (int u = 0; u < 3; u++) {
            int i = pi[u], j = pj[u];
            if (i >= 0) {
                int gi = c0 + i, gj = c0 + j;
                Ap[gi * (gi + 1) / 2 + gj] *= rsq[j];
            }
        }
        __syncthreads();

        int R = M_ - c0 - 32;
        if (R > 0) {
            if (t < R) {
                int gi = c0 + 32 + t;
                int base = gi * (gi + 1) / 2 + c0;
                float xr[32];
#pragma unroll
                for (int j = 0; j < 32; j++) xr[j] = Ap[base + j];
#pragma unroll
                for (int q = 0; q < 32; q++) {
                    float xq = xr[q] * rsq[q];
                    xr[q] = xq;
#pragma unroll
                    for (int j = q + 1; j < 32; j++)
                        xr[j] -= xq * Ap[(c0 + j) * (c0 + j + 1) / 2 + c0 + q];
                }
#pragma unroll
                for (int j = 0; j < 32; j++) Ap[base + j] = xr[j];
            }
            __syncthreads();
            int nb = R >> 2;
            int ntile = nb * (nb + 1) / 2;
            for (int tp = t; tp < ntile; tp += 256) {
                int bi = (int)((sqrtf(8.f * tp + 1.f) - 1.f) * 0.5f);
                while ((bi + 1) * (bi + 2) / 2 <= tp) bi++;
                while (bi * (bi + 1) / 2 > tp) bi--;
                int bj = tp - bi * (bi + 1) / 2;
                int i0 = c0 + 32 + bi * 4, j0 = c0 + 32 + bj * 4;
                float acc[4][4] = {};
                for (int k = 0; k < 32; k++) {
                    float a[4], b[4];
#pragma unroll
                    for (int q = 0; q < 4; q++) a[q] = Ap[(i0 + q) * (i0 + q + 1) / 2 + c0 + k];
#pragma unroll
                    for (int r = 0; r < 4; r++) b[r] = Ap[(j0 + r) * (j0 + r + 1) / 2 + c0 + k];
#pragma unroll
                    for (int q = 0; q < 4; q++)
#pragma unroll
                        for (int r = 0; r < 4; r++) acc[q][r] += a[q] * b[r];
                }
#pragma unroll
                for (int q = 0; q < 4; q++)
#pragma unroll
                    for (int r = 0; r < 4; r++) {
                        int gi = i0 + q, gj = j0 + r;
                        if (gj <= gi) Ap[gi * (gi + 1) / 2 + gj] -= acc[q][r];
                    }
            }
            __syncthreads();
        }
    }

    float* Dst = dst + (long)pair * spd;
    for (int e = t; e < M_ * M_; e += 256) {
        int i = e >> 7, j = e & 127;
        Dst[(long)i * lddst + j] = (j <= i) ? Ap[i * (i + 1) / 2 + j] : 0.f;
    }
}

// transpose A1 [pair][128][128] into BL quadrant of L256 [pair][256][256]
__global__ __launch_bounds__(256) void k_copyT(const float* __restrict__ A1, float* __restrict__ L) {
    int pair = blockIdx.x, t = threadIdx.x;
    int tx = t & 31, ty = t >> 5;
    __shared__ float tl[32][33];
    for (int bi = 0; bi < 4; bi++)
        for (int bj = 0; bj < 4; bj++) {
            for (int r = ty; r < 32; r += 8)
                tl[r][tx] = A1[(long)pair * 16384 + (long)(bj * 32 + r) * 128 + bi * 32 + tx];
            __syncthreads();
            for (int r = ty; r < 32; r += 8)
                L[(long)pair * 65536 + (long)(128 + bi * 32 + r) * 256 + bj * 32 + tx] = tl[tx][r];
            __syncthreads();
        }
}

// transpose+split LINV fp32 [pair][256][256] -> LINVT hi/lo bf16 planes
__global__ __launch_bounds__(256) void k_tsplit(const float* __restrict__ Lv,
                                                ushort_t* __restrict__ Th,
                                                ushort_t* __restrict__ Tl) {
    int pair = blockIdx.x, t = threadIdx.x;
    int tx = t & 31, ty = t >> 5;  // 8 rows of 32
    __shared__ float tile[32][33];
    long base = (long)pair * 65536;
    for (int bi = 0; bi < 8; bi++)
        for (int bj = 0; bj < 8; bj++) {
            for (int r = ty; r < 32; r += 8)
                tile[r][tx] = Lv[base + (long)(bi * 32 + r) * 256 + bj * 32 + tx];
            __syncthreads();
            for (int r = ty; r < 32; r += 8) {
                ushort_t hb, lb;
                splitbf(tile[tx][r], hb, lb);
                long oidx = base + (long)(bj * 32 + r) * 256 + bi * 32 + tx;
                Th[oidx] = hb;
                Tl[oidx] = lb;
            }
            __syncthreads();
        }
}

__global__ __launch_bounds__(64) void k_diaginv(const float* __restrict__ L, long sPair, int ld,
                                                float* __restrict__ Out, long sPairO, int ldo) {
    int pair = blockIdx.x, I0 = blockIdx.y * 64;
    int c = threadIdx.x;
    __shared__ float Ld[64][66];
    __shared__ float Wd[64][66];
    const float* Lp = L + (long)pair * sPair + (long)I0 * ld + I0;
    for (int e = c; e < 4096; e += 64) {
        int i = e >> 6, j = e & 63;
        Ld[i][j] = Lp[(long)i * ld + j];
    }
    __syncthreads();
    for (int i = 0; i < 64; i++) {
        float acc = (i == c) ? 1.f : 0.f;
        for (int j = 0; j < i; j++) acc -= Ld[i][j] * Wd[j][c];
        Wd[i][c] = acc / Ld[i][i];
    }
    float* Op = Out + (long)pair * sPairO + (long)I0 * ldo + I0;
    for (int i = 0; i < 64; i++) Op[(long)i * ldo + c] = Wd[i][c];
}

__global__ __launch_bounds__(256) void k_linvoff(const float* __restrict__ L, long sPair, int ld,
                                                 float* __restrict__ Linv, long sPairO, int ldo,
                                                 int d) {
    int pair = blockIdx.x, J = blockIdx.y, I = J + d;
    int I0 = I * 64, J0 = J * 64;
    int t = threadIdx.x, tx = t & 15, ty = t >> 4;
    __shared__ float La[64][66], Lb[64][66], Ss[64][66];
    float acc[4][4] = {};
    for (int K = J; K < I; K++) {
        int K0 = K * 64;
        for (int e = t; e < 4096; e += 256) {
            int i = e >> 6, k = e & 63;
            La[i][k] = L[(long)pair * sPair + (long)(I0 + i) * ld + K0 + k];
            Lb[i][k] = Linv[(long)pair * sPairO + (long)(K0 + i) * ldo + J0 + k];
        }
        __syncthreads();
#pragma unroll 4
        for (int kk = 0; kk < 64; kk++) {
            float a[4], b[4];
#pragma unroll
            for (int q = 0; q < 4; q++) { a[q] = La[ty + 16 * q][kk]; b[q] = Lb[kk][tx + 16 * q]; }
#pragma unroll
            for (int q = 0; q < 4; q++)
#pragma unroll
                for (int r = 0; r < 4; r++) acc[q][r] += a[q] * b[r];
        }
        __syncthreads();
    }
#pragma unroll
    for (int q = 0; q < 4; q++)
#pragma unroll
        for (int r = 0; r < 4; r++) Ss[ty + 16 * q][tx + 16 * r] = acc[q][r];
    for (int e = t; e < 4096; e += 256) {
        int i = e >> 6, k = e & 63;
        La[i][k] = Linv[(long)pair * sPairO + (long)(I0 + i) * ldo + I0 + k];
    }
    __syncthreads();
    float out[4][4] = {};
#pragma unroll 4
    for (int kk = 0; kk < 64; kk++) {
        float a[4], b[4];
#pragma unroll
        for (int q = 0; q < 4; q++) { a[q] = La[ty + 16 * q][kk]; b[q] = Ss[kk][tx + 16 * q]; }
#pragma unroll
        for (int q = 0; q < 4; q++)
#pragma unroll
            for (int r = 0; r < 4; r++) out[q][r] += a[q] * b[r];
    }
#pragma unroll
    for (int q = 0; q < 4; q++)
#pragma unroll
        for (int r = 0; r < 4; r++)
            Linv[(long)pair * sPairO + (long)(I0 + ty + 16 * q) * ldo + J0 + tx + 16 * r] = -out[q][r];
}

__global__ __launch_bounds__(128) void k_stage1vec(const float* __restrict__ Linv128,
                                                   const float* __restrict__ A1,
                                                   const float* __restrict__ m_old,
                                                   const float* __restrict__ u_mean,
                                                   float* __restrict__ MJ) {
    int pair = blockIdx.x, o = pair & 31, t = threadIdx.x;
    __shared__ float mo[128], a2[128];
    mo[t] = m_old[o * 128 + t];
    __syncthreads();
    const float* Lr = Linv128 + (long)pair * 16384 + (long)t * 128;
    float acc = 0.f;
    for (int j = 0; j <= t; j++) acc += Lr[j] * mo[j];
    a2[t] = acc;
    __syncthreads();
    float m = 0.f;
    for (int i = 0; i < 128; i++) m += A1[(long)pair * 16384 + (long)i * 128 + t] * a2[i];
    MJ[pair * 256 + t] = mo[t];
    MJ[pair * 256 + 128 + t] = m + u_mean[o * 128 + t];
}

__global__ __launch_bounds__(256) void k_assemble(const float* __restrict__ SOLD,
                                                  const float* __restrict__ SCUR,
                                                  const float* __restrict__ TRb,
                                                  const float* __restrict__ BRb,
                                                  float* __restrict__ COV) {
    int pair = blockIdx.x, quad = blockIdx.y, o = pair & 31, t = threadIdx.x;
    long base = (long)pair * M2 * M2;
    for (int e = t; e < 16384; e += 256) {
        int i = e >> 7, j = e & 127;
        if (quad == 0) {
            COV[base + (long)i * 256 + j] = SOLD[(long)o * 16384 + e] + ((i == j) ? JIT : 0.f);
        } else if (quad == 1) {
            COV[base + (long)i * 256 + 128 + j] = TRb[(long)pair * 16384 + e];
        } else if (quad == 2) {
            COV[base + (long)(128 + i) * 256 + j] = TRb[(long)pair * 16384 + (long)j * 128 + i];
        } else {
            COV[base + (long)(128 + i) * 256 + 128 + j] =
                SCUR[(long)o * 16384 + e] + BRb[(long)pair * 16384 + e] + ((i == j) ? JIT : 0.f);
        }
    }
}

__global__ __launch_bounds__(256) void k_cvec(const float* __restrict__ Linv,
                                              const float* __restrict__ MJ,
                                              float* __restrict__ CV) {
    int pair = blockIdx.x, t = threadIdx.x;
    __shared__ float mj[256], tmp[256];
    mj[t] = MJ[pair * 256 + t];
    __syncthreads();
    const float* Lp = Linv + (long)pair * 65536;
    float acc = 0.f;
    for (int j = 0; j <= t; j++) acc += Lp[(long)t * 256 + j] * mj[j];
    tmp[t] = acc;
    __syncthreads();
    float c = 0.f;
    for (int k = t; k < 256; k++) c += Lp[(long)k * 256 + t] * tmp[k];
    CV[pair * 256 + t] = c;
}

// generic batched fp32 SGEMM (kept for the 128-chain)
template <int TA, int TB>
__global__ __launch_bounds__(256) void k_bmm(const float* __restrict__ A, long aSH, long aSO, int lda,
                                             const float* __restrict__ B, long bSH, long bSO, int ldb,
                                             float* __restrict__ C, long cSH, long cSO, int ldc,
                                             const float* __restrict__ Dm,
                                             int Ksz, int kLoMode, int kHiMode, float alpha,
                                             int accum, int tiles3) {
    int pair = blockIdx.x;
    int h = pair >> 5, o = pair & 31;
    const float* Ap = A + (long)h * aSH + (long)o * aSO;
    const float* Bp = B + (long)h * bSH + (long)o * bSO;
    float* Cp = C + (long)h * cSH + (long)o * cSO;
    const float* Dp = Dm ? (Dm + (long)h * cSH + (long)o * cSO) : nullptr;
    int I0, J0, mir = 0;
    if (tiles3) {
        int qb = blockIdx.y;
        I0 = (qb == 0) ? 0 : 128;
        J0 = (qb == 2) ? 0 : I0;
        mir = (qb == 2);
    } else {
        I0 = blockIdx.y * 128;
        J0 = blockIdx.z * 128;
    }
    int k0 = (kLoMode == 0) ? 0 : (kLoMode == 1) ? I0 : (kLoMode == 2) ? J0 : max(I0, J0);
    int k1 = (kHiMode == 0) ? Ksz : (kHiMode == 1) ? min(Ksz, I0 + 128) : min(Ksz, min(I0, J0) + 128);
    int t = threadIdx.x, tx = t & 15, ty = t >> 4;
    __shared__ float As[16][132], Bs[16][132];
    float acc[8][8] = {};
    for (int kt = k0; kt < k1; kt += 16) {
#pragma unroll
        for (int q = 0; q < 8; q++) {
            int e = q * 256 + t;
            if (TA) {
                int kk = e >> 7, m = e & 127;
                As[kk][m] = Ap[(long)(kt + kk) * lda + I0 + m];
            } else {
                int m = e >> 4, kk = e & 15;
                As[kk][m] = Ap[(long)(I0 + m) * lda + kt + kk];
            }
            if (TB) {
                int n = e >> 4, kk = e & 15;
                Bs[kk][n] = Bp[(long)(J0 + n) * ldb + kt + kk];
            } else {
                int kk = e >> 7, n = e & 127;
                Bs[kk][n] = Bp[(long)(kt + kk) * ldb + J0 + n];
            }
        }
        __syncthreads();
#pragma unroll
        for (int kk = 0; kk < 16; kk++) {
            float a[8], b[8];
#pragma unroll
            for (int q = 0; q < 8; q++) { a[q] = As[kk][ty + 16 * q]; b[q] = Bs[kk][tx + 16 * q]; }
#pragma unroll
            for (int q = 0; q < 8; q++)
#pragma unroll
                for (int r = 0; r < 8; r++) acc[q][r] += a[q] * b[r];
        }
        __syncthreads();
    }
#pragma unroll
    for (int q = 0; q < 8; q++)
#pragma unroll
        for (int r = 0; r < 8; r++) {
            int row = I0 + ty + 16 * q, col = J0 + tx + 16 * r;
            long idx = (long)row * ldc + col;
            float v = alpha * acc[q][r];
            if (accum == 1) v += Cp[idx];
            if (accum == 2) v += Dp[idx];
            Cp[idx] = v;
            if (mir) Cp[(long)col * ldc + row] = v;
        }
}

// split fp32 -> bf16 hi + lo planes (generic)
__global__ __launch_bounds__(256) void k_gsplit(const float* __restrict__ G,
                                                ushort_t* __restrict__ hi,
                                                ushort_t* __restrict__ lo) {
    long idx = ((long)blockIdx.x * 256 + threadIdx.x) * 4;
    float4 g = *(const float4*)(G + idx);
    v4us h, l;
    float gv[4] = {g.x, g.y, g.z, g.w};
#pragma unroll
    for (int e = 0; e < 4; e++) splitbf(gv[e], ((ushort_t*)&h)[e], ((ushort_t*)&l)[e]);
    *(v4us*)(hi + idx) = h;
    *(v4us*)(lo + idx) = l;
}

// split-bf16 MFMA batched GEMM: C = alpha*(Ah+Al)@(Bh+Bl)^T' [+ Dm]
// A planes: [m][k] row-major ld=256. B planes: [n][k] row-major ld=256
// (i.e. B operand of the math GEMM must satisfy B[k][n] == Bplane[n][k]).
// Per-pair stride 65536 elems everywhere. 128x128 tile per block, 4 waves 2x2.
// TILES3: blockIdx.y in {0,1,2} -> (0,0),(128,128),(128,0)+mirror; else 2x2 grid.
#define BSTR 56  // LDS row stride (elems): 112B, 16B-aligned, conflict-benign
template <int TILES3>
__global__ __launch_bounds__(256) void k_bmmx(const ushort_t* __restrict__ Ah,
                                              const ushort_t* __restrict__ Al,
                                              const ushort_t* __restrict__ Bh,
                                              const ushort_t* __restrict__ Bl,
                                              float* __restrict__ Cf,
                                              ushort_t* __restrict__ Chi,
                                              ushort_t* __restrict__ Clo,
                                              const float* __restrict__ Dm,
                                              int kLoMax, float alpha) {
    int pair = blockIdx.x;
    long base = (long)pair * 65536;
    int I0, J0, mir = 0;
    if (TILES3) {
        int qb = blockIdx.y;
        I0 = (qb == 0) ? 0 : 128;
        J0 = (qb == 2) ? 0 : I0;
        mir = (qb == 2);
    } else {
        I0 = (blockIdx.y >> 1) * 128;
        J0 = (blockIdx.y & 1) * 128;
    }
    int k0 = kLoMax ? max(I0, J0) : 0;
    int t = threadIdx.x;
    int w = t >> 6, lane = t & 63;
    int l31 = lane & 31, lhalf = lane >> 5;
    int wy = w >> 1, wx = w & 1;

    __shared__ __align__(16) ushort_t AsH[128][BSTR], AsL[128][BSTR];
    __shared__ __align__(16) ushort_t BsH[128][BSTR], BsL[128][BSTR];

    v16f acc[2][2];
#pragma unroll
    for (int mt = 0; mt < 2; mt++)
#pragma unroll
        for (int nt = 0; nt < 2; nt++)
#pragma unroll
            for (int r = 0; r < 16; r++) acc[mt][nt][r] = 0.f;

    for (int kt = k0; kt < 256; kt += 32) {
        __syncthreads();
#pragma unroll
        for (int u = 0; u < 2; u++) {
            int idx = u * 256 + t;
            int m = idx >> 2, kc = (idx & 3) * 8;
            long arow = base + (long)(I0 + m) * 256 + kt + kc;
            long brow = base + (long)(J0 + m) * 256 + kt + kc;
            *(v8us*)&AsH[m][kc] = *(const v8us*)(Ah + arow);
            *(v8us*)&AsL[m][kc] = *(const v8us*)(Al + arow);
            *(v8us*)&BsH[m][kc] = *(const v8us*)(Bh + brow);
            *(v8us*)&BsL[m][kc] = *(const v8us*)(Bl + brow);
        }
        __syncthreads();
#pragma unroll
        for (int ks = 0; ks < 2; ks++) {
            int ko = ks * 16 + lhalf * 8;
            v8bf ah[2], al[2], bh[2], bl[2];
#pragma unroll
            for (int mt = 0; mt < 2; mt++) {
                int r = wy * 64 + mt * 32 + l31;
                ah[mt] = *(const v8bf*)&AsH[r][ko];
                al[mt] = *(const v8bf*)&AsL[r][ko];
            }
#pragma unroll
            for (int nt = 0; nt < 2; nt++) {
                int r = wx * 64 + nt * 32 + l31;
                bh[nt] = *(const v8bf*)&BsH[r][ko];
                bl[nt] = *(const v8bf*)&BsL[r][ko];
            }
#pragma unroll
            for (int mt = 0; mt < 2; mt++)
#pragma unroll
                for (int nt = 0; nt < 2; nt++) {
                    acc[mt][nt] = __builtin_amdgcn_mfma_f32_32x32x16_bf16(ah[mt], bh[nt], acc[mt][nt], 0, 0, 0);
                    acc[mt][nt] = __builtin_amdgcn_mfma_f32_32x32x16_bf16(ah[mt], bl[nt], acc[mt][nt], 0, 0, 0);
                    acc[mt][nt] = __builtin_amdgcn_mfma_f32_32x32x16_bf16(al[mt], bh[nt], acc[mt][nt], 0, 0, 0);
                }
        }
    }

#pragma unroll
    for (int mt = 0; mt < 2; mt++)
#pragma unroll
        for (int nt = 0; nt < 2; nt++) {
#pragma unroll
            for (int r = 0; r < 16; r++) {
                int row = I0 + wy * 64 + mt * 32 + 8 * (r >> 2) + 4 * lhalf + (r & 3);
                int col = J0 + wx * 64 + nt * 32 + l31;
                long idx = base + (long)row * 256 + col;
                float v = alpha * acc[mt][nt][r];
                if (Dm) v += Dm[idx];
                ushort_t hb, lb;
                splitbf(v, hb, lb);
                if (Cf) Cf[idx] = v;
                if (Chi) { Chi[idx] = hb; Clo[idx] = lb; }
                if (mir) {
                    long idxT = base + (long)col * 256 + row;
                    if (Cf) Cf[idxT] = v;
                    if (Chi) { Chi[idxT] = hb; Clo[idxT] = lb; }
                }
            }
        }
}

// fused final kernel (MFMA) — unchanged from R3
#define KTP 280
__global__ __launch_bounds__(256) void k_kb3(const float* __restrict__ ZS, const float* __restrict__ ZN,
                                             const float* __restrict__ XS, const float* __restrict__ XN,
                                             const float* __restrict__ SF2,
                                             const ushort_t* __restrict__ Ghi,
                                             const ushort_t* __restrict__ Glo,
                                             const float* __restrict__ CV, float* __restrict__ out) {
    int bt = blockIdx.x;
    int pair = blockIdx.y;
    int h = pair >> 5;
    int t = threadIdx.x;
    int w = t >> 6;
    int lane = t & 63;
    int l31 = lane & 31, lhalf = lane >> 5;

    __shared__ __align__(16) ushort_t KbT[64][KTP];
    __shared__ float qpart[4][64];
    __shared__ float mup[4][64];

    float sf2 = SF2[h];
    {
        int b = t & 63;
        long bg = (long)h * B_ + bt * 64 + b;
        const float4* xrow = (const float4*)(XS + bg * 16);
        float4 x0 = xrow[0], x1 = xrow[1], x2 = xrow[2], x3 = xrow[3];
        float xn = XN[bg];
        float mupart = 0.f;
        const float* cvp = CV + pair * 256;
        const float* znp = ZN + pair * 256;
#pragma unroll 2
        for (int j8 = 0; j8 < 8; j8++) {
            v8us kb8;
#pragma unroll
            for (int e = 0; e < 8; e++) {
                int j = w * 64 + j8 * 8 + e;
                const float4* zrow = (const float4*)(ZS + ((long)pair * 256 + j) * 16);
                float4 z0 = zrow[0], z1 = zrow[1], z2 = zrow[2], z3 = zrow[3];
                float dot = z0.x * x0.x + z0.y * x0.y + z0.z * x0.z + z0.w * x0.w +
                            z1.x * x1.x + z1.y * x1.y + z1.z * x1.z + z1.w * x1.w +
                            z2.x * x2.x + z2.y * x2.y + z2.z * x2.z + z2.w * x2.w +
                            z3.x * x3.x + z3.y * x3.y + z3.z * x3.z + z3.w * x3.w;
                float d2 = fmaxf(znp[j] + xn - 2.f * dot, 0.f);
                float kv = sf2 * __expf(-0.5f * d2);
                mupart += cvp[j] * kv;
                unsigned int u = __float_as_uint(kv);
                u += 0x7fffu + ((u >> 16) & 1u);
                kb8[e] = (unsigned short)(u >> 16);
            }
            *(v8us*)&KbT[b][w * 64 + j8 * 8] = kb8;
        }
        mup[w][b] = mupart;
    }
    __syncthreads();

    v16f acc[2][2];
#pragma unroll
    for (int mt = 0; mt < 2; mt++)
#pragma unroll
        for (int nt = 0; nt < 2; nt++)
#pragma unroll
            for (int r = 0; r < 16; r++) acc[mt][nt][r] = 0.f;

    const ushort_t* GhiP = Ghi + (long)pair * 65536;
    const ushort_t* GloP = Glo + (long)pair * 65536;
    for (int k0 = 0; k0 < 256; k0 += 16) {
        v8bf bfr[2];
#pragma unroll
        for (int nt = 0; nt < 2; nt++)
            bfr[nt] = *(const v8bf*)&KbT[nt * 32 + l31][k0 + lhalf * 8];
#pragma unroll
        for (int mt = 0; mt < 2; mt++) {
            int i = w * 64 + mt * 32 + l31;
            v8bf ah = *(const v8bf*)(GhiP + (long)i * 256 + k0 + lhalf * 8);
            v8bf al = *(const v8bf*)(GloP + (long)i * 256 + k0 + lhalf * 8);
#pragma unroll
            for (int nt = 0; nt < 2; nt++) {
                acc[mt][nt] = __builtin_amdgcn_mfma_f32_32x32x16_bf16(ah, bfr[nt], acc[mt][nt], 0, 0, 0);
                acc[mt][nt] = __builtin_amdgcn_mfma_f32_32x32x16_bf16(al, bfr[nt], acc[mt][nt], 0, 0, 0);
            }
        }
    }

    float qp[2] = {0.f, 0.f};
#pragma unroll
    for (int mt = 0; mt < 2; mt++) {
#pragma unroll
        for (int nt = 0; nt < 2; nt++) {
            int b = nt * 32 + l31;
#pragma unroll
            for (int g = 0; g < 4; g++) {
                int ibase = w * 64 + mt * 32 + 8 * g + 4 * lhalf;
                v4us k4 = *(const v4us*)&KbT[b][ibase];
#pragma unroll
                for (int e = 0; e < 4; e++) {
                    float kv = __uint_as_float((unsigned int)k4[e] << 16);
                    qp[nt] += kv * acc[mt][nt][4 * g + e];
                }
            }
        }
    }
#pragma unroll
    for (int nt = 0; nt < 2; nt++) {
        qp[nt] += __shfl_down(qp[nt], 32, 64);
        if (lhalf == 0) qpart[w][nt * 32 + l31] = qp[nt];
    }
    __syncthreads();

    if (t < 64) {
        float mu = mup[0][t] + mup[1][t] + mup[2][t] + mup[3][t];
        float q = qpart[0][t] + qpart[1][t] + qpart[2][t] + qpart[3][t];
        long ob = (long)pair * 1024 + bt * 64 + t;
        out[ob] = mu;
        out[(long)H_ * O_ * B_ + ob] = sf2 - q;
    }
}

// ---------------------------------------------------------------------------
extern "C" void kernel_launch(void* const* d_in, const int* in_sizes, int n_in,
                              void* d_out, int out_size, void* d_ws, size_t ws_size,
                              hipStream_t stream) {
    const float* x = (const float*)d_in[0];
    const float* z = (const float*)d_in[1];
    const float* u_mean = (const float*)d_in[2];
    const float* u_tril_vec = (const float*)d_in[3];
    const float* m_old = (const float*)d_in[4];
    const float* L_old = (const float*)d_in[5];
    const float* z_old = (const float*)d_in[6];
    const float* theta = (const float*)d_in[7];

    const long BIGSZ = (long)HO * M2 * M2;  // 8388608
    const long MSZ = (long)HO * M_ * M_;
    const long OSZ = (long)O_ * M_ * M_;
    const long SH2 = (long)O_ * M2 * M2;
    const long SO2 = (long)M2 * M2;
    const long SH1 = (long)O_ * M_ * M_;
    const long SO1 = (long)M_ * M_;

    float* ws = (float*)d_ws;
    long off = 0;
    float* BIG0 = ws + off; off += BIGSZ;  // KUU2 -> AINV fp32
    float* BIG1 = ws + off; off += BIGSZ;  // UT -> COV fp32 -> PTh/l
    float* BIG2 = ws + off; off += BIGSZ;  // Linv128|A1|A3|ATX -> LINV fp32 -> AINVh/l
    float* BIG3 = ws + off; off += BIGSZ;  // L256 -> LINVTh/l -> COVh/l -> Gh/l
    float* SOLD = ws + off; off += OSZ;
    float* SCUR = ws + off; off += OSZ;
    float* ZS = ws + off; off += (long)HO * M2 * D_;
    float* XS = ws + off; off += (long)H_ * B_ * D_;
    float* ZN = ws + off; off += (long)HO * M2;
    float* XN = ws + off; off += (long)H_ * B_;
    float* MJ = ws + off; off += (long)HO * M2;
    float* CV = ws + off; off += (long)HO * M2;
    float* LSI = ws + off; off += H_ * D_;
    float* SF2v = ws + off; off += H_;

    float* UT = BIG1;
    float* KUU2 = BIG0;
    float* COV = BIG1;
    float* Linv128 = BIG2;
    float* A1 = BIG2 + MSZ;
    float* A3 = BIG2 + 2 * MSZ;
    float* ATX = BIG2 + 3 * MSZ;
    float* TRb = BIG2 + 2 * MSZ;
    float* BRb = BIG2;
    float* L256 = BIG3;
    float* LINV = BIG2;
    float* AINV = BIG0;
    ushort_t* LINVTh = (ushort_t*)BIG3;          // over L256 (dead)
    ushort_t* LINVTl = LINVTh + BIGSZ;
    ushort_t* AINVh = (ushort_t*)BIG2;           // over LINV fp32 (dead after tsplit/cvec)
    ushort_t* AINVl = AINVh + BIGSZ;
    ushort_t* COVh = (ushort_t*)BIG3;            // over LINVT (dead after AINV gemm)
    ushort_t* COVl = COVh + BIGSZ;
    ushort_t* PTh = (ushort_t*)BIG1;             // over COV fp32 (dead after split)
    ushort_t* PTl = PTh + BIGSZ;
    ushort_t* Ghi = (ushort_t*)BIG3;             // over COVh/l (dead after PT gemm)
    ushort_t* Glo = Ghi + BIGSZ;
    const long BRoff = 128L * M2 + 128;

    k_prep<<<1, 64, 0, stream>>>(theta, LSI, SF2v);
    k_scale_x<<<(H_ * B_ + 255) / 256, 256, 0, stream>>>(x, LSI, XS, XN);
    k_scale_z<<<HO * M2 / 256, 256, 0, stream>>>(z, z_old, LSI, ZS, ZN);
    k_unpack<<<(int)(OSZ / 256), 256, 0, stream>>>(u_tril_vec, UT);

    k_bmm<0, 1><<<dim3(O_, 1, 1), 256, 0, stream>>>(L_old, 0, SO1, M_, L_old, 0, SO1, M_,
                                                    SOLD, 0, SO1, M_, nullptr, M_, 0, 0, 1.f, 0, 0);
    k_bmm<0, 1><<<dim3(O_, 1, 1), 256, 0, stream>>>(UT, 0, SO1, M_, UT, 0, SO1, M_,
                                                    SCUR, 0, SO1, M_, nullptr, M_, 0, 0, 1.f, 0, 0);

    k_kuu2<<<HO, 256, 0, stream>>>(ZS, ZN, SF2v, KUU2);
    k_chol128<<<HO, 256, 0, stream>>>(KUU2, SO2, M2, L256, SO2, M2);

    hipMemsetAsync(Linv128, 0, MSZ * sizeof(float), stream);
    k_diaginv<<<dim3(HO, 2), 64, 0, stream>>>(L256, SO2, M2, Linv128, SO1, M_);
    k_linvoff<<<dim3(HO, 1), 256, 0, stream>>>(L256, SO2, M2, Linv128, SO1, M_, 1);

    k_bmm<0, 0><<<dim3(HO, 1, 1), 256, 0, stream>>>(Linv128, SH1, SO1, M_,
                                                    KUU2 + 128, SH2, SO2, M2,
                                                    A1, SH1, SO1, M_, nullptr, M_, 0, 0, 1.f, 0, 0);
    k_bmm<0, 0><<<dim3(HO, 1, 1), 256, 0, stream>>>(Linv128, SH1, SO1, M_, L_old, 0, SO1, M_,
                                                    A3, SH1, SO1, M_, nullptr, M_, 0, 0, 1.f, 0, 0);
    k_stage1vec<<<HO, 128, 0, stream>>>(Linv128, A1, m_old, u_mean, MJ);

    k_bmm<1, 0><<<dim3(HO, 1, 1), 256, 0, stream>>>(A3, SH1, SO1, M_, A1, SH1, SO1, M_,
                                                    ATX, SH1, SO1, M_, nullptr, M_, 0, 0, 1.f, 0, 0);
    k_bmm<0, 0><<<dim3(HO, 1, 1), 256, 0, stream>>>(L_old, 0, SO1, M_, ATX, SH1, SO1, M_,
                                                    TRb, SH1, SO1, M_, nullptr, M_, 0, 0, 1.f, 0, 0);
    k_bmm<1, 0><<<dim3(HO, 1, 1), 256, 0, stream>>>(ATX, SH1, SO1, M_, ATX, SH1, SO1, M_,
                                                    BRb, SH1, SO1, M_, nullptr, M_, 0, 0, 1.f, 0, 0);

    k_assemble<<<dim3(HO, 4), 256, 0, stream>>>(SOLD, SCUR, TRb, BRb, COV);

    k_copyT<<<HO, 256, 0, stream>>>(A1, L256);
    k_bmm<1, 0><<<dim3(HO, 1, 1), 256, 0, stream>>>(A1, SH1, SO1, M_, A1, SH1, SO1, M_,
                                                    KUU2 + BRoff, SH2, SO2, M2, nullptr,
                                                    M_, 0, 0, -1.f, 1, 0);
    k_chol128<<<HO, 256, 0, stream>>>(KUU2 + BRoff, SO2, M2, L256 + BRoff, SO2, M2);

    hipMemsetAsync(LINV, 0, BIGSZ * sizeof(float), stream);
    k_diaginv<<<dim3(HO, 4), 64, 0, stream>>>(L256, SO2, M2, LINV, SO2, M2);
    k_linvoff<<<dim3(HO, 3), 256, 0, stream>>>(L256, SO2, M2, LINV, SO2, M2, 1);
    k_linvoff<<<dim3(HO, 2), 256, 0, stream>>>(L256, SO2, M2, LINV, SO2, M2, 2);
    k_linvoff<<<dim3(HO, 1), 256, 0, stream>>>(L256, SO2, M2, LINV, SO2, M2, 3);

    k_cvec<<<HO, 256, 0, stream>>>(LINV, MJ, CV);

    // LINVT hi/lo (transpose+split; L256 dead -> BIG3)
    k_tsplit<<<HO, 256, 0, stream>>>(LINV, LINVTh, LINVTl);

    // AINV = LINVT (.) LINVT : fp32 out + split planes (LINV fp32 dead -> BIG2)
    k_bmmx<1><<<dim3(HO, 3), 256, 0, stream>>>(LINVTh, LINVTl, LINVTh, LINVTl,
                                               AINV, AINVh, AINVl, nullptr, 1, 1.f);

    // COV split (COV fp32 in BIG1; LINVT dead -> BIG3)
    k_gsplit<<<(int)(BIGSZ / 1024), 256, 0, stream>>>(COV, COVh, COVl);

    // PT = AINV @ COV : split planes only (COV fp32 dead -> BIG1)
    k_bmmx<0><<<dim3(HO, 4), 256, 0, stream>>>(AINVh, AINVl, COVh, COVl,
                                               nullptr, PTh, PTl, nullptr, 0, 1.f);

    // G = AINV - PT @ AINV : split planes only (COVh/l dead -> BIG3)
    k_bmmx<1><<<dim3(HO, 3), 256, 0, stream>>>(PTh, PTl, AINVh, AINVl,
                                               nullptr, Ghi, Glo, AINV, 0, -1.f);

    k_kb3<<<dim3(16, HO), 256, 0, stream>>>(ZS, ZN, XS, XN, SF2v, Ghi, Glo, CV, (float*)d_out);
}

// Round 6
// 909.735 us; speedup vs baseline: 1.1905x; 1.1905x over previous
//
#include <hip/hip_runtime.h>

#define H_ 4
#define O_ 32
#define HO 128
#define M_ 128
#define M2 256
#define D_ 16
#define B_ 1024
#define JIT 1e-4f

typedef unsigned short ushort_t;
typedef __bf16 v8bf __attribute__((ext_vector_type(8)));
typedef float v16f __attribute__((ext_vector_type(16)));
typedef unsigned short v8us __attribute__((ext_vector_type(8)));
typedef unsigned short v4us __attribute__((ext_vector_type(4)));

__device__ inline void splitbf(float v, ushort_t& hb, ushort_t& lb) {
    unsigned int u = __float_as_uint(v);
    hb = (ushort_t)(u >> 16);
    float hf = __uint_as_float((unsigned int)hb << 16);
    float r = v - hf;
    lb = (ushort_t)(__float_as_uint(r) >> 16);
}
__device__ inline float bf2f(ushort_t u) { return __uint_as_float((unsigned int)u << 16); }

// ---------------------------------------------------------------------------
// merged preprocessing: blocks 0-127 scale_z (one pair each), 128-143 scale_x,
// 144 writes LSI/SF2 globals (consumed by later launches)
__global__ __launch_bounds__(256) void k_pre(const float* __restrict__ theta,
                                             const float* __restrict__ x,
                                             const float* __restrict__ z,
                                             const float* __restrict__ z_old,
                                             float* __restrict__ LSI, float* __restrict__ SF2,
                                             float* __restrict__ XS, float* __restrict__ XN,
                                             float* __restrict__ ZS, float* __restrict__ ZN) {
    int bb = blockIdx.x, t = threadIdx.x;
    if (bb == 144) {
        if (t < H_ * D_) {
            int h = t / D_, d = t % D_;
            LSI[h * D_ + d] = __expf(-theta[h * (D_ + 1) + 1 + d]);
        }
        if (t < H_) SF2[t] = __expf(theta[t * (D_ + 1)]);
        return;
    }
    __shared__ float ls[D_];
    if (bb < 128) {  // scale_z: pair = bb, row i = t
        int pair = bb, h = pair >> 5, o = pair & 31, i = t;
        if (t < D_) ls[t] = __expf(-theta[h * (D_ + 1) + 1 + t]);
        __syncthreads();
        const float* src = (i < M_) ? (z_old + ((long)o * M_ + i) * D_)
                                    : (z + ((long)o * M_ + (i - M_)) * D_);
        float s = 0.f;
#pragma unroll
        for (int d = 0; d < D_; d++) {
            float v = src[d] * ls[d];
            ZS[((long)pair * M2 + i) * D_ + d] = v;
            s += v * v;
        }
        ZN[pair * M2 + i] = s;
    } else {  // scale_x
        int j = (bb - 128) * 256 + t;  // h*B + b
        int h = j >> 10, b = j & 1023;
        if (t < D_) ls[t] = __expf(-theta[h * (D_ + 1) + 1 + t]);
        __syncthreads();
        float s = 0.f;
#pragma unroll
        for (int d = 0; d < D_; d++) {
            float v = x[b * D_ + d] * ls[d];
            XS[(long)j * D_ + d] = v;
            s += v * v;
        }
        XN[j] = s;
    }
}

// kuu2 = k_rbf(z_joint, z_joint) + JIT*I   [HO][256][256]
__global__ __launch_bounds__(256) void k_kuu2(const float* __restrict__ ZS,
                                              const float* __restrict__ ZN,
                                              const float* __restrict__ SF2,
                                              float* __restrict__ K2) {
    int pair = blockIdx.x;
    int h = pair >> 5;
    int t = threadIdx.x;
    __shared__ float zs[M2][D_];
    __shared__ float zn[M2];
    for (int e = t; e < M2 * D_; e += 256) zs[e / D_][e % D_] = ZS[(long)pair * M2 * D_ + e];
    zn[t] = ZN[pair * M2 + t];
    __syncthreads();
    float sf2 = SF2[h];
    float my[D_];
#pragma unroll
    for (int d = 0; d < D_; d++) my[d] = zs[t][d];
    float myn = zn[t];
    for (int q = 0; q < M2; q++) {
        float dot = 0.f;
#pragma unroll
        for (int d = 0; d < D_; d++) dot += zs[q][d] * my[d];
        float d2 = fmaxf(zn[q] + myn - 2.f * dot, 0.f);
        float v = sf2 * __expf(-0.5f * d2);
        if (q == t) v += JIT;
        K2[(long)pair * M2 * M2 + (long)q * M2 + t] = v;
    }
}

// blocked (BK=32) in-LDS Cholesky of a 128x128 block, 256 threads.
__global__ __launch_bounds__(256) void k_chol128(const float* __restrict__ src, long sps, int ldsrc,
                                                 float* __restrict__ dst, long spd, int lddst) {
    int pair = blockIdx.x, t = threadIdx.x;
    __shared__ float Ap[M_ * (M_ + 1) / 2];
    __shared__ float rsq[32];
    const float* S = src + (long)pair * sps;
    for (int e = t; e < M_ * (M_ + 1) / 2; e += 256) {
        int i = (int)((sqrtf(8.f * e + 1.f) - 1.f) * 0.5f);
        while ((i + 1) * (i + 2) / 2 <= e) i++;
        while (i * (i + 1) / 2 > e) i--;
        int j = e - i * (i + 1) / 2;
        Ap[e] = S[(long)i * ldsrc + j];
    }
    int pi[3], pj[3];
#pragma unroll
    for (int u = 0; u < 3; u++) {
        int p = t + u * 256;
        if (p < 528) {
            int i = (int)((sqrtf(8.f * p + 1.f) - 1.f) * 0.5f);
            while ((i + 1) * (i + 2) / 2 <= p) i++;
            while (i * (i + 1) / 2 > p) i--;
            pi[u] = i;
            pj[u] = p - i * (i + 1) / 2;
        } else {
            pi[u] = -1;
            pj[u] = 0;
        }
    }
    __syncthreads();

    for (int kb = 0; kb < 4; kb++) {
        int c0 = kb * 32;
        for (int k = 0; k < 32; k++) {
            int kc = c0 + k;
            float rd = 1.f / Ap[kc * (kc + 1) / 2 + kc];
#pragma unroll
            for (int u = 0; u < 3; u++) {
                int i = pi[u], j = pj[u];
                if (i > k && j > k) {
                    int gi = c0 + i, gj = c0 + j;
                    Ap[gi * (gi + 1) / 2 + gj] -=
                        Ap[gi * (gi + 1) / 2 + kc] * Ap[gj * (gj + 1) / 2 + kc] * rd;
                }
            }
            __syncthreads();
        }
        if (t < 32) {
            int g = c0 + t;
            rsq[t] = rsqrtf(Ap[g * (g + 1) / 2 + g]);
        }
        __syncthreads();
#pragma unroll
        for (int u = 0; u < 3; u++) {
            int i = pi[u], j = pj[u];
            if (i >= 0) {
                int gi = c0 + i, gj = c0 + j;
                Ap[gi * (gi + 1) / 2 + gj] *= rsq[j];
            }
        }
        __syncthreads();

        int R = M_ - c0 - 32;
        if (R > 0) {
            if (t < R) {
                int gi = c0 + 32 + t;
                int base = gi * (gi + 1) / 2 + c0;
                float xr[32];
#pragma unroll
                for (int j = 0; j < 32; j++) xr[j] = Ap[base + j];
#pragma unroll
                for (int q = 0; q < 32; q++) {
                    float xq = xr[q] * rsq[q];
                    xr[q] = xq;
#pragma unroll
                    for (int j = q + 1; j < 32; j++)
                        xr[j] -= xq * Ap[(c0 + j) * (c0 + j + 1) / 2 + c0 + q];
                }
#pragma unroll
                for (int j = 0; j < 32; j++) Ap[base + j] = xr[j];
            }
            __syncthreads();
            int nb = R >> 2;
            int ntile = nb * (nb + 1) / 2;
            for (int tp = t; tp < ntile; tp += 256) {
                int bi = (int)((sqrtf(8.f * tp + 1.f) - 1.f) * 0.5f);
                while ((bi + 1) * (bi + 2) / 2 <= tp) bi++;
                while (bi * (bi + 1) / 2 > tp) bi--;
                int bj = tp - bi * (bi + 1) / 2;
                int i0 = c0 + 32 + bi * 4, j0 = c0 + 32 + bj * 4;
                float acc[4][4] = {};
                for (int k = 0; k < 32; k++) {
                    float a[4], b[4];
#pragma unroll
                    for (int q = 0; q < 4; q++) a[q] = Ap[(i0 + q) * (i0 + q + 1) / 2 + c0 + k];
#pragma unroll
                    for (int r = 0; r < 4; r++) b[r] = Ap[(j0 + r) * (j0 + r + 1) / 2 + c0 + k];
#pragma unroll
                    for (int q = 0; q < 4; q++)
#pragma unroll
                        for (int r = 0; r < 4; r++) acc[q][r] += a[q] * b[r];
                }
#pragma unroll
                for (int q = 0; q < 4; q++)
#pragma unroll
                    for (int r = 0; r < 4; r++) {
                        int gi = i0 + q, gj = j0 + r;
                        if (gj <= gi) Ap[gi * (gi + 1) / 2 + gj] -= acc[q][r];
                    }
            }
            __syncthreads();
        }
    }

    float* Dst = dst + (long)pair * spd;
    for (int e = t; e < M_ * M_; e += 256) {
        int i = e >> 7, j = e & 127;
        Dst[(long)i * lddst + j] = (j <= i) ? Ap[i * (i + 1) / 2 + j] : 0.f;
    }
}

// fused 128 triangular inverse: Linv128 = (L256 TL)^{-1}, full incl. zero upper
__global__ __launch_bounds__(256) void k_trinv128(const float* __restrict__ L256,
                                                  float* __restrict__ Li) {
    int pair = blockIdx.x, t = threadIdx.x;
    long b2 = (long)pair * 65536, b1 = (long)pair * 16384;
    __shared__ float Ld[2][64][66], Wd[2][64][66], LB[64][66], Tt[64][66];
    for (int e = t; e < 8192; e += 256) {
        int g = e >> 12, i = (e >> 6) & 63, j = e & 63;
        Ld[g][i][j] = L256[b2 + (long)(g * 64 + i) * 256 + g * 64 + j];
    }
    for (int e = t; e < 4096; e += 256) {
        int i = e >> 6, j = e & 63;
        LB[i][j] = L256[b2 + (long)(64 + i) * 256 + j];
    }
    __syncthreads();
    if (t < 128) {
        int g = t >> 6, c = t & 63;
        for (int i = 0; i < 64; i++) {
            float acc = (i == c) ? 1.f : 0.f;
            for (int j = 0; j < i; j++) acc -= Ld[g][i][j] * Wd[g][j][c];
            Wd[g][i][c] = acc / Ld[g][i][i];
        }
    }
    __syncthreads();
    int ti = t >> 4, tj = t & 15;
    float acc[4][4] = {};
    for (int kk = 0; kk < 64; kk++) {
        float a[4], b[4];
#pragma unroll
        for (int q = 0; q < 4; q++) a[q] = LB[ti * 4 + q][kk];
#pragma unroll
        for (int r = 0; r < 4; r++) b[r] = Wd[0][kk][tj * 4 + r];
#pragma unroll
        for (int q = 0; q < 4; q++)
#pragma unroll
            for (int r = 0; r < 4; r++) acc[q][r] += a[q] * b[r];
    }
#pragma unroll
    for (int q = 0; q < 4; q++)
#pragma unroll
        for (int r = 0; r < 4; r++) Tt[ti * 4 + q][tj * 4 + r] = acc[q][r];
    __syncthreads();
    float xo[4][4] = {};
    for (int kk = 0; kk < 64; kk++) {
        float a[4], b[4];
#pragma unroll
        for (int q = 0; q < 4; q++) a[q] = Wd[1][ti * 4 + q][kk];
#pragma unroll
        for (int r = 0; r < 4; r++) b[r] = Tt[kk][tj * 4 + r];
#pragma unroll
        for (int q = 0; q < 4; q++)
#pragma unroll
            for (int r = 0; r < 4; r++) xo[q][r] -= a[q] * b[r];
    }
#pragma unroll
    for (int q = 0; q < 4; q++)
#pragma unroll
        for (int r = 0; r < 4; r++)
            Li[b1 + (long)(64 + ti * 4 + q) * 128 + tj * 4 + r] = xo[q][r];
    for (int e = t; e < 4096; e += 256) {
        int i = e >> 6, j = e & 63;
        Li[b1 + (long)i * 128 + j] = Wd[0][i][j];
        Li[b1 + (long)(64 + i) * 128 + 64 + j] = Wd[1][i][j];
        Li[b1 + (long)i * 128 + 64 + j] = 0.f;
    }
}

// fused 256 triangular inverse: writes LINVT split planes (LINVT[n][k]=LINV[k][n])
// + CV = Linv^T Linv m_joint (cvec).  BL quadrant of L256 comes from A1^T.
__global__ __launch_bounds__(256) void k_trinv256(const float* __restrict__ L256,
                                                  const float* __restrict__ A1,
                                                  const float* __restrict__ MJ,
                                                  ushort_t* __restrict__ Th,
                                                  ushort_t* __restrict__ Tl,
                                                  float* __restrict__ CV) {
    int pair = blockIdx.x, t = threadIdx.x;
    long b2 = (long)pair * 65536;
    __shared__ float Wd[4][64][66];
    __shared__ float Bf[4][64][66];
    __shared__ float vv[512];
    // stage 4 diagonal blocks (TL: g=0,1; BR: g=2,3 — chol wrote both quadrants)
    for (int e = t; e < 16384; e += 256) {
        int g = e >> 12, i = (e >> 6) & 63, j = e & 63;
        Bf[g][i][j] = L256[b2 + (long)(g * 64 + i) * 256 + g * 64 + j];
    }
    __syncthreads();
    {  // 4 parallel 64-tri inversions (one wave each; columns private)
        int g = t >> 6, c = t & 63;
        for (int i = 0; i < 64; i++) {
            float acc = (i == c) ? 1.f : 0.f;
            for (int j = 0; j < i; j++) acc -= Bf[g][i][j] * Wd[g][j][c];
            Wd[g][i][c] = acc / Bf[g][i][i];
        }
    }
    __syncthreads();
    // diag blocks -> planes (transposed)
    for (int e = t; e < 16384; e += 256) {
        int g = e >> 12, j = (e >> 6) & 63, i = e & 63;
        ushort_t hb, lb;
        splitbf(Wd[g][j][i], hb, lb);  // value LINV[I0+j][J0+i]? careful below
        // LINVT[(g*64+i2)][g*64+k2] = LINV[k2][i2]; write with k fastest:
        // here: out row n=g*64+j? Use direct: LINVT[n][k] = Wd[g][k- g64][n-g64]
        long a = b2 + (long)(g * 64 + j) * 256 + g * 64 + i;
        splitbf(Wd[g][i][j], hb, lb);  // LINVT[n=g64+j][k=g64+i] = LINV[i][j] block-local = Wd[g][i][j]
        Th[a] = hb;
        Tl[a] = lb;
    }
    // zero tiles of LINVT: (N,K) with K<N
    {
        const int ZNb[6] = {1, 2, 2, 3, 3, 3};
        const int ZKb[6] = {0, 0, 1, 0, 1, 2};
        for (int e = t; e < 6 * 4096; e += 256) {
            int w = e >> 12, j = (e >> 6) & 63, i = e & 63;
            long a = b2 + (long)(ZNb[w] * 64 + j) * 256 + ZKb[w] * 64 + i;
            Th[a] = 0;
            Tl[a] = 0;
        }
    }
    // off-blocks: X_IJ = -Dinv_I * sum_{K=J..I-1} L_IK * X_KJ  (X_JJ = Dinv_J)
    int ti = t >> 4, tj = t & 15;
    const int SI[6] = {1, 2, 3, 2, 3, 3};
    const int SJ[6] = {0, 1, 2, 0, 1, 0};
    const int SKEEP[6] = {0, 1, -1, 2, -1, -1};  // Bf slot for X10, X21, X20
    for (int s = 0; s < 6; s++) {
        int I = SI[s], J = SJ[s];
        float acc[4][4] = {};
        for (int K = J; K < I; K++) {
            // stage L_IK into Bf[3]
            if (I >= 2 && K < 2) {  // BL quadrant = A1^T
                for (int e = t; e < 4096; e += 256) {
                    int k = e >> 6, i = e & 63;
                    Bf[3][i][k] = A1[(long)pair * 16384 + (long)(K * 64 + k) * 128 + (I - 2) * 64 + i];
                }
            } else {
                for (int e = t; e < 4096; e += 256) {
                    int i = e >> 6, j = e & 63;
                    Bf[3][i][j] = L256[b2 + (long)(I * 64 + i) * 256 + K * 64 + j];
                }
            }
            __syncthreads();
            const float(*X)[66] = (K == J) ? Wd[J]
                                 : (K == 1 && J == 0) ? (const float(*)[66])Bf[0]
                                 : (K == 2 && J == 1) ? (const float(*)[66])Bf[1]
                                                      : (const float(*)[66])Bf[2];
            for (int kk = 0; kk < 64; kk++) {
                float a[4], b[4];
#pragma unroll
                for (int q = 0; q < 4; q++) a[q] = Bf[3][ti * 4 + q][kk];
#pragma unroll
                for (int r = 0; r < 4; r++) b[r] = X[kk][tj * 4 + r];
#pragma unroll
                for (int q = 0; q < 4; q++)
#pragma unroll
                    for (int r = 0; r < 4; r++) acc[q][r] += a[q] * b[r];
            }
            __syncthreads();
        }
        // T into Bf[3]
#pragma unroll
        for (int q = 0; q < 4; q++)
#pragma unroll
            for (int r = 0; r < 4; r++) Bf[3][ti * 4 + q][tj * 4 + r] = acc[q][r];
        __syncthreads();
        float xo[4][4] = {};
        for (int kk = 0; kk < 64; kk++) {
            float a[4], b[4];
#pragma unroll
            for (int q = 0; q < 4; q++) a[q] = Wd[I][ti * 4 + q][kk];
#pragma unroll
            for (int r = 0; r < 4; r++) b[r] = Bf[3][kk][tj * 4 + r];
#pragma unroll
            for (int q = 0; q < 4; q++)
#pragma unroll
                for (int r = 0; r < 4; r++) xo[q][r] -= a[q] * b[r];
        }
#pragma unroll
        for (int q = 0; q < 4; q++)
#pragma unroll
            for (int r = 0; r < 4; r++) {
                float v = xo[q][r];
                ushort_t hb, lb;
                splitbf(v, hb, lb);
                long a = b2 + (long)(J * 64 + tj * 4 + r) * 256 + I * 64 + ti * 4 + q;
                Th[a] = hb;
                Tl[a] = lb;
                if (SKEEP[s] >= 0) Bf[SKEEP[s]][ti * 4 + q][tj * 4 + r] = v;
            }
        __syncthreads();
    }
    // cvec: c = Linv^T (Linv * mj), reading reconstructed planes
    vv[t] = MJ[pair * 256 + t];
    __syncthreads();
    float tm = 0.f;
    for (int j = 0; j <= t; j++) {
        long a = b2 + (long)j * 256 + t;  // LINV[t][j] = LINVT[j][t]
        tm += (bf2f(Th[a]) + bf2f(Tl[a])) * vv[j];
    }
    vv[256 + t] = tm;
    __syncthreads();
    float cv = 0.f;
    for (int k = t; k < 256; k++) {
        long a = b2 + (long)t * 256 + k;  // LINV[k][t] = LINVT[t][k]
        cv += (bf2f(Th[a]) + bf2f(Tl[a])) * vv[256 + k];
    }
    CV[pair * 256 + t] = cv;
}

// a2 = Linv128 * m_old ; m_new = A1^T a2 + u_mean ; write m_joint
__global__ __launch_bounds__(128) void k_stage1vec(const float* __restrict__ Linv128,
                                                   const float* __restrict__ A1,
                                                   const float* __restrict__ m_old,
                                                   const float* __restrict__ u_mean,
                                                   float* __restrict__ MJ) {
    int pair = blockIdx.x, o = pair & 31, t = threadIdx.x;
    __shared__ float mo[128], a2[128];
    mo[t] = m_old[o * 128 + t];
    __syncthreads();
    const float* Lr = Linv128 + (long)pair * 16384 + (long)t * 128;
    float acc = 0.f;
    for (int j = 0; j <= t; j++) acc += Lr[j] * mo[j];
    a2[t] = acc;
    __syncthreads();
    float m = 0.f;
    for (int i = 0; i < 128; i++) m += A1[(long)pair * 16384 + (long)i * 128 + t] * a2[i];
    MJ[pair * 256 + t] = mo[t];
    MJ[pair * 256 + 128 + t] = m + u_mean[o * 128 + t];
}

// build WcT split planes: WcT[n][k] = Wc[k][n],
// Wc = [[L_old, 0],[BLW, UT]] lower-tri (BLW = A1^T A3, UT = unpacked u_tril)
__global__ __launch_bounds__(256) void k_wsplit(const float* __restrict__ L_old,
                                                const float* __restrict__ BLW,
                                                const float* __restrict__ vec,
                                                ushort_t* __restrict__ Th,
                                                ushort_t* __restrict__ Tl) {
    int pair = blockIdx.x, o = pair & 31, t = threadIdx.x;
    long b2 = (long)pair * 65536;
    __shared__ float vs[M_ * (M_ + 1) / 2];
    __shared__ float tile[32][33];
    for (int e = t; e < M_ * (M_ + 1) / 2; e += 256) vs[e] = vec[(long)o * (M_ * (M_ + 1) / 2) + e];
    __syncthreads();
    // BR quadrant of WcT: [128+n][128+k] = UT[k][n]
    for (int e = t; e < 16384; e += 256) {
        int n = e >> 7, k = e & 127;
        float v = (k >= n) ? vs[k * (k + 1) / 2 + n] : 0.f;
        ushort_t hb, lb;
        splitbf(v, hb, lb);
        long a = b2 + (long)(128 + n) * 256 + 128 + k;
        Th[a] = hb;
        Tl[a] = lb;
    }
    // zeros: rows 128+, cols <128
    for (int e = t; e < 16384; e += 256) {
        int n = e >> 7, k = e & 127;
        long a = b2 + (long)(128 + n) * 256 + k;
        Th[a] = 0;
        Tl[a] = 0;
    }
    // TL from L_old^T ; cols 128+ rows <128 from BLW^T
    for (int part = 0; part < 2; part++) {
        const float* src = part ? (BLW + (long)pair * 16384) : (L_old + (long)o * 16384);
        int cofs = part ? 128 : 0;
        for (int bi = 0; bi < 4; bi++)
            for (int bj = 0; bj < 4; bj++) {
                __syncthreads();
                for (int r = t >> 5; r < 32; r += 8)
                    tile[r][t & 31] = src[(long)(bi * 32 + r) * 128 + bj * 32 + (t & 31)];
                __syncthreads();
                for (int r = t >> 5; r < 32; r += 8) {
                    ushort_t hb, lb;
                    splitbf(tile[t & 31][r], hb, lb);
                    long a = b2 + (long)(bj * 32 + r) * 256 + cofs + bi * 32 + (t & 31);
                    Th[a] = hb;
                    Tl[a] = lb;
                }
            }
    }
}

// generic batched fp32 SGEMM (128-chain only)
template <int TA, int TB>
__global__ __launch_bounds__(256) void k_bmm(const float* __restrict__ A, long aSH, long aSO, int lda,
                                             const float* __restrict__ B, long bSH, long bSO, int ldb,
                                             float* __restrict__ C, long cSH, long cSO, int ldc,
                                             int Ksz, float alpha, int accum) {
    int pair = blockIdx.x;
    int h = pair >> 5, o = pair & 31;
    const float* Ap = A + (long)h * aSH + (long)o * aSO;
    const float* Bp = B + (long)h * bSH + (long)o * bSO;
    float* Cp = C + (long)h * cSH + (long)o * cSO;
    int t = threadIdx.x, tx = t & 15, ty = t >> 4;
    __shared__ float As[16][132], Bs[16][132];
    float acc[8][8] = {};
    for (int kt = 0; kt < Ksz; kt += 16) {
#pragma unroll
        for (int q = 0; q < 8; q++) {
            int e = q * 256 + t;
            if (TA) {
                int kk = e >> 7, m = e & 127;
                As[kk][m] = Ap[(long)(kt + kk) * lda + m];
            } else {
                int m = e >> 4, kk = e & 15;
                As[kk][m] = Ap[(long)m * lda + kt + kk];
            }
            if (TB) {
                int n = e >> 4, kk = e & 15;
                Bs[kk][n] = Bp[(long)n * ldb + kt + kk];
            } else {
                int kk = e >> 7, n = e & 127;
                Bs[kk][n] = Bp[(long)(kt + kk) * ldb + n];
            }
        }
        __syncthreads();
#pragma unroll
        for (int kk = 0; kk < 16; kk++) {
            float a[8], b[8];
#pragma unroll
            for (int q = 0; q < 8; q++) { a[q] = As[kk][ty + 16 * q]; b[q] = Bs[kk][tx + 16 * q]; }
#pragma unroll
            for (int q = 0; q < 8; q++)
#pragma unroll
                for (int r = 0; r < 8; r++) acc[q][r] += a[q] * b[r];
        }
        __syncthreads();
    }
#pragma unroll
    for (int q = 0; q < 8; q++)
#pragma unroll
        for (int r = 0; r < 8; r++) {
            long idx = (long)(ty + 16 * q) * ldc + tx + 16 * r;
            float v = alpha * acc[q][r];
            if (accum) v += Cp[idx];
            Cp[idx] = v;
        }
}

// split-bf16 MFMA batched GEMM: C = alpha*(Ah+Al)(Bh+Bl)^T [+ Dm]
// planes row-major [out][k], ld 256, per-pair stride 65536.
// kLoMode: 0 none, 1 k0=max(I0,J0), 2 k0=J0
#define BSTR 56
template <int TILES3>
__global__ __launch_bounds__(256) void k_bmmx(const ushort_t* __restrict__ Ah,
                                              const ushort_t* __restrict__ Al,
                                              const ushort_t* __restrict__ Bh,
                                              const ushort_t* __restrict__ Bl,
                                              float* __restrict__ Cf,
                                              ushort_t* __restrict__ Chi,
                                              ushort_t* __restrict__ Clo,
                                              const float* __restrict__ Dm,
                                              int kLoMode, float alpha) {
    int pair = blockIdx.x;
    long base = (long)pair * 65536;
    int I0, J0, mir = 0;
    if (TILES3) {
        int qb = blockIdx.y;
        I0 = (qb == 0) ? 0 : 128;
        J0 = (qb == 2) ? 0 : I0;
        mir = (qb == 2);
    } else {
        I0 = (blockIdx.y >> 1) * 128;
        J0 = (blockIdx.y & 1) * 128;
    }
    int k0 = (kLoMode == 1) ? max(I0, J0) : (kLoMode == 2) ? J0 : 0;
    int t = threadIdx.x;
    int w = t >> 6, lane = t & 63;
    int l31 = lane & 31, lhalf = lane >> 5;
    int wy = w >> 1, wx = w & 1;

    __shared__ __align__(16) ushort_t AsH[128][BSTR], AsL[128][BSTR];
    __shared__ __align__(16) ushort_t BsH[128][BSTR], BsL[128][BSTR];

    v16f acc[2][2];
#pragma unroll
    for (int mt = 0; mt < 2; mt++)
#pragma unroll
        for (int nt = 0; nt < 2; nt++)
#pragma unroll
            for (int r = 0; r < 16; r++) acc[mt][nt][r] = 0.f;

    for (int kt = k0; kt < 256; kt += 32) {
        __syncthreads();
#pragma unroll
        for (int u = 0; u < 2; u++) {
            int idx = u * 256 + t;
            int m = idx >> 2, kc = (idx & 3) * 8;
            long arow = base + (long)(I0 + m) * 256 + kt + kc;
            long brow = base + (long)(J0 + m) * 256 + kt + kc;
            *(v8us*)&AsH[m][kc] = *(const v8us*)(Ah + arow);
            *(v8us*)&AsL[m][kc] = *(const v8us*)(Al + arow);
            *(v8us*)&BsH[m][kc] = *(const v8us*)(Bh + brow);
            *(v8us*)&BsL[m][kc] = *(const v8us*)(Bl + brow);
        }
        __syncthreads();
#pragma unroll
        for (int ks = 0; ks < 2; ks++) {
            int ko = ks * 16 + lhalf * 8;
            v8bf ah[2], al[2], bh[2], bl[2];
#pragma unroll
            for (int mt = 0; mt < 2; mt++) {
                int r = wy * 64 + mt * 32 + l31;
                ah[mt] = *(const v8bf*)&AsH[r][ko];
                al[mt] = *(const v8bf*)&AsL[r][ko];
            }
#pragma unroll
            for (int nt = 0; nt < 2; nt++) {
                int r = wx * 64 + nt * 32 + l31;
                bh[nt] = *(const v8bf*)&BsH[r][ko];
                bl[nt] = *(const v8bf*)&BsL[r][ko];
            }
#pragma unroll
            for (int mt = 0; mt < 2; mt++)
#pragma unroll
                for (int nt = 0; nt < 2; nt++) {
                    acc[mt][nt] = __builtin_amdgcn_mfma_f32_32x32x16_bf16(ah[mt], bh[nt], acc[mt][nt], 0, 0, 0);
                    acc[mt][nt] = __builtin_amdgcn_mfma_f32_32x32x16_bf16(ah[mt], bl[nt], acc[mt][nt], 0, 0, 0);
                    acc[mt][nt] = __builtin_amdgcn_mfma_f32_32x32x16_bf16(al[mt], bh[nt], acc[mt][nt], 0, 0, 0);
                }
        }
    }

#pragma unroll
    for (int mt = 0; mt < 2; mt++)
#pragma unroll
        for (int nt = 0; nt < 2; nt++) {
#pragma unroll
            for (int r = 0; r < 16; r++) {
                int row = I0 + wy * 64 + mt * 32 + 8 * (r >> 2) + 4 * lhalf + (r & 3);
                int col = J0 + wx * 64 + nt * 32 + l31;
                long idx = base + (long)row * 256 + col;
                float v = alpha * acc[mt][nt][r];
                if (Dm) v += Dm[idx];
                ushort_t hb, lb;
                splitbf(v, hb, lb);
                if (Cf) Cf[idx] = v;
                if (Chi) { Chi[idx] = hb; Clo[idx] = lb; }
                if (mir) {
                    long idxT = base + (long)col * 256 + row;
                    if (Cf) Cf[idxT] = v;
                    if (Chi) { Chi[idxT] = hb; Clo[idxT] = lb; }
                }
            }
        }
}

// fused final kernel (MFMA); 1D grid: pair = idx&127 (XCD-local G reuse), bt = idx>>7
#define KTP 280
__global__ __launch_bounds__(256) void k_kb3(const float* __restrict__ ZS, const float* __restrict__ ZN,
                                             const float* __restrict__ XS, const float* __restrict__ XN,
                                             const float* __restrict__ SF2,
                                             const ushort_t* __restrict__ Ghi,
                                             const ushort_t* __restrict__ Glo,
                                             const float* __restrict__ CV, float* __restrict__ out) {
    int pair = blockIdx.x & 127;
    int bt = blockIdx.x >> 7;
    int h = pair >> 5;
    int t = threadIdx.x;
    int w = t >> 6;
    int lane = t & 63;
    int l31 = lane & 31, lhalf = lane >> 5;

    __shared__ __align__(16) ushort_t KbT[64][KTP];
    __shared__ float qpart[4][64];
    __shared__ float mup[4][64];

    float sf2 = SF2[h];
    {
        int b = t & 63;
        long bg = (long)h * B_ + bt * 64 + b;
        const float4* xrow = (const float4*)(XS + bg * 16);
        float4 x0 = xrow[0], x1 = xrow[1], x2 = xrow[2], x3 = xrow[3];
        float xn = XN[bg];
        float mupart = 0.f;
        const float* cvp = CV + pair * 256;
        const float* znp = ZN + pair * 256;
#pragma unroll 2
        for (int j8 = 0; j8 < 8; j8++) {
            v8us kb8;
#pragma unroll
            for (int e = 0; e < 8; e++) {
                int j = w * 64 + j8 * 8 + e;
                const float4* zrow = (const float4*)(ZS + ((long)pair * 256 + j) * 16);
                float4 z0 = zrow[0], z1 = zrow[1], z2 = zrow[2], z3 = zrow[3];
                float dot = z0.x * x0.x + z0.y * x0.y + z0.z * x0.z + z0.w * x0.w +
                            z1.x * x1.x + z1.y * x1.y + z1.z * x1.z + z1.w * x1.w +
                            z2.x * x2.x + z2.y * x2.y + z2.z * x2.z + z2.w * x2.w +
                            z3.x * x3.x + z3.y * x3.y + z3.z * x3.z + z3.w * x3.w;
                float d2 = fmaxf(znp[j] + xn - 2.f * dot, 0.f);
                float kv = sf2 * __expf(-0.5f * d2);
                mupart += cvp[j] * kv;
                unsigned int u = __float_as_uint(kv);
                u += 0x7fffu + ((u >> 16) & 1u);
                kb8[e] = (unsigned short)(u >> 16);
            }
            *(v8us*)&KbT[b][w * 64 + j8 * 8] = kb8;
        }
        mup[w][b] = mupart;
    }
    __syncthreads();

    v16f acc[2][2];
#pragma unroll
    for (int mt = 0; mt < 2; mt++)
#pragma unroll
        for (int nt = 0; nt < 2; nt++)
#pragma unroll
            for (int r = 0; r < 16; r++) acc[mt][nt][r] = 0.f;

    const ushort_t* GhiP = Ghi + (long)pair * 65536;
    const ushort_t* GloP = Glo + (long)pair * 65536;
    for (int k0 = 0; k0 < 256; k0 += 16) {
        v8bf bfr[2];
#pragma unroll
        for (int nt = 0; nt < 2; nt++)
            bfr[nt] = *(const v8bf*)&KbT[nt * 32 + l31][k0 + lhalf * 8];
#pragma unroll
        for (int mt = 0; mt < 2; mt++) {
            int i = w * 64 + mt * 32 + l31;
            v8bf ah = *(const v8bf*)(GhiP + (long)i * 256 + k0 + lhalf * 8);
            v8bf al = *(const v8bf*)(GloP + (long)i * 256 + k0 + lhalf * 8);
#pragma unroll
            for (int nt = 0; nt < 2; nt++) {
                acc[mt][nt] = __builtin_amdgcn_mfma_f32_32x32x16_bf16(ah, bfr[nt], acc[mt][nt], 0, 0, 0);
                acc[mt][nt] = __builtin_amdgcn_mfma_f32_32x32x16_bf16(al, bfr[nt], acc[mt][nt], 0, 0, 0);
            }
        }
    }

    float qp[2] = {0.f, 0.f};
#pragma unroll
    for (int mt = 0; mt < 2; mt++) {
#pragma unroll
        for (int nt = 0; nt < 2; nt++) {
            int b = nt * 32 + l31;
#pragma unroll
            for (int g = 0; g < 4; g++) {
                int ibase = w * 64 + mt * 32 + 8 * g + 4 * lhalf;
                v4us k4 = *(const v4us*)&KbT[b][ibase];
#pragma unroll
                for (int e = 0; e < 4; e++) {
                    float kv = bf2f(k4[e]);
                    qp[nt] += kv * acc[mt][nt][4 * g + e];
                }
            }
        }
    }
#pragma unroll
    for (int nt = 0; nt < 2; nt++) {
        qp[nt] += __shfl_down(qp[nt], 32, 64);
        if (lhalf == 0) qpart[w][nt * 32 + l31] = qp[nt];
    }
    __syncthreads();

    if (t < 64) {
        float mu = mup[0][t] + mup[1][t] + mup[2][t] + mup[3][t];
        float q = qpart[0][t] + qpart[1][t] + qpart[2][t] + qpart[3][t];
        long ob = (long)pair * 1024 + bt * 64 + t;
        out[ob] = mu;
        out[(long)H_ * O_ * B_ + ob] = sf2 - q;
    }
}

// ---------------------------------------------------------------------------
extern "C" void kernel_launch(void* const* d_in, const int* in_sizes, int n_in,
                              void* d_out, int out_size, void* d_ws, size_t ws_size,
                              hipStream_t stream) {
    const float* x = (const float*)d_in[0];
    const float* z = (const float*)d_in[1];
    const float* u_mean = (const float*)d_in[2];
    const float* u_tril_vec = (const float*)d_in[3];
    const float* m_old = (const float*)d_in[4];
    const float* L_old = (const float*)d_in[5];
    const float* z_old = (const float*)d_in[6];
    const float* theta = (const float*)d_in[7];

    const long BIGSZ = (long)HO * M2 * M2;  // 8388608
    const long MSZ = (long)HO * M_ * M_;
    const long SH2 = (long)O_ * M2 * M2;
    const long SO2 = (long)M2 * M2;
    const long SH1 = (long)O_ * M_ * M_;
    const long SO1 = (long)M_ * M_;

    float* ws = (float*)d_ws;
    long off = 0;
    float* BIG0 = ws + off; off += BIGSZ;  // KUU2 -> AINV fp32
    float* BIG1 = ws + off; off += BIGSZ;  // LINVT h/l -> Y h/l
    float* BIG2 = ws + off; off += BIGSZ;  // Linv128|A1|A3|BLW -> AINV h/l
    float* BIG3 = ws + off; off += BIGSZ;  // L256 -> WcT h/l -> G h/l
    float* ZS = ws + off; off += (long)HO * M2 * D_;
    float* XS = ws + off; off += (long)H_ * B_ * D_;
    float* ZN = ws + off; off += (long)HO * M2;
    float* XN = ws + off; off += (long)H_ * B_;
    float* MJ = ws + off; off += (long)HO * M2;
    float* CV = ws + off; off += (long)HO * M2;
    float* LSI = ws + off; off += H_ * D_;
    float* SF2v = ws + off; off += H_;

    float* KUU2 = BIG0;
    float* AINV = BIG0;
    float* Linv128 = BIG2;
    float* A1 = BIG2 + MSZ;
    float* A3 = BIG2 + 2 * MSZ;
    float* BLW = BIG2 + 3 * MSZ;
    float* L256 = BIG3;
    ushort_t* LINVTh = (ushort_t*)BIG1;
    ushort_t* LINVTl = LINVTh + BIGSZ;
    ushort_t* AINVh = (ushort_t*)BIG2;
    ushort_t* AINVl = AINVh + BIGSZ;
    ushort_t* WcTh = (ushort_t*)BIG3;
    ushort_t* WcTl = WcTh + BIGSZ;
    ushort_t* Yh = (ushort_t*)BIG1;
    ushort_t* Yl = Yh + BIGSZ;
    ushort_t* Ghi = (ushort_t*)BIG3;
    ushort_t* Glo = Ghi + BIGSZ;
    const long BRoff = 128L * M2 + 128;

    // 1. merged preprocessing
    k_pre<<<145, 256, 0, stream>>>(theta, x, z, z_old, LSI, SF2v, XS, XN, ZS, ZN);
    // 2. kuu2
    k_kuu2<<<HO, 256, 0, stream>>>(ZS, ZN, SF2v, KUU2);
    // 3. chol TL
    k_chol128<<<HO, 256, 0, stream>>>(KUU2, SO2, M2, L256, SO2, M2);
    // 4. Linv128
    k_trinv128<<<HO, 256, 0, stream>>>(L256, Linv128);
    // 5-6. A1 = Linv128 @ kuf ; A3 = Linv128 @ L_old
    k_bmm<0, 0><<<HO, 256, 0, stream>>>(Linv128, SH1, SO1, M_, KUU2 + 128, SH2, SO2, M2,
                                        A1, SH1, SO1, M_, M_, 1.f, 0);
    k_bmm<0, 0><<<HO, 256, 0, stream>>>(Linv128, SH1, SO1, M_, L_old, 0, SO1, M_,
                                        A3, SH1, SO1, M_, M_, 1.f, 0);
    // 7. m_joint
    k_stage1vec<<<HO, 128, 0, stream>>>(Linv128, A1, m_old, u_mean, MJ);
    // 8. BLW = A1^T @ A3  (= Wc BL block)
    k_bmm<1, 0><<<HO, 256, 0, stream>>>(A1, SH1, SO1, M_, A3, SH1, SO1, M_,
                                        BLW, SH1, SO1, M_, M_, 1.f, 0);
    // 9. Schur: KUU2_BR -= A1^T A1
    k_bmm<1, 0><<<HO, 256, 0, stream>>>(A1, SH1, SO1, M_, A1, SH1, SO1, M_,
                                        KUU2 + BRoff, SH2, SO2, M2, M_, -1.f, 1);
    // 10. chol BR
    k_chol128<<<HO, 256, 0, stream>>>(KUU2 + BRoff, SO2, M2, L256 + BRoff, SO2, M2);
    // 11. full 256 triangular inverse -> LINVT planes + CV (cvec fused)
    k_trinv256<<<HO, 256, 0, stream>>>(L256, A1, MJ, LINVTh, LINVTl, CV);
    // 12. WcT planes (L256 dead)
    k_wsplit<<<HO, 256, 0, stream>>>(L_old, BLW, u_tril_vec, WcTh, WcTl);
    // 13. AINV = LINVT (.) LINVT (syrk, k>=max) -> fp32 + planes (BIG2 free now)
    k_bmmx<1><<<dim3(HO, 3), 256, 0, stream>>>(LINVTh, LINVTl, LINVTh, LINVTl,
                                               AINV, AINVh, AINVl, nullptr, 1, 1.f);
    // 14. Y = AINV @ Wc  (B = WcT planes, k>=J0) -> Y planes (BIG1, LINVT dead)
    k_bmmx<0><<<dim3(HO, 4), 256, 0, stream>>>(AINVh, AINVl, WcTh, WcTl,
                                               nullptr, Yh, Yl, nullptr, 2, 1.f);
    // 15. G = AINV - Y Y^T (syrk) -> G planes (BIG3, WcT dead)
    k_bmmx<1><<<dim3(HO, 3), 256, 0, stream>>>(Yh, Yl, Yh, Yl,
                                               nullptr, Ghi, Glo, AINV, 0, -1.f);
    // 16. fused predict
    k_kb3<<<2048, 256, 0, stream>>>(ZS, ZN, XS, XN, SF2v, Ghi, Glo, CV, (float*)d_out);
}

// Round 7
// 906.943 us; speedup vs baseline: 1.1942x; 1.0031x over previous
//
#include <hip/hip_runtime.h>

#define H_ 4
#define O_ 32
#define HO 128
#define M_ 128
#define M2 256
#define D_ 16
#define B_ 1024
#define JIT 1e-4f

typedef unsigned short ushort_t;
typedef __bf16 v8bf __attribute__((ext_vector_type(8)));
typedef float v16f __attribute__((ext_vector_type(16)));
typedef unsigned short v8us __attribute__((ext_vector_type(8)));
typedef unsigned short v4us __attribute__((ext_vector_type(4)));

__device__ inline void splitbf(float v, ushort_t& hb, ushort_t& lb) {
    unsigned int u = __float_as_uint(v);
    hb = (ushort_t)(u >> 16);
    float hf = __uint_as_float((unsigned int)hb << 16);
    float r = v - hf;
    lb = (ushort_t)(__float_as_uint(r) >> 16);
}
__device__ inline float bf2f(ushort_t u) { return __uint_as_float((unsigned int)u << 16); }

// ---------------------------------------------------------------------------
// merged preprocessing
__global__ __launch_bounds__(256) void k_pre(const float* __restrict__ theta,
                                             const float* __restrict__ x,
                                             const float* __restrict__ z,
                                             const float* __restrict__ z_old,
                                             float* __restrict__ SF2,
                                             float* __restrict__ XS, float* __restrict__ XN,
                                             float* __restrict__ ZS, float* __restrict__ ZN) {
    int bb = blockIdx.x, t = threadIdx.x;
    if (bb == 144) {
        if (t < H_) SF2[t] = __expf(theta[t * (D_ + 1)]);
        return;
    }
    __shared__ float ls[D_];
    if (bb < 128) {
        int pair = bb, h = pair >> 5, o = pair & 31, i = t;
        if (t < D_) ls[t] = __expf(-theta[h * (D_ + 1) + 1 + t]);
        __syncthreads();
        const float* src = (i < M_) ? (z_old + ((long)o * M_ + i) * D_)
                                    : (z + ((long)o * M_ + (i - M_)) * D_);
        float s = 0.f;
#pragma unroll
        for (int d = 0; d < D_; d++) {
            float v = src[d] * ls[d];
            ZS[((long)pair * M2 + i) * D_ + d] = v;
            s += v * v;
        }
        ZN[pair * M2 + i] = s;
    } else {
        int j = (bb - 128) * 256 + t;
        int h = j >> 10, b = j & 1023;
        if (t < D_) ls[t] = __expf(-theta[h * (D_ + 1) + 1 + t]);
        __syncthreads();
        float s = 0.f;
#pragma unroll
        for (int d = 0; d < D_; d++) {
            float v = x[b * D_ + d] * ls[d];
            XS[(long)j * D_ + d] = v;
            s += v * v;
        }
        XN[j] = s;
    }
}

// kuu2 = k_rbf(z_joint, z_joint) + JIT*I   [HO][256][256]
__global__ __launch_bounds__(256) void k_kuu2(const float* __restrict__ ZS,
                                              const float* __restrict__ ZN,
                                              const float* __restrict__ SF2,
                                              float* __restrict__ K2) {
    int pair = blockIdx.x;
    int h = pair >> 5;
    int t = threadIdx.x;
    __shared__ float zs[M2][D_];
    __shared__ float zn[M2];
    for (int e = t; e < M2 * D_; e += 256) zs[e / D_][e % D_] = ZS[(long)pair * M2 * D_ + e];
    zn[t] = ZN[pair * M2 + t];
    __syncthreads();
    float sf2 = SF2[h];
    float my[D_];
#pragma unroll
    for (int d = 0; d < D_; d++) my[d] = zs[t][d];
    float myn = zn[t];
    for (int q = 0; q < M2; q++) {
        float dot = 0.f;
#pragma unroll
        for (int d = 0; d < D_; d++) dot += zs[q][d] * my[d];
        float d2 = fmaxf(zn[q] + myn - 2.f * dot, 0.f);
        float v = sf2 * __expf(-0.5f * d2);
        if (q == t) v += JIT;
        K2[(long)pair * M2 * M2 + (long)q * M2 + t] = v;
    }
}

// blocked (BK=32) in-LDS Cholesky of a 128x128 block, 256 threads.
__global__ __launch_bounds__(256) void k_chol128(const float* __restrict__ src, long sps, int ldsrc,
                                                 float* __restrict__ dst, long spd, int lddst) {
    int pair = blockIdx.x, t = threadIdx.x;
    __shared__ float Ap[M_ * (M_ + 1) / 2];
    __shared__ float rsq[32];
    const float* S = src + (long)pair * sps;
    for (int e = t; e < M_ * (M_ + 1) / 2; e += 256) {
        int i = (int)((sqrtf(8.f * e + 1.f) - 1.f) * 0.5f);
        while ((i + 1) * (i + 2) / 2 <= e) i++;
        while (i * (i + 1) / 2 > e) i--;
        int j = e - i * (i + 1) / 2;
        Ap[e] = S[(long)i * ldsrc + j];
    }
    int pi[3], pj[3];
#pragma unroll
    for (int u = 0; u < 3; u++) {
        int p = t + u * 256;
        if (p < 528) {
            int i = (int)((sqrtf(8.f * p + 1.f) - 1.f) * 0.5f);
            while ((i + 1) * (i + 2) / 2 <= p) i++;
            while (i * (i + 1) / 2 > p) i--;
            pi[u] = i;
            pj[u] = p - i * (i + 1) / 2;
        } else {
            pi[u] = -1;
            pj[u] = 0;
        }
    }
    __syncthreads();

    for (int kb = 0; kb < 4; kb++) {
        int c0 = kb * 32;
        for (int k = 0; k < 32; k++) {
            int kc = c0 + k;
            float rd = 1.f / Ap[kc * (kc + 1) / 2 + kc];
#pragma unroll
            for (int u = 0; u < 3; u++) {
                int i = pi[u], j = pj[u];
                if (i > k && j > k) {
                    int gi = c0 + i, gj = c0 + j;
                    Ap[gi * (gi + 1) / 2 + gj] -=
                        Ap[gi * (gi + 1) / 2 + kc] * Ap[gj * (gj + 1) / 2 + kc] * rd;
                }
            }
            __syncthreads();
        }
        if (t < 32) {
            int g = c0 + t;
            rsq[t] = rsqrtf(Ap[g * (g + 1) / 2 + g]);
        }
        __syncthreads();
#pragma unroll
        for (int u = 0; u < 3; u++) {
            int i = pi[u], j = pj[u];
            if (i >= 0) {
                int gi = c0 + i, gj = c0 + j;
                Ap[gi * (gi + 1) / 2 + gj] *= rsq[j];
            }
        }
        __syncthreads();

        int R = M_ - c0 - 32;
        if (R > 0) {
            if (t < R) {
                int gi = c0 + 32 + t;
                int base = gi * (gi + 1) / 2 + c0;
                float xr[32];
#pragma unroll
                for (int j = 0; j < 32; j++) xr[j] = Ap[base + j];
#pragma unroll
                for (int q = 0; q < 32; q++) {
                    float xq = xr[q] * rsq[q];
                    xr[q] = xq;
#pragma unroll
                    for (int j = q + 1; j < 32; j++)
                        xr[j] -= xq * Ap[(c0 + j) * (c0 + j + 1) / 2 + c0 + q];
                }
#pragma unroll
                for (int j = 0; j < 32; j++) Ap[base + j] = xr[j];
            }
            __syncthreads();
            int nb = R >> 2;
            int ntile = nb * (nb + 1) / 2;
            for (int tp = t; tp < ntile; tp += 256) {
                int bi = (int)((sqrtf(8.f * tp + 1.f) - 1.f) * 0.5f);
                while ((bi + 1) * (bi + 2) / 2 <= tp) bi++;
                while (bi * (bi + 1) / 2 > tp) bi--;
                int bj = tp - bi * (bi + 1) / 2;
                int i0 = c0 + 32 + bi * 4, j0 = c0 + 32 + bj * 4;
                float acc[4][4] = {};
                for (int k = 0; k < 32; k++) {
                    float a[4], b[4];
#pragma unroll
                    for (int q = 0; q < 4; q++) a[q] = Ap[(i0 + q) * (i0 + q + 1) / 2 + c0 + k];
#pragma unroll
                    for (int r = 0; r < 4; r++) b[r] = Ap[(j0 + r) * (j0 + r + 1) / 2 + c0 + k];
#pragma unroll
                    for (int q = 0; q < 4; q++)
#pragma unroll
                        for (int r = 0; r < 4; r++) acc[q][r] += a[q] * b[r];
                }
#pragma unroll
                for (int q = 0; q < 4; q++)
#pragma unroll
                    for (int r = 0; r < 4; r++) {
                        int gi = i0 + q, gj = j0 + r;
                        if (gj <= gi) Ap[gi * (gi + 1) / 2 + gj] -= acc[q][r];
                    }
            }
            __syncthreads();
        }
    }

    float* Dst = dst + (long)pair * spd;
    for (int e = t; e < M_ * M_; e += 256) {
        int i = e >> 7, j = e & 127;
        Dst[(long)i * lddst + j] = (j <= i) ? Ap[i * (i + 1) / 2 + j] : 0.f;
    }
}

// fused 128 triangular inverse of a lower-tri 128x128 (src ld ldsrc, per-pair sps)
// -> dst full 128x128 (zero upper), per-pair 16384, ld 128
__global__ __launch_bounds__(256) void k_trinv128(const float* __restrict__ src, long sps, int ldsrc,
                                                  float* __restrict__ Li) {
    int pair = blockIdx.x, t = threadIdx.x;
    long b1 = (long)pair * 16384;
    const float* S = src + (long)pair * sps;
    __shared__ float Ld[2][64][66], Wd[2][64][66], LB[64][66], Tt[64][66];
    for (int e = t; e < 8192; e += 256) {
        int g = e >> 12, i = (e >> 6) & 63, j = e & 63;
        Ld[g][i][j] = S[(long)(g * 64 + i) * ldsrc + g * 64 + j];
    }
    for (int e = t; e < 4096; e += 256) {
        int i = e >> 6, j = e & 63;
        LB[i][j] = S[(long)(64 + i) * ldsrc + j];
    }
    __syncthreads();
    if (t < 128) {
        int g = t >> 6, c = t & 63;
        for (int i = 0; i < 64; i++) {
            float acc = (i == c) ? 1.f : 0.f;
            for (int j = 0; j < i; j++) acc -= Ld[g][i][j] * Wd[g][j][c];
            Wd[g][i][c] = acc / Ld[g][i][i];
        }
    }
    __syncthreads();
    int ti = t >> 4, tj = t & 15;
    float acc[4][4] = {};
    for (int kk = 0; kk < 64; kk++) {
        float a[4], b[4];
#pragma unroll
        for (int q = 0; q < 4; q++) a[q] = LB[ti * 4 + q][kk];
#pragma unroll
        for (int r = 0; r < 4; r++) b[r] = Wd[0][kk][tj * 4 + r];
#pragma unroll
        for (int q = 0; q < 4; q++)
#pragma unroll
            for (int r = 0; r < 4; r++) acc[q][r] += a[q] * b[r];
    }
#pragma unroll
    for (int q = 0; q < 4; q++)
#pragma unroll
        for (int r = 0; r < 4; r++) Tt[ti * 4 + q][tj * 4 + r] = acc[q][r];
    __syncthreads();
    float xo[4][4] = {};
    for (int kk = 0; kk < 64; kk++) {
        float a[4], b[4];
#pragma unroll
        for (int q = 0; q < 4; q++) a[q] = Wd[1][ti * 4 + q][kk];
#pragma unroll
        for (int r = 0; r < 4; r++) b[r] = Tt[kk][tj * 4 + r];
#pragma unroll
        for (int q = 0; q < 4; q++)
#pragma unroll
            for (int r = 0; r < 4; r++) xo[q][r] -= a[q] * b[r];
    }
#pragma unroll
    for (int q = 0; q < 4; q++)
#pragma unroll
        for (int r = 0; r < 4; r++)
            Li[b1 + (long)(64 + ti * 4 + q) * 128 + tj * 4 + r] = xo[q][r];
    for (int e = t; e < 4096; e += 256) {
        int i = e >> 6, j = e & 63;
        Li[b1 + (long)i * 128 + j] = Wd[0][i][j];
        Li[b1 + (long)(64 + i) * 128 + 64 + j] = Wd[1][i][j];
        Li[b1 + (long)i * 128 + 64 + j] = 0.f;
    }
}

// merged A1/A3: y=0: A1 = Linv1 @ kuf(KUU2 TR); y=1: A3 = Linv1 @ L_old
__global__ __launch_bounds__(256) void k_a1a3(const float* __restrict__ Linv1,
                                              const float* __restrict__ KUU2,
                                              const float* __restrict__ L_old,
                                              float* __restrict__ A1, float* __restrict__ A3) {
    int pair = blockIdx.x, y = blockIdx.y, o = pair & 31;
    const float* Ap = Linv1 + (long)pair * 16384;
    const float* Bp = y ? (L_old + (long)o * 16384) : (KUU2 + (long)pair * 65536 + 128);
    int ldb = y ? 128 : 256;
    float* Cp = (y ? A3 : A1) + (long)pair * 16384;
    int t = threadIdx.x, tx = t & 15, ty = t >> 4;
    __shared__ float As[16][132], Bs[16][132];
    float acc[8][8] = {};
    for (int kt = 0; kt < M_; kt += 16) {
#pragma unroll
        for (int q = 0; q < 8; q++) {
            int e = q * 256 + t;
            int m = e >> 4, kk = e & 15;
            As[kk][m] = Ap[(long)m * 128 + kt + kk];
            int kk2 = e >> 7, n = e & 127;
            Bs[kk2][n] = Bp[(long)(kt + kk2) * ldb + n];
        }
        __syncthreads();
#pragma unroll
        for (int kk = 0; kk < 16; kk++) {
            float a[8], b[8];
#pragma unroll
            for (int q = 0; q < 8; q++) { a[q] = As[kk][ty + 16 * q]; b[q] = Bs[kk][tx + 16 * q]; }
#pragma unroll
            for (int q = 0; q < 8; q++)
#pragma unroll
                for (int r = 0; r < 8; r++) acc[q][r] += a[q] * b[r];
        }
        __syncthreads();
    }
#pragma unroll
    for (int q = 0; q < 8; q++)
#pragma unroll
        for (int r = 0; r < 8; r++)
            Cp[(long)(ty + 16 * q) * 128 + tx + 16 * r] = acc[q][r];
}

// merged BLW/Schur: y=0: BLW = A1^T @ A3; y=1: KUU2_BR -= A1^T @ A1
__global__ __launch_bounds__(256) void k_blwschur(const float* __restrict__ A1,
                                                  const float* __restrict__ A3,
                                                  float* __restrict__ BLW,
                                                  float* __restrict__ KUU2) {
    int pair = blockIdx.x, y = blockIdx.y;
    const float* Ap = A1 + (long)pair * 16384;
    const float* Bp = (y ? A1 : A3) + (long)pair * 16384;
    float* Cp;
    int ldc;
    if (y) { Cp = KUU2 + (long)pair * 65536 + 128L * 256 + 128; ldc = 256; }
    else   { Cp = BLW + (long)pair * 16384; ldc = 128; }
    int t = threadIdx.x, tx = t & 15, ty = t >> 4;
    __shared__ float As[16][132], Bs[16][132];
    float acc[8][8] = {};
    for (int kt = 0; kt < M_; kt += 16) {
#pragma unroll
        for (int q = 0; q < 8; q++) {
            int e = q * 256 + t;
            int kk = e >> 7, m = e & 127;
            As[kk][m] = Ap[(long)(kt + kk) * 128 + m];
            Bs[kk][m] = Bp[(long)(kt + kk) * 128 + m];
        }
        __syncthreads();
#pragma unroll
        for (int kk = 0; kk < 16; kk++) {
            float a[8], b[8];
#pragma unroll
            for (int q = 0; q < 8; q++) { a[q] = As[kk][ty + 16 * q]; b[q] = Bs[kk][tx + 16 * q]; }
#pragma unroll
            for (int q = 0; q < 8; q++)
#pragma unroll
                for (int r = 0; r < 8; r++) acc[q][r] += a[q] * b[r];
        }
        __syncthreads();
    }
#pragma unroll
    for (int q = 0; q < 8; q++)
#pragma unroll
        for (int r = 0; r < 8; r++) {
            long idx = (long)(ty + 16 * q) * ldc + tx + 16 * r;
            if (y) Cp[idx] -= acc[q][r];
            else Cp[idx] = acc[q][r];
        }
}

// a2 = Linv128 * m_old ; m_new = A1^T a2 + u_mean ; write m_joint
__global__ __launch_bounds__(128) void k_stage1vec(const float* __restrict__ Linv128,
                                                   const float* __restrict__ A1,
                                                   const float* __restrict__ m_old,
                                                   const float* __restrict__ u_mean,
                                                   float* __restrict__ MJ) {
    int pair = blockIdx.x, o = pair & 31, t = threadIdx.x;
    __shared__ float mo[128], a2[128];
    mo[t] = m_old[o * 128 + t];
    __syncthreads();
    const float* Lr = Linv128 + (long)pair * 16384 + (long)t * 128;
    float acc = 0.f;
    for (int j = 0; j <= t; j++) acc += Lr[j] * mo[j];
    a2[t] = acc;
    __syncthreads();
    float m = 0.f;
    for (int i = 0; i < 128; i++) m += A1[(long)pair * 16384 + (long)i * 128 + t] * a2[i];
    MJ[pair * 256 + t] = mo[t];
    MJ[pair * 256 + 128 + t] = m + u_mean[o * 128 + t];
}

// generic batched fp32 SGEMM
template <int TA, int TB>
__global__ __launch_bounds__(256) void k_bmm(const float* __restrict__ A, long aSH, long aSO, int lda,
                                             const float* __restrict__ B, long bSH, long bSO, int ldb,
                                             float* __restrict__ C, long cSH, long cSO, int ldc,
                                             int Ksz, float alpha, int accum) {
    int pair = blockIdx.x;
    int h = pair >> 5, o = pair & 31;
    const float* Ap = A + (long)h * aSH + (long)o * aSO;
    const float* Bp = B + (long)h * bSH + (long)o * bSO;
    float* Cp = C + (long)h * cSH + (long)o * cSO;
    int t = threadIdx.x, tx = t & 15, ty = t >> 4;
    __shared__ float As[16][132], Bs[16][132];
    float acc[8][8] = {};
    for (int kt = 0; kt < Ksz; kt += 16) {
#pragma unroll
        for (int q = 0; q < 8; q++) {
            int e = q * 256 + t;
            if (TA) {
                int kk = e >> 7, m = e & 127;
                As[kk][m] = Ap[(long)(kt + kk) * lda + m];
            } else {
                int m = e >> 4, kk = e & 15;
                As[kk][m] = Ap[(long)m * lda + kt + kk];
            }
            if (TB) {
                int n = e >> 4, kk = e & 15;
                Bs[kk][n] = Bp[(long)n * ldb + kt + kk];
            } else {
                int kk = e >> 7, n = e & 127;
                Bs[kk][n] = Bp[(long)(kt + kk) * ldb + n];
            }
        }
        __syncthreads();
#pragma unroll
        for (int kk = 0; kk < 16; kk++) {
            float a[8], b[8];
#pragma unroll
            for (int q = 0; q < 8; q++) { a[q] = As[kk][ty + 16 * q]; b[q] = Bs[kk][tx + 16 * q]; }
#pragma unroll
            for (int q = 0; q < 8; q++)
#pragma unroll
                for (int r = 0; r < 8; r++) acc[q][r] += a[q] * b[r];
        }
        __syncthreads();
    }
#pragma unroll
    for (int q = 0; q < 8; q++)
#pragma unroll
        for (int r = 0; r < 8; r++) {
            long idx = (long)(ty + 16 * q) * ldc + tx + 16 * r;
            float v = alpha * acc[q][r];
            if (accum) v += Cp[idx];
            Cp[idx] = v;
        }
}

// assemble LINVT split planes from block pieces:
// LINVT[n][k] = LINV[k][n]; LINV = [[Linv1,0],[BLi,Linv2]]
__global__ __launch_bounds__(256) void k_lsplit(const float* __restrict__ Linv1,
                                                const float* __restrict__ BLi,
                                                const float* __restrict__ Linv2,
                                                ushort_t* __restrict__ Th,
                                                ushort_t* __restrict__ Tl) {
    int pair = blockIdx.x, t = threadIdx.x;
    long b2 = (long)pair * 65536, b1 = (long)pair * 16384;
    int tx = t & 31, ty = t >> 5;
    __shared__ float tile[32][33];
    // zeros: rows n>=128, cols k<128  (LINV upper block is zero)
    for (int e = t; e < 16384; e += 256) {
        int n = e >> 7, k = e & 127;
        long a = b2 + (long)(128 + n) * 256 + k;
        Th[a] = 0;
        Tl[a] = 0;
    }
    for (int part = 0; part < 3; part++) {
        const float* src = (part == 0) ? (Linv1 + b1) : (part == 1) ? (BLi + b1) : (Linv2 + b1);
        int nofs = (part == 2) ? 128 : 0;
        int kofs = (part == 0) ? 0 : 128;
        for (int bi = 0; bi < 4; bi++)
            for (int bj = 0; bj < 4; bj++) {
                __syncthreads();
                for (int r = ty; r < 32; r += 8)
                    tile[r][tx] = src[(long)(bi * 32 + r) * 128 + bj * 32 + tx];
                __syncthreads();
                for (int r = ty; r < 32; r += 8) {
                    ushort_t hb, lb;
                    splitbf(tile[tx][r], hb, lb);
                    long a = b2 + (long)(nofs + bj * 32 + r) * 256 + kofs + bi * 32 + tx;
                    Th[a] = hb;
                    Tl[a] = lb;
                }
            }
    }
}

// build WcT split planes: WcT[n][k] = Wc[k][n],
// Wc = [[L_old, 0],[BLW, UT]] (UT = unpacked u_tril)
__global__ __launch_bounds__(256) void k_wsplit(const float* __restrict__ L_old,
                                                const float* __restrict__ BLW,
                                                const float* __restrict__ vec,
                                                ushort_t* __restrict__ Th,
                                                ushort_t* __restrict__ Tl) {
    int pair = blockIdx.x, o = pair & 31, t = threadIdx.x;
    long b2 = (long)pair * 65536;
    __shared__ float vs[M_ * (M_ + 1) / 2];
    __shared__ float tile[32][33];
    for (int e = t; e < M_ * (M_ + 1) / 2; e += 256) vs[e] = vec[(long)o * (M_ * (M_ + 1) / 2) + e];
    __syncthreads();
    for (int e = t; e < 16384; e += 256) {
        int n = e >> 7, k = e & 127;
        float v = (k >= n) ? vs[k * (k + 1) / 2 + n] : 0.f;
        ushort_t hb, lb;
        splitbf(v, hb, lb);
        long a = b2 + (long)(128 + n) * 256 + 128 + k;
        Th[a] = hb;
        Tl[a] = lb;
    }
    for (int e = t; e < 16384; e += 256) {
        int n = e >> 7, k = e & 127;
        long a = b2 + (long)(128 + n) * 256 + k;
        Th[a] = 0;
        Tl[a] = 0;
    }
    for (int part = 0; part < 2; part++) {
        const float* src = part ? (BLW + (long)pair * 16384) : (L_old + (long)o * 16384);
        int cofs = part ? 128 : 0;
        for (int bi = 0; bi < 4; bi++)
            for (int bj = 0; bj < 4; bj++) {
                __syncthreads();
                for (int r = t >> 5; r < 32; r += 8)
                    tile[r][t & 31] = src[(long)(bi * 32 + r) * 128 + bj * 32 + (t & 31)];
                __syncthreads();
                for (int r = t >> 5; r < 32; r += 8) {
                    ushort_t hb, lb;
                    splitbf(tile[t & 31][r], hb, lb);
                    long a = b2 + (long)(bj * 32 + r) * 256 + cofs + bi * 32 + (t & 31);
                    Th[a] = hb;
                    Tl[a] = lb;
                }
            }
    }
}

// CV = AINV @ MJ (per-pair matvec)
__global__ __launch_bounds__(256) void k_mv(const float* __restrict__ AINV,
                                            const float* __restrict__ MJ,
                                            float* __restrict__ CV) {
    int pair = blockIdx.x, t = threadIdx.x;
    __shared__ float mj[256];
    mj[t] = MJ[pair * 256 + t];
    __syncthreads();
    const float4* row = (const float4*)(AINV + (long)pair * 65536 + (long)t * 256);
    float acc = 0.f;
#pragma unroll 8
    for (int k4 = 0; k4 < 64; k4++) {
        float4 v = row[k4];
        acc += v.x * mj[k4 * 4] + v.y * mj[k4 * 4 + 1] + v.z * mj[k4 * 4 + 2] + v.w * mj[k4 * 4 + 3];
    }
    CV[pair * 256 + t] = acc;
}

// split-bf16 MFMA batched GEMM: C = alpha*(Ah+Al)(Bh+Bl)^T [+ Dm]
#define BSTR 56
template <int TILES3>
__global__ __launch_bounds__(256) void k_bmmx(const ushort_t* __restrict__ Ah,
                                              const ushort_t* __restrict__ Al,
                                              const ushort_t* __restrict__ Bh,
                                              const ushort_t* __restrict__ Bl,
                                              float* __restrict__ Cf,
                                              ushort_t* __restrict__ Chi,
                                              ushort_t* __restrict__ Clo,
                                              const float* __restrict__ Dm,
                                              int kLoMode, float alpha) {
    int pair = blockIdx.x;
    long base = (long)pair * 65536;
    int I0, J0, mir = 0;
    if (TILES3) {
        int qb = blockIdx.y;
        I0 = (qb == 0) ? 0 : 128;
        J0 = (qb == 2) ? 0 : I0;
        mir = (qb == 2);
    } else {
        I0 = (blockIdx.y >> 1) * 128;
        J0 = (blockIdx.y & 1) * 128;
    }
    int k0 = (kLoMode == 1) ? max(I0, J0) : (kLoMode == 2) ? J0 : 0;
    int t = threadIdx.x;
    int w = t >> 6, lane = t & 63;
    int l31 = lane & 31, lhalf = lane >> 5;
    int wy = w >> 1, wx = w & 1;

    __shared__ __align__(16) ushort_t AsH[128][BSTR], AsL[128][BSTR];
    __shared__ __align__(16) ushort_t BsH[128][BSTR], BsL[128][BSTR];

    v16f acc[2][2];
#pragma unroll
    for (int mt = 0; mt < 2; mt++)
#pragma unroll
        for (int nt = 0; nt < 2; nt++)
#pragma unroll
            for (int r = 0; r < 16; r++) acc[mt][nt][r] = 0.f;

    for (int kt = k0; kt < 256; kt += 32) {
        __syncthreads();
#pragma unroll
        for (int u = 0; u < 2; u++) {
            int idx = u * 256 + t;
            int m = idx >> 2, kc = (idx & 3) * 8;
            long arow = base + (long)(I0 + m) * 256 + kt + kc;
            long brow = base + (long)(J0 + m) * 256 + kt + kc;
            *(v8us*)&AsH[m][kc] = *(const v8us*)(Ah + arow);
            *(v8us*)&AsL[m][kc] = *(const v8us*)(Al + arow);
            *(v8us*)&BsH[m][kc] = *(const v8us*)(Bh + brow);
            *(v8us*)&BsL[m][kc] = *(const v8us*)(Bl + brow);
        }
        __syncthreads();
#pragma unroll
        for (int ks = 0; ks < 2; ks++) {
            int ko = ks * 16 + lhalf * 8;
            v8bf ah[2], al[2], bh[2], bl[2];
#pragma unroll
            for (int mt = 0; mt < 2; mt++) {
                int r = wy * 64 + mt * 32 + l31;
                ah[mt] = *(const v8bf*)&AsH[r][ko];
                al[mt] = *(const v8bf*)&AsL[r][ko];
            }
#pragma unroll
            for (int nt = 0; nt < 2; nt++) {
                int r = wx * 64 + nt * 32 + l31;
                bh[nt] = *(const v8bf*)&BsH[r][ko];
                bl[nt] = *(const v8bf*)&BsL[r][ko];
            }
#pragma unroll
            for (int mt = 0; mt < 2; mt++)
#pragma unroll
                for (int nt = 0; nt < 2; nt++) {
                    acc[mt][nt] = __builtin_amdgcn_mfma_f32_32x32x16_bf16(ah[mt], bh[nt], acc[mt][nt], 0, 0, 0);
                    acc[mt][nt] = __builtin_amdgcn_mfma_f32_32x32x16_bf16(ah[mt], bl[nt], acc[mt][nt], 0, 0, 0);
                    acc[mt][nt] = __builtin_amdgcn_mfma_f32_32x32x16_bf16(al[mt], bh[nt], acc[mt][nt], 0, 0, 0);
                }
        }
    }

#pragma unroll
    for (int mt = 0; mt < 2; mt++)
#pragma unroll
        for (int nt = 0; nt < 2; nt++) {
#pragma unroll
            for (int r = 0; r < 16; r++) {
                int row = I0 + wy * 64 + mt * 32 + 8 * (r >> 2) + 4 * lhalf + (r & 3);
                int col = J0 + wx * 64 + nt * 32 + l31;
                long idx = base + (long)row * 256 + col;
                float v = alpha * acc[mt][nt][r];
                if (Dm) v += Dm[idx];
                ushort_t hb, lb;
                splitbf(v, hb, lb);
                if (Cf) Cf[idx] = v;
                if (Chi) { Chi[idx] = hb; Clo[idx] = lb; }
                if (mir) {
                    long idxT = base + (long)col * 256 + row;
                    if (Cf) Cf[idxT] = v;
                    if (Chi) { Chi[idxT] = hb; Clo[idxT] = lb; }
                }
            }
        }
}

// fused final kernel (MFMA); 1D grid: pair = idx&127 (XCD-local G reuse), bt = idx>>7
#define KTP 280
__global__ __launch_bounds__(256) void k_kb3(const float* __restrict__ ZS, const float* __restrict__ ZN,
                                             const float* __restrict__ XS, const float* __restrict__ XN,
                                             const float* __restrict__ SF2,
                                             const ushort_t* __restrict__ Ghi,
                                             const ushort_t* __restrict__ Glo,
                                             const float* __restrict__ CV, float* __restrict__ out) {
    int pair = blockIdx.x & 127;
    int bt = blockIdx.x >> 7;
    int h = pair >> 5;
    int t = threadIdx.x;
    int w = t >> 6;
    int lane = t & 63;
    int l31 = lane & 31, lhalf = lane >> 5;

    __shared__ __align__(16) ushort_t KbT[64][KTP];
    __shared__ float qpart[4][64];
    __shared__ float mup[4][64];

    float sf2 = SF2[h];
    {
        int b = t & 63;
        long bg = (long)h * B_ + bt * 64 + b;
        const float4* xrow = (const float4*)(XS + bg * 16);
        float4 x0 = xrow[0], x1 = xrow[1], x2 = xrow[2], x3 = xrow[3];
        float xn = XN[bg];
        float mupart = 0.f;
        const float* cvp = CV + pair * 256;
        const float* znp = ZN + pair * 256;
#pragma unroll 2
        for (int j8 = 0; j8 < 8; j8++) {
            v8us kb8;
#pragma unroll
            for (int e = 0; e < 8; e++) {
                int j = w * 64 + j8 * 8 + e;
                const float4* zrow = (const float4*)(ZS + ((long)pair * 256 + j) * 16);
                float4 z0 = zrow[0], z1 = zrow[1], z2 = zrow[2], z3 = zrow[3];
                float dot = z0.x * x0.x + z0.y * x0.y + z0.z * x0.z + z0.w * x0.w +
                            z1.x * x1.x + z1.y * x1.y + z1.z * x1.z + z1.w * x1.w +
                            z2.x * x2.x + z2.y * x2.y + z2.z * x2.z + z2.w * x2.w +
                            z3.x * x3.x + z3.y * x3.y + z3.z * x3.z + z3.w * x3.w;
                float d2 = fmaxf(znp[j] + xn - 2.f * dot, 0.f);
                float kv = sf2 * __expf(-0.5f * d2);
                mupart += cvp[j] * kv;
                unsigned int u = __float_as_uint(kv);
                u += 0x7fffu + ((u >> 16) & 1u);
                kb8[e] = (unsigned short)(u >> 16);
            }
            *(v8us*)&KbT[b][w * 64 + j8 * 8] = kb8;
        }
        mup[w][b] = mupart;
    }
    __syncthreads();

    v16f acc[2][2];
#pragma unroll
    for (int mt = 0; mt < 2; mt++)
#pragma unroll
        for (int nt = 0; nt < 2; nt++)
#pragma unroll
            for (int r = 0; r < 16; r++) acc[mt][nt][r] = 0.f;

    const ushort_t* GhiP = Ghi + (long)pair * 65536;
    const ushort_t* GloP = Glo + (long)pair * 65536;
    for (int k0 = 0; k0 < 256; k0 += 16) {
        v8bf bfr[2];
#pragma unroll
        for (int nt = 0; nt < 2; nt++)
            bfr[nt] = *(const v8bf*)&KbT[nt * 32 + l31][k0 + lhalf * 8];
#pragma unroll
        for (int mt = 0; mt < 2; mt++) {
            int i = w * 64 + mt * 32 + l31;
            v8bf ah = *(const v8bf*)(GhiP + (long)i * 256 + k0 + lhalf * 8);
            v8bf al = *(const v8bf*)(GloP + (long)i * 256 + k0 + lhalf * 8);
#pragma unroll
            for (int nt = 0; nt < 2; nt++) {
                acc[mt][nt] = __builtin_amdgcn_mfma_f32_32x32x16_bf16(ah, bfr[nt], acc[mt][nt], 0, 0, 0);
                acc[mt][nt] = __builtin_amdgcn_mfma_f32_32x32x16_bf16(al, bfr[nt], acc[mt][nt], 0, 0, 0);
            }
        }
    }

    float qp[2] = {0.f, 0.f};
#pragma unroll
    for (int mt = 0; mt < 2; mt++) {
#pragma unroll
        for (int nt = 0; nt < 2; nt++) {
            int b = nt * 32 + l31;
#pragma unroll
            for (int g = 0; g < 4; g++) {
                int ibase = w * 64 + mt * 32 + 8 * g + 4 * lhalf;
                v4us k4 = *(const v4us*)&KbT[b][ibase];
#pragma unroll
                for (int e = 0; e < 4; e++) {
                    float kv = bf2f(k4[e]);
                    qp[nt] += kv * acc[mt][nt][4 * g + e];
                }
            }
        }
    }
#pragma unroll
    for (int nt = 0; nt < 2; nt++) {
        qp[nt] += __shfl_down(qp[nt], 32, 64);
        if (lhalf == 0) qpart[w][nt * 32 + l31] = qp[nt];
    }
    __syncthreads();

    if (t < 64) {
        float mu = mup[0][t] + mup[1][t] + mup[2][t] + mup[3][t];
        float q = qpart[0][t] + qpart[1][t] + qpart[2][t] + qpart[3][t];
        long ob = (long)pair * 1024 + bt * 64 + t;
        out[ob] = mu;
        out[(long)H_ * O_ * B_ + ob] = sf2 - q;
    }
}

// ---------------------------------------------------------------------------
extern "C" void kernel_launch(void* const* d_in, const int* in_sizes, int n_in,
                              void* d_out, int out_size, void* d_ws, size_t ws_size,
                              hipStream_t stream) {
    const float* x = (const float*)d_in[0];
    const float* z = (const float*)d_in[1];
    const float* u_mean = (const float*)d_in[2];
    const float* u_tril_vec = (const float*)d_in[3];
    const float* m_old = (const float*)d_in[4];
    const float* L_old = (const float*)d_in[5];
    const float* z_old = (const float*)d_in[6];
    const float* theta = (const float*)d_in[7];

    const long BIGSZ = (long)HO * M2 * M2;  // 8388608
    const long MSZ = (long)HO * M_ * M_;    // 2097152
    const long SH1 = (long)O_ * M_ * M_;
    const long SO1 = (long)M_ * M_;
    const long SO2 = (long)M2 * M2;

    float* ws = (float*)d_ws;
    long off = 0;
    float* BIG0 = ws + off; off += BIGSZ;  // KUU2 -> AINV fp32
    float* BIG1 = ws + off; off += BIGSZ;  // LINVT h/l -> Y h/l
    float* BIG2 = ws + off; off += BIGSZ;  // Linv1|A1|Linv2|BLW -> AINV h/l
    float* BIG3 = ws + off; off += BIGSZ;  // L256 -> T1/BLi -> WcT h/l -> G h/l
    float* ZS = ws + off; off += (long)HO * M2 * D_;
    float* XS = ws + off; off += (long)H_ * B_ * D_;
    float* ZN = ws + off; off += (long)HO * M2;
    float* XN = ws + off; off += (long)H_ * B_;
    float* MJ = ws + off; off += (long)HO * M2;
    float* CV = ws + off; off += (long)HO * M2;
    float* SF2v = ws + off; off += H_;

    float* KUU2 = BIG0;
    float* AINV = BIG0;
    float* Linv1 = BIG2;              // slot 0 (alive until lsplit)
    float* A1 = BIG2 + MSZ;           // slot 1 (alive until T1)
    float* A3 = BIG2 + 2 * MSZ;       // slot 2 (dead after blwschur)
    float* Linv2 = BIG2 + 2 * MSZ;    // reuse slot 2
    float* BLW = BIG2 + 3 * MSZ;      // slot 3 (alive until wsplit)
    float* L256 = BIG3;
    float* T1 = BIG3;                 // after L256 dead
    float* BLi = BIG3 + MSZ;
    ushort_t* LINVTh = (ushort_t*)BIG1;
    ushort_t* LINVTl = LINVTh + BIGSZ;
    ushort_t* AINVh = (ushort_t*)BIG2;
    ushort_t* AINVl = AINVh + BIGSZ;
    ushort_t* WcTh = (ushort_t*)BIG3;
    ushort_t* WcTl = WcTh + BIGSZ;
    ushort_t* Yh = (ushort_t*)BIG1;
    ushort_t* Yl = Yh + BIGSZ;
    ushort_t* Ghi = (ushort_t*)BIG3;
    ushort_t* Glo = Ghi + BIGSZ;
    const long BRoff = 128L * M2 + 128;

    // 1. preprocessing
    k_pre<<<145, 256, 0, stream>>>(theta, x, z, z_old, SF2v, XS, XN, ZS, ZN);
    // 2. kuu2
    k_kuu2<<<HO, 256, 0, stream>>>(ZS, ZN, SF2v, KUU2);
    // 3. chol TL -> L256 TL
    k_chol128<<<HO, 256, 0, stream>>>(KUU2, SO2, M2, L256, SO2, M2);
    // 4. Linv1
    k_trinv128<<<HO, 256, 0, stream>>>(L256, SO2, M2, Linv1);
    // 5. A1 = Linv1@kuf ; A3 = Linv1@L_old (merged)
    k_a1a3<<<dim3(HO, 2), 256, 0, stream>>>(Linv1, KUU2, L_old, A1, A3);
    // 6. m_joint
    k_stage1vec<<<HO, 128, 0, stream>>>(Linv1, A1, m_old, u_mean, MJ);
    // 7. BLW = A1^T A3 ; KUU2_BR -= A1^T A1 (merged)
    k_blwschur<<<dim3(HO, 2), 256, 0, stream>>>(A1, A3, BLW, KUU2);
    // 8. chol BR -> L256 BR
    k_chol128<<<HO, 256, 0, stream>>>(KUU2 + BRoff, SO2, M2, L256 + BRoff, SO2, M2);
    // 9. Linv2 (overwrites A3 slot)
    k_trinv128<<<HO, 256, 0, stream>>>(L256 + BRoff, SO2, M2, Linv2);
    // 10. T1 = A1^T @ Linv1 (L256 dead -> BIG3)
    k_bmm<1, 0><<<HO, 256, 0, stream>>>(A1, SH1, SO1, M_, Linv1, SH1, SO1, M_,
                                        T1, SH1, SO1, M_, M_, 1.f, 0);
    // 11. BLi = -Linv2 @ T1
    k_bmm<0, 0><<<HO, 256, 0, stream>>>(Linv2, SH1, SO1, M_, T1, SH1, SO1, M_,
                                        BLi, SH1, SO1, M_, M_, -1.f, 0);
    // 12. LINVT planes from (Linv1, BLi, Linv2)
    k_lsplit<<<HO, 256, 0, stream>>>(Linv1, BLi, Linv2, LINVTh, LINVTl);
    // 13. WcT planes (T1/BLi dead -> BIG3)
    k_wsplit<<<HO, 256, 0, stream>>>(L_old, BLW, u_tril_vec, WcTh, WcTl);
    // 14. AINV = LINVT (.) LINVT -> fp32 (BIG0) + planes (BIG2; all fp32 dead)
    k_bmmx<1><<<dim3(HO, 3), 256, 0, stream>>>(LINVTh, LINVTl, LINVTh, LINVTl,
                                               AINV, AINVh, AINVl, nullptr, 1, 1.f);
    // 15. CV = AINV @ MJ
    k_mv<<<HO, 256, 0, stream>>>(AINV, MJ, CV);
    // 16. Y = AINV @ Wc -> Y planes (BIG1; LINVT dead)
    k_bmmx<0><<<dim3(HO, 4), 256, 0, stream>>>(AINVh, AINVl, WcTh, WcTl,
                                               nullptr, Yh, Yl, nullptr, 2, 1.f);
    // 17. G = AINV - Y Y^T -> G planes (BIG3; WcT dead)
    k_bmmx<1><<<dim3(HO, 3), 256, 0, stream>>>(Yh, Yl, Yh, Yl,
                                               nullptr, Ghi, Glo, AINV, 0, -1.f);
    // 18. fused predict
    k_kb3<<<2048, 256, 0, stream>>>(ZS, ZN, XS, XN, SF2v, Ghi, Glo, CV, (float*)d_out);
}

// Round 9
// 791.933 us; speedup vs baseline: 1.3676x; 1.1452x over previous
//
#include <hip/hip_runtime.h>

#define H_ 4
#define O_ 32
#define HO 128
#define M_ 128
#define M2 256
#define D_ 16
#define B_ 1024
#define JIT 1e-4f

typedef unsigned short ushort_t;
typedef __bf16 v8bf __attribute__((ext_vector_type(8)));
typedef float v16f __attribute__((ext_vector_type(16)));
typedef unsigned short v8us __attribute__((ext_vector_type(8)));
typedef unsigned short v4us __attribute__((ext_vector_type(4)));

__device__ inline void splitbf(float v, ushort_t& hb, ushort_t& lb) {
    unsigned int u = __float_as_uint(v);
    hb = (ushort_t)(u >> 16);
    float hf = __uint_as_float((unsigned int)hb << 16);
    float r = v - hf;
    lb = (ushort_t)(__float_as_uint(r) >> 16);
}
__device__ inline float bf2f(ushort_t u) { return __uint_as_float((unsigned int)u << 16); }

// ---------------------------------------------------------------------------
// merged preprocessing
__global__ __launch_bounds__(256) void k_pre(const float* __restrict__ theta,
                                             const float* __restrict__ x,
                                             const float* __restrict__ z,
                                             const float* __restrict__ z_old,
                                             float* __restrict__ SF2,
                                             float* __restrict__ XS, float* __restrict__ XN,
                                             float* __restrict__ ZS, float* __restrict__ ZN) {
    int bb = blockIdx.x, t = threadIdx.x;
    if (bb == 144) {
        if (t < H_) SF2[t] = __expf(theta[t * (D_ + 1)]);
        return;
    }
    __shared__ float ls[D_];
    if (bb < 128) {
        int pair = bb, h = pair >> 5, o = pair & 31, i = t;
        if (t < D_) ls[t] = __expf(-theta[h * (D_ + 1) + 1 + t]);
        __syncthreads();
        const float* src = (i < M_) ? (z_old + ((long)o * M_ + i) * D_)
                                    : (z + ((long)o * M_ + (i - M_)) * D_);
        float s = 0.f;
#pragma unroll
        for (int d = 0; d < D_; d++) {
            float v = src[d] * ls[d];
            ZS[((long)pair * M2 + i) * D_ + d] = v;
            s += v * v;
        }
        ZN[pair * M2 + i] = s;
    } else {
        int j = (bb - 128) * 256 + t;
        int h = j >> 10, b = j & 1023;
        if (t < D_) ls[t] = __expf(-theta[h * (D_ + 1) + 1 + t]);
        __syncthreads();
        float s = 0.f;
#pragma unroll
        for (int d = 0; d < D_; d++) {
            float v = x[b * D_ + d] * ls[d];
            XS[(long)j * D_ + d] = v;
            s += v * v;
        }
        XN[j] = s;
    }
}

// kuu2 = k_rbf(z_joint, z_joint) + JIT*I   [HO][256][256]
__global__ __launch_bounds__(256) void k_kuu2(const float* __restrict__ ZS,
                                              const float* __restrict__ ZN,
                                              const float* __restrict__ SF2,
                                              float* __restrict__ K2) {
    int pair = blockIdx.x;
    int h = pair >> 5;
    int t = threadIdx.x;
    __shared__ float zs[M2][D_];
    __shared__ float zn[M2];
    for (int e = t; e < M2 * D_; e += 256) zs[e / D_][e % D_] = ZS[(long)pair * M2 * D_ + e];
    zn[t] = ZN[pair * M2 + t];
    __syncthreads();
    float sf2 = SF2[h];
    float my[D_];
#pragma unroll
    for (int d = 0; d < D_; d++) my[d] = zs[t][d];
    float myn = zn[t];
    for (int q = 0; q < M2; q++) {
        float dot = 0.f;
#pragma unroll
        for (int d = 0; d < D_; d++) dot += zs[q][d] * my[d];
        float d2 = fmaxf(zn[q] + myn - 2.f * dot, 0.f);
        float v = sf2 * __expf(-0.5f * d2);
        if (q == t) v += JIT;
        K2[(long)pair * M2 * M2 + (long)q * M2 + t] = v;
    }
}

// blocked (BK=32) in-LDS Cholesky of a 128x128 block, 256 threads.
__global__ __launch_bounds__(256) void k_chol128(const float* __restrict__ src, long sps, int ldsrc,
                                                 float* __restrict__ dst, long spd, int lddst) {
    int pair = blockIdx.x, t = threadIdx.x;
    __shared__ float Ap[M_ * (M_ + 1) / 2];
    __shared__ float rsq[32];
    const float* S = src + (long)pair * sps;
    for (int e = t; e < M_ * (M_ + 1) / 2; e += 256) {
        int i = (int)((sqrtf(8.f * e + 1.f) - 1.f) * 0.5f);
        while ((i + 1) * (i + 2) / 2 <= e) i++;
        while (i * (i + 1) / 2 > e) i--;
        int j = e - i * (i + 1) / 2;
        Ap[e] = S[(long)i * ldsrc + j];
    }
    int pi[3], pj[3];
#pragma unroll
    for (int u = 0; u < 3; u++) {
        int p = t + u * 256;
        if (p < 528) {
            int i = (int)((sqrtf(8.f * p + 1.f) - 1.f) * 0.5f);
            while ((i + 1) * (i + 2) / 2 <= p) i++;
            while (i * (i + 1) / 2 > p) i--;
            pi[u] = i;
            pj[u] = p - i * (i + 1) / 2;
        } else {
            pi[u] = -1;
            pj[u] = 0;
        }
    }
    __syncthreads();

    for (int kb = 0; kb < 4; kb++) {
        int c0 = kb * 32;
        for (int k = 0; k < 32; k++) {
            int kc = c0 + k;
            float rd = 1.f / Ap[kc * (kc + 1) / 2 + kc];
#pragma unroll
            for (int u = 0; u < 3; u++) {
                int i = pi[u], j = pj[u];
                if (i > k && j > k) {
                    int gi = c0 + i, gj = c0 + j;
                    Ap[gi * (gi + 1) / 2 + gj] -=
                        Ap[gi * (gi + 1) / 2 + kc] * Ap[gj * (gj + 1) / 2 + kc] * rd;
                }
            }
            __syncthreads();
        }
        if (t < 32) {
            int g = c0 + t;
            rsq[t] = rsqrtf(Ap[g * (g + 1) / 2 + g]);
        }
        __syncthreads();
#pragma unroll
        for (int u = 0; u < 3; u++) {
            int i = pi[u], j = pj[u];
            if (i >= 0) {
                int gi = c0 + i, gj = c0 + j;
                Ap[gi * (gi + 1) / 2 + gj] *= rsq[j];
            }
        }
        __syncthreads();

        int R = M_ - c0 - 32;
        if (R > 0) {
            if (t < R) {
                int gi = c0 + 32 + t;
                int base = gi * (gi + 1) / 2 + c0;
                float xr[32];
#pragma unroll
                for (int j = 0; j < 32; j++) xr[j] = Ap[base + j];
#pragma unroll
                for (int q = 0; q < 32; q++) {
                    float xq = xr[q] * rsq[q];
                    xr[q] = xq;
#pragma unroll
                    for (int j = q + 1; j < 32; j++)
                        xr[j] -= xq * Ap[(c0 + j) * (c0 + j + 1) / 2 + c0 + q];
                }
#pragma unroll
                for (int j = 0; j < 32; j++) Ap[base + j] = xr[j];
            }
            __syncthreads();
            int nb = R >> 2;
            int ntile = nb * (nb + 1) / 2;
            for (int tp = t; tp < ntile; tp += 256) {
                int bi = (int)((sqrtf(8.f * tp + 1.f) - 1.f) * 0.5f);
                while ((bi + 1) * (bi + 2) / 2 <= tp) bi++;
                while (bi * (bi + 1) / 2 > tp) bi--;
                int bj = tp - bi * (bi + 1) / 2;
                int i0 = c0 + 32 + bi * 4, j0 = c0 + 32 + bj * 4;
                float acc[4][4] = {};
                for (int k = 0; k < 32; k++) {
                    float a[4], b[4];
#pragma unroll
                    for (int q = 0; q < 4; q++) a[q] = Ap[(i0 + q) * (i0 + q + 1) / 2 + c0 + k];
#pragma unroll
                    for (int r = 0; r < 4; r++) b[r] = Ap[(j0 + r) * (j0 + r + 1) / 2 + c0 + k];
#pragma unroll
                    for (int q = 0; q < 4; q++)
#pragma unroll
                        for (int r = 0; r < 4; r++) acc[q][r] += a[q] * b[r];
                }
#pragma unroll
                for (int q = 0; q < 4; q++)
#pragma unroll
                    for (int r = 0; r < 4; r++) {
                        int gi = i0 + q, gj = j0 + r;
                        if (gj <= gi) Ap[gi * (gi + 1) / 2 + gj] -= acc[q][r];
                    }
            }
            __syncthreads();
        }
    }

    float* Dst = dst + (long)pair * spd;
    for (int e = t; e < M_ * M_; e += 256) {
        int i = e >> 7, j = e & 127;
        Dst[(long)i * lddst + j] = (j <= i) ? Ap[i * (i + 1) / 2 + j] : 0.f;
    }
}

// fused 128 triangular inverse of a lower-tri 128x128
__global__ __launch_bounds__(256) void k_trinv128(const float* __restrict__ src, long sps, int ldsrc,
                                                  float* __restrict__ Li) {
    int pair = blockIdx.x, t = threadIdx.x;
    long b1 = (long)pair * 16384;
    const float* S = src + (long)pair * sps;
    __shared__ float Ld[2][64][66], Wd[2][64][66], LB[64][66], Tt[64][66];
    for (int e = t; e < 8192; e += 256) {
        int g = e >> 12, i = (e >> 6) & 63, j = e & 63;
        Ld[g][i][j] = S[(long)(g * 64 + i) * ldsrc + g * 64 + j];
    }
    for (int e = t; e < 4096; e += 256) {
        int i = e >> 6, j = e & 63;
        LB[i][j] = S[(long)(64 + i) * ldsrc + j];
    }
    __syncthreads();
    if (t < 128) {
        int g = t >> 6, c = t & 63;
        for (int i = 0; i < 64; i++) {
            float acc = (i == c) ? 1.f : 0.f;
            for (int j = 0; j < i; j++) acc -= Ld[g][i][j] * Wd[g][j][c];
            Wd[g][i][c] = acc / Ld[g][i][i];
        }
    }
    __syncthreads();
    int ti = t >> 4, tj = t & 15;
    float acc[4][4] = {};
    for (int kk = 0; kk < 64; kk++) {
        float a[4], b[4];
#pragma unroll
        for (int q = 0; q < 4; q++) a[q] = LB[ti * 4 + q][kk];
#pragma unroll
        for (int r = 0; r < 4; r++) b[r] = Wd[0][kk][tj * 4 + r];
#pragma unroll
        for (int q = 0; q < 4; q++)
#pragma unroll
            for (int r = 0; r < 4; r++) acc[q][r] += a[q] * b[r];
    }
#pragma unroll
    for (int q = 0; q < 4; q++)
#pragma unroll
        for (int r = 0; r < 4; r++) Tt[ti * 4 + q][tj * 4 + r] = acc[q][r];
    __syncthreads();
    float xo[4][4] = {};
    for (int kk = 0; kk < 64; kk++) {
        float a[4], b[4];
#pragma unroll
        for (int q = 0; q < 4; q++) a[q] = Wd[1][ti * 4 + q][kk];
#pragma unroll
        for (int r = 0; r < 4; r++) b[r] = Tt[kk][tj * 4 + r];
#pragma unroll
        for (int q = 0; q < 4; q++)
#pragma unroll
            for (int r = 0; r < 4; r++) xo[q][r] -= a[q] * b[r];
    }
#pragma unroll
    for (int q = 0; q < 4; q++)
#pragma unroll
        for (int r = 0; r < 4; r++)
            Li[b1 + (long)(64 + ti * 4 + q) * 128 + tj * 4 + r] = xo[q][r];
    for (int e = t; e < 4096; e += 256) {
        int i = e >> 6, j = e & 63;
        Li[b1 + (long)i * 128 + j] = Wd[0][i][j];
        Li[b1 + (long)(64 + i) * 128 + 64 + j] = Wd[1][i][j];
        Li[b1 + (long)i * 128 + 64 + j] = 0.f;
    }
}

// merged A1/A3: y=0: A1 = Linv1 @ kuf(KUU2 TR); y=1: A3 = Linv1 @ L_old
__global__ __launch_bounds__(256) void k_a1a3(const float* __restrict__ Linv1,
                                              const float* __restrict__ KUU2,
                                              const float* __restrict__ L_old,
                                              float* __restrict__ A1, float* __restrict__ A3) {
    int pair = blockIdx.x, y = blockIdx.y, o = pair & 31;
    const float* Ap = Linv1 + (long)pair * 16384;
    const float* Bp = y ? (L_old + (long)o * 16384) : (KUU2 + (long)pair * 65536 + 128);
    int ldb = y ? 128 : 256;
    float* Cp = (y ? A3 : A1) + (long)pair * 16384;
    int t = threadIdx.x, tx = t & 15, ty = t >> 4;
    __shared__ float As[16][132], Bs[16][132];
    float acc[8][8] = {};
    for (int kt = 0; kt < M_; kt += 16) {
#pragma unroll
        for (int q = 0; q < 8; q++) {
            int e = q * 256 + t;
            int m = e >> 4, kk = e & 15;
            As[kk][m] = Ap[(long)m * 128 + kt + kk];
            int kk2 = e >> 7, n = e & 127;
            Bs[kk2][n] = Bp[(long)(kt + kk2) * ldb + n];
        }
        __syncthreads();
#pragma unroll
        for (int kk = 0; kk < 16; kk++) {
            float a[8], b[8];
#pragma unroll
            for (int q = 0; q < 8; q++) { a[q] = As[kk][ty + 16 * q]; b[q] = Bs[kk][tx + 16 * q]; }
#pragma unroll
            for (int q = 0; q < 8; q++)
#pragma unroll
                for (int r = 0; r < 8; r++) acc[q][r] += a[q] * b[r];
        }
        __syncthreads();
    }
#pragma unroll
    for (int q = 0; q < 8; q++)
#pragma unroll
        for (int r = 0; r < 8; r++)
            Cp[(long)(ty + 16 * q) * 128 + tx + 16 * r] = acc[q][r];
}

// merged BLW/Schur: y=0: BLW = A1^T @ A3; y=1: KUU2_BR -= A1^T @ A1
__global__ __launch_bounds__(256) void k_blwschur(const float* __restrict__ A1,
                                                  const float* __restrict__ A3,
                                                  float* __restrict__ BLW,
                                                  float* __restrict__ KUU2) {
    int pair = blockIdx.x, y = blockIdx.y;
    const float* Ap = A1 + (long)pair * 16384;
    const float* Bp = (y ? A1 : A3) + (long)pair * 16384;
    float* Cp;
    int ldc;
    if (y) { Cp = KUU2 + (long)pair * 65536 + 128L * 256 + 128; ldc = 256; }
    else   { Cp = BLW + (long)pair * 16384; ldc = 128; }
    int t = threadIdx.x, tx = t & 15, ty = t >> 4;
    __shared__ float As[16][132], Bs[16][132];
    float acc[8][8] = {};
    for (int kt = 0; kt < M_; kt += 16) {
#pragma unroll
        for (int q = 0; q < 8; q++) {
            int e = q * 256 + t;
            int kk = e >> 7, m = e & 127;
            As[kk][m] = Ap[(long)(kt + kk) * 128 + m];
            Bs[kk][m] = Bp[(long)(kt + kk) * 128 + m];
        }
        __syncthreads();
#pragma unroll
        for (int kk = 0; kk < 16; kk++) {
            float a[8], b[8];
#pragma unroll
            for (int q = 0; q < 8; q++) { a[q] = As[kk][ty + 16 * q]; b[q] = Bs[kk][tx + 16 * q]; }
#pragma unroll
            for (int q = 0; q < 8; q++)
#pragma unroll
                for (int r = 0; r < 8; r++) acc[q][r] += a[q] * b[r];
        }
        __syncthreads();
    }
#pragma unroll
    for (int q = 0; q < 8; q++)
#pragma unroll
        for (int r = 0; r < 8; r++) {
            long idx = (long)(ty + 16 * q) * ldc + tx + 16 * r;
            if (y) Cp[idx] -= acc[q][r];
            else Cp[idx] = acc[q][r];
        }
}

// a2 = Linv128 * m_old ; m_new = A1^T a2 + u_mean ; write m_joint
__global__ __launch_bounds__(128) void k_stage1vec(const float* __restrict__ Linv128,
                                                   const float* __restrict__ A1,
                                                   const float* __restrict__ m_old,
                                                   const float* __restrict__ u_mean,
                                                   float* __restrict__ MJ) {
    int pair = blockIdx.x, o = pair & 31, t = threadIdx.x;
    __shared__ float mo[128], a2[128];
    mo[t] = m_old[o * 128 + t];
    __syncthreads();
    const float* Lr = Linv128 + (long)pair * 16384 + (long)t * 128;
    float acc = 0.f;
    for (int j = 0; j <= t; j++) acc += Lr[j] * mo[j];
    a2[t] = acc;
    __syncthreads();
    float m = 0.f;
    for (int i = 0; i < 128; i++) m += A1[(long)pair * 16384 + (long)i * 128 + t] * a2[i];
    MJ[pair * 256 + t] = mo[t];
    MJ[pair * 256 + 128 + t] = m + u_mean[o * 128 + t];
}

// generic batched fp32 SGEMM
template <int TA, int TB>
__global__ __launch_bounds__(256) void k_bmm(const float* __restrict__ A, long aSH, long aSO, int lda,
                                             const float* __restrict__ B, long bSH, long bSO, int ldb,
                                             float* __restrict__ C, long cSH, long cSO, int ldc,
                                             int Ksz, float alpha, int accum) {
    int pair = blockIdx.x;
    int h = pair >> 5, o = pair & 31;
    const float* Ap = A + (long)h * aSH + (long)o * aSO;
    const float* Bp = B + (long)h * bSH + (long)o * bSO;
    float* Cp = C + (long)h * cSH + (long)o * cSO;
    int t = threadIdx.x, tx = t & 15, ty = t >> 4;
    __shared__ float As[16][132], Bs[16][132];
    float acc[8][8] = {};
    for (int kt = 0; kt < Ksz; kt += 16) {
#pragma unroll
        for (int q = 0; q < 8; q++) {
            int e = q * 256 + t;
            if (TA) {
                int kk = e >> 7, m = e & 127;
                As[kk][m] = Ap[(long)(kt + kk) * lda + m];
            } else {
                int m = e >> 4, kk = e & 15;
                As[kk][m] = Ap[(long)m * lda + kt + kk];
            }
            if (TB) {
                int n = e >> 4, kk = e & 15;
                Bs[kk][n] = Bp[(long)n * ldb + kt + kk];
            } else {
                int kk = e >> 7, n = e & 127;
                Bs[kk][n] = Bp[(long)(kt + kk) * ldb + n];
            }
        }
        __syncthreads();
#pragma unroll
        for (int kk = 0; kk < 16; kk++) {
            float a[8], b[8];
#pragma unroll
            for (int q = 0; q < 8; q++) { a[q] = As[kk][ty + 16 * q]; b[q] = Bs[kk][tx + 16 * q]; }
#pragma unroll
            for (int q = 0; q < 8; q++)
#pragma unroll
                for (int r = 0; r < 8; r++) acc[q][r] += a[q] * b[r];
        }
        __syncthreads();
    }
#pragma unroll
    for (int q = 0; q < 8; q++)
#pragma unroll
        for (int r = 0; r < 8; r++) {
            long idx = (long)(ty + 16 * q) * ldc + tx + 16 * r;
            float v = alpha * acc[q][r];
            if (accum) v += Cp[idx];
            Cp[idx] = v;
        }
}

// merged split-planes kernel: y=0 -> LINVT from (Linv1,BLi,Linv2); y=1 -> WcT from (L_old,BLW,u_tril)
// NOTE: BLi must NOT alias the WcT output planes (caller places BLi in BIG0).
__global__ __launch_bounds__(256) void k_split2(const float* __restrict__ Linv1,
                                                const float* __restrict__ BLi,
                                                const float* __restrict__ Linv2,
                                                const float* __restrict__ L_old,
                                                const float* __restrict__ BLW,
                                                const float* __restrict__ vec,
                                                ushort_t* __restrict__ LTh, ushort_t* __restrict__ LTl,
                                                ushort_t* __restrict__ WTh, ushort_t* __restrict__ WTl) {
    int pair = blockIdx.x, y = blockIdx.y, o = pair & 31, t = threadIdx.x;
    long b2 = (long)pair * 65536, b1 = (long)pair * 16384;
    int tx = t & 31, ty = t >> 5;
    __shared__ float vs[M_ * (M_ + 1) / 2];
    __shared__ float tile[32][33];
    ushort_t* Th = y ? WTh : LTh;
    ushort_t* Tl = y ? WTl : LTl;
    if (y) {
        for (int e = t; e < M_ * (M_ + 1) / 2; e += 256) vs[e] = vec[(long)o * (M_ * (M_ + 1) / 2) + e];
        __syncthreads();
        // BR quadrant of WcT: [128+n][128+k] = UT[k][n]
        for (int e = t; e < 16384; e += 256) {
            int n = e >> 7, k = e & 127;
            float v = (k >= n) ? vs[k * (k + 1) / 2 + n] : 0.f;
            ushort_t hb, lb;
            splitbf(v, hb, lb);
            long a = b2 + (long)(128 + n) * 256 + 128 + k;
            Th[a] = hb;
            Tl[a] = lb;
        }
    }
    // zeros: rows n>=128, cols k<128
    for (int e = t; e < 16384; e += 256) {
        int n = e >> 7, k = e & 127;
        long a = b2 + (long)(128 + n) * 256 + k;
        Th[a] = 0;
        Tl[a] = 0;
    }
    // transposed parts
    for (int part = 0; part < 3; part++) {
        const float* src;
        int nofs, kofs;
        if (y) {
            if (part == 2) break;
            src = part ? (BLW + b1) : (L_old + (long)o * 16384);
            nofs = 0;
            kofs = part ? 128 : 0;
        } else {
            src = (part == 0) ? (Linv1 + b1) : (part == 1) ? (BLi + b1) : (Linv2 + b1);
            nofs = (part == 2) ? 128 : 0;
            kofs = (part == 0) ? 0 : 128;
        }
        for (int bi = 0; bi < 4; bi++)
            for (int bj = 0; bj < 4; bj++) {
                __syncthreads();
                for (int r = ty; r < 32; r += 8)
                    tile[r][tx] = src[(long)(bi * 32 + r) * 128 + bj * 32 + tx];
                __syncthreads();
                for (int r = ty; r < 32; r += 8) {
                    ushort_t hb, lb;
                    splitbf(tile[tx][r], hb, lb);
                    long a = b2 + (long)(nofs + bj * 32 + r) * 256 + kofs + bi * 32 + tx;
                    Th[a] = hb;
                    Tl[a] = lb;
                }
            }
    }
}

// CV = AINV @ MJ (per-pair matvec)
__global__ __launch_bounds__(256) void k_mv(const float* __restrict__ AINV,
                                            const float* __restrict__ MJ,
                                            float* __restrict__ CV) {
    int pair = blockIdx.x, t = threadIdx.x;
    __shared__ float mj[256];
    mj[t] = MJ[pair * 256 + t];
    __syncthreads();
    const float4* row = (const float4*)(AINV + (long)pair * 65536 + (long)t * 256);
    float acc = 0.f;
#pragma unroll 8
    for (int k4 = 0; k4 < 64; k4++) {
        float4 v = row[k4];
        acc += v.x * mj[k4 * 4] + v.y * mj[k4 * 4 + 1] + v.z * mj[k4 * 4 + 2] + v.w * mj[k4 * 4 + 3];
    }
    CV[pair * 256 + t] = acc;
}

// split-bf16 MFMA batched GEMM: C = alpha*(Ah+Al)(Bh+Bl)^T [+ Dm]
#define BSTR 56
template <int TILES3>
__global__ __launch_bounds__(256) void k_bmmx(const ushort_t* __restrict__ Ah,
                                              const ushort_t* __restrict__ Al,
                                              const ushort_t* __restrict__ Bh,
                                              const ushort_t* __restrict__ Bl,
                                              float* __restrict__ Cf,
                                              ushort_t* __restrict__ Chi,
                                              ushort_t* __restrict__ Clo,
                                              const float* __restrict__ Dm,
                                              int kLoMode, float alpha) {
    int pair = blockIdx.x;
    long base = (long)pair * 65536;
    int I0, J0, mir = 0;
    if (TILES3) {
        int qb = blockIdx.y;
        I0 = (qb == 0) ? 0 : 128;
        J0 = (qb == 2) ? 0 : I0;
        mir = (qb == 2);
    } else {
        I0 = (blockIdx.y >> 1) * 128;
        J0 = (blockIdx.y & 1) * 128;
    }
    int k0 = (kLoMode == 1) ? max(I0, J0) : (kLoMode == 2) ? J0 : 0;
    int t = threadIdx.x;
    int w = t >> 6, lane = t & 63;
    int l31 = lane & 31, lhalf = lane >> 5;
    int wy = w >> 1, wx = w & 1;

    __shared__ __align__(16) ushort_t AsH[128][BSTR], AsL[128][BSTR];
    __shared__ __align__(16) ushort_t BsH[128][BSTR], BsL[128][BSTR];

    v16f acc[2][2];
#pragma unroll
    for (int mt = 0; mt < 2; mt++)
#pragma unroll
        for (int nt = 0; nt < 2; nt++)
#pragma unroll
            for (int r = 0; r < 16; r++) acc[mt][nt][r] = 0.f;

    for (int kt = k0; kt < 256; kt += 32) {
        __syncthreads();
#pragma unroll
        for (int u = 0; u < 2; u++) {
            int idx = u * 256 + t;
            int m = idx >> 2, kc = (idx & 3) * 8;
            long arow = base + (long)(I0 + m) * 256 + kt + kc;
            long brow = base + (long)(J0 + m) * 256 + kt + kc;
            *(v8us*)&AsH[m][kc] = *(const v8us*)(Ah + arow);
            *(v8us*)&AsL[m][kc] = *(const v8us*)(Al + arow);
            *(v8us*)&BsH[m][kc] = *(const v8us*)(Bh + brow);
            *(v8us*)&BsL[m][kc] = *(const v8us*)(Bl + brow);
        }
        __syncthreads();
#pragma unroll
        for (int ks = 0; ks < 2; ks++) {
            int ko = ks * 16 + lhalf * 8;
            v8bf ah[2], al[2], bh[2], bl[2];
#pragma unroll
            for (int mt = 0; mt < 2; mt++) {
                int r = wy * 64 + mt * 32 + l31;
                ah[mt] = *(const v8bf*)&AsH[r][ko];
                al[mt] = *(const v8bf*)&AsL[r][ko];
            }
#pragma unroll
            for (int nt = 0; nt < 2; nt++) {
                int r = wx * 64 + nt * 32 + l31;
                bh[nt] = *(const v8bf*)&BsH[r][ko];
                bl[nt] = *(const v8bf*)&BsL[r][ko];
            }
#pragma unroll
            for (int mt = 0; mt < 2; mt++)
#pragma unroll
                for (int nt = 0; nt < 2; nt++) {
                    acc[mt][nt] = __builtin_amdgcn_mfma_f32_32x32x16_bf16(ah[mt], bh[nt], acc[mt][nt], 0, 0, 0);
                    acc[mt][nt] = __builtin_amdgcn_mfma_f32_32x32x16_bf16(ah[mt], bl[nt], acc[mt][nt], 0, 0, 0);
                    acc[mt][nt] = __builtin_amdgcn_mfma_f32_32x32x16_bf16(al[mt], bh[nt], acc[mt][nt], 0, 0, 0);
                }
        }
    }

#pragma unroll
    for (int mt = 0; mt < 2; mt++)
#pragma unroll
        for (int nt = 0; nt < 2; nt++) {
#pragma unroll
            for (int r = 0; r < 16; r++) {
                int row = I0 + wy * 64 + mt * 32 + 8 * (r >> 2) + 4 * lhalf + (r & 3);
                int col = J0 + wx * 64 + nt * 32 + l31;
                long idx = base + (long)row * 256 + col;
                float v = alpha * acc[mt][nt][r];
                if (Dm) v += Dm[idx];
                ushort_t hb, lb;
                splitbf(v, hb, lb);
                if (Cf) Cf[idx] = v;
                if (Chi) { Chi[idx] = hb; Clo[idx] = lb; }
                if (mir) {
                    long idxT = base + (long)col * 256 + row;
                    if (Cf) Cf[idxT] = v;
                    if (Chi) { Chi[idxT] = hb; Clo[idxT] = lb; }
                }
            }
        }
}

#define KTP 280
// K build: per (bt, pair): compute K tile (fp32 kv), write bf16 K to global, fold mu
__global__ __launch_bounds__(256) void k_kbuild(const float* __restrict__ ZS, const float* __restrict__ ZN,
                                                const float* __restrict__ XS, const float* __restrict__ XN,
                                                const float* __restrict__ SF2, const float* __restrict__ CV,
                                                ushort_t* __restrict__ Kg, float* __restrict__ out) {
    int bt = blockIdx.x;    // 16
    int pair = blockIdx.y;  // 128
    int h = pair >> 5;
    int t = threadIdx.x;
    int w = t >> 6;
    int b = t & 63;

    __shared__ __align__(16) ushort_t KbT[64][KTP];
    __shared__ float mup[4][64];

    float sf2 = SF2[h];
    long bg = (long)h * B_ + bt * 64 + b;
    const float4* xrow = (const float4*)(XS + bg * 16);
    float4 x0 = xrow[0], x1 = xrow[1], x2 = xrow[2], x3 = xrow[3];
    float xn = XN[bg];
    float mupart = 0.f;
    const float* cvp = CV + pair * 256;
    const float* znp = ZN + pair * 256;
#pragma unroll 2
    for (int j8 = 0; j8 < 8; j8++) {
        v8us kb8;
#pragma unroll
        for (int e = 0; e < 8; e++) {
            int j = w * 64 + j8 * 8 + e;
            const float4* zrow = (const float4*)(ZS + ((long)pair * 256 + j) * 16);
            float4 z0 = zrow[0], z1 = zrow[1], z2 = zrow[2], z3 = zrow[3];
            float dot = z0.x * x0.x + z0.y * x0.y + z0.z * x0.z + z0.w * x0.w +
                        z1.x * x1.x + z1.y * x1.y + z1.z * x1.z + z1.w * x1.w +
                        z2.x * x2.x + z2.y * x2.y + z2.z * x2.z + z2.w * x2.w +
                        z3.x * x3.x + z3.y * x3.y + z3.z * x3.z + z3.w * x3.w;
            float d2 = fmaxf(znp[j] + xn - 2.f * dot, 0.f);
            float kv = sf2 * __expf(-0.5f * d2);
            mupart += cvp[j] * kv;
            unsigned int u = __float_as_uint(kv);
            u += 0x7fffu + ((u >> 16) & 1u);
            kb8[e] = (unsigned short)(u >> 16);
        }
        *(v8us*)&KbT[b][w * 64 + j8 * 8] = kb8;
    }
    mup[w][b] = mupart;
    __syncthreads();
    // coalesced LDS -> global (layout Kg[pair][b_global][j])
    long kbase = ((long)pair * 1024 + bt * 64) * 256;
#pragma unroll
    for (int e = 0; e < 8; e++) {
        int c = e * 256 + t;
        int bb = c >> 5, cj = (c & 31) * 8;
        *(v8us*)(Kg + kbase + (long)bb * 256 + cj) = *(const v8us*)&KbT[bb][cj];
    }
    if (t < 64) {
        float mu = mup[0][t] + mup[1][t] + mup[2][t] + mup[3][t];
        out[(long)pair * 1024 + bt * 64 + t] = mu;
    }
}

// MFMA q kernel: 1D grid, pair = idx&127 (XCD L2 locality for G)
__global__ __launch_bounds__(256) void k_kb4(const ushort_t* __restrict__ Kg,
                                             const ushort_t* __restrict__ Ghi,
                                             const ushort_t* __restrict__ Glo,
                                             const float* __restrict__ SF2, float* __restrict__ out) {
    int pair = blockIdx.x & 127;
    int bt = blockIdx.x >> 7;
    int h = pair >> 5;
    int t = threadIdx.x;
    int w = t >> 6;
    int lane = t & 63;
    int l31 = lane & 31, lhalf = lane >> 5;

    __shared__ __align__(16) ushort_t KbT[64][KTP];
    __shared__ float qpart[4][64];

    float sf2 = SF2[h];
    long kbase = ((long)pair * 1024 + bt * 64) * 256;
#pragma unroll
    for (int e = 0; e < 8; e++) {
        int c = e * 256 + t;
        int bb = c >> 5, cj = (c & 31) * 8;
        *(v8us*)&KbT[bb][cj] = *(const v8us*)(Kg + kbase + (long)bb * 256 + cj);
    }
    __syncthreads();

    v16f acc[2][2];
#pragma unroll
    for (int mt = 0; mt < 2; mt++)
#pragma unroll
        for (int nt = 0; nt < 2; nt++)
#pragma unroll
            for (int r = 0; r < 16; r++) acc[mt][nt][r] = 0.f;

    const ushort_t* GhiP = Ghi + (long)pair * 65536;
    const ushort_t* GloP = Glo + (long)pair * 65536;
#pragma unroll 2
    for (int k0 = 0; k0 < 256; k0 += 16) {
        v8bf bfr[2];
#pragma unroll
        for (int nt = 0; nt < 2; nt++)
            bfr[nt] = *(const v8bf*)&KbT[nt * 32 + l31][k0 + lhalf * 8];
#pragma unroll
        for (int mt = 0; mt < 2; mt++) {
            int i = w * 64 + mt * 32 + l31;
            v8bf ah = *(const v8bf*)(GhiP + (long)i * 256 + k0 + lhalf * 8);
            v8bf al = *(const v8bf*)(GloP + (long)i * 256 + k0 + lhalf * 8);
#pragma unroll
            for (int nt = 0; nt < 2; nt++) {
                acc[mt][nt] = __builtin_amdgcn_mfma_f32_32x32x16_bf16(ah, bfr[nt], acc[mt][nt], 0, 0, 0);
                acc[mt][nt] = __builtin_amdgcn_mfma_f32_32x32x16_bf16(al, bfr[nt], acc[mt][nt], 0, 0, 0);
            }
        }
    }

    float qp[2] = {0.f, 0.f};
#pragma unroll
    for (int mt = 0; mt < 2; mt++) {
#pragma unroll
        for (int nt = 0; nt < 2; nt++) {
            int b = nt * 32 + l31;
#pragma unroll
            for (int g = 0; g < 4; g++) {
                int ibase = w * 64 + mt * 32 + 8 * g + 4 * lhalf;
                v4us k4 = *(const v4us*)&KbT[b][ibase];
#pragma unroll
                for (int e = 0; e < 4; e++) {
                    float kv = bf2f(k4[e]);
                    qp[nt] += kv * acc[mt][nt][4 * g + e];
                }
            }
        }
    }
#pragma unroll
    for (int nt = 0; nt < 2; nt++) {
        qp[nt] += __shfl_down(qp[nt], 32, 64);
        if (lhalf == 0) qpart[w][nt * 32 + l31] = qp[nt];
    }
    __syncthreads();

    if (t < 64) {
        float q = qpart[0][t] + qpart[1][t] + qpart[2][t] + qpart[3][t];
        out[(long)H_ * O_ * B_ + (long)pair * 1024 + bt * 64 + t] = sf2 - q;
    }
}

// ---------------------------------------------------------------------------
extern "C" void kernel_launch(void* const* d_in, const int* in_sizes, int n_in,
                              void* d_out, int out_size, void* d_ws, size_t ws_size,
                              hipStream_t stream) {
    const float* x = (const float*)d_in[0];
    const float* z = (const float*)d_in[1];
    const float* u_mean = (const float*)d_in[2];
    const float* u_tril_vec = (const float*)d_in[3];
    const float* m_old = (const float*)d_in[4];
    const float* L_old = (const float*)d_in[5];
    const float* z_old = (const float*)d_in[6];
    const float* theta = (const float*)d_in[7];

    const long BIGSZ = (long)HO * M2 * M2;  // 8388608
    const long MSZ = (long)HO * M_ * M_;    // 2097152
    const long SH1 = (long)O_ * M_ * M_;
    const long SO1 = (long)M_ * M_;
    const long SO2 = (long)M2 * M2;

    float* ws = (float*)d_ws;
    long off = 0;
    float* BIG0 = ws + off; off += BIGSZ;  // KUU2 -> T1/BLi -> AINV fp32
    float* BIG1 = ws + off; off += BIGSZ;  // LINVT h/l -> Y h/l -> Kg (part 1)
    float* BIG2 = ws + off; off += BIGSZ;  // Linv1|A1|Linv2|BLW -> AINV h/l -> Kg (part 2)
    float* BIG3 = ws + off; off += BIGSZ;  // L256 -> WcT h/l -> G h/l
    float* ZS = ws + off; off += (long)HO * M2 * D_;
    float* XS = ws + off; off += (long)H_ * B_ * D_;
    float* ZN = ws + off; off += (long)HO * M2;
    float* XN = ws + off; off += (long)H_ * B_;
    float* MJ = ws + off; off += (long)HO * M2;
    float* CV = ws + off; off += (long)HO * M2;
    float* SF2v = ws + off; off += H_;

    float* KUU2 = BIG0;
    float* AINV = BIG0;
    float* Linv1 = BIG2;
    float* A1 = BIG2 + MSZ;
    float* A3 = BIG2 + 2 * MSZ;
    float* Linv2 = BIG2 + 2 * MSZ;
    float* BLW = BIG2 + 3 * MSZ;
    float* L256 = BIG3;
    float* T1 = BIG0;                // over KUU2 TL (dead after step 8)
    float* BLi = BIG0 + MSZ;         // over KUU2 (dead) — NOT in BIG3 (k_split2 race fix)
    ushort_t* LINVTh = (ushort_t*)BIG1;
    ushort_t* LINVTl = LINVTh + BIGSZ;
    ushort_t* AINVh = (ushort_t*)BIG2;
    ushort_t* AINVl = AINVh + BIGSZ;
    ushort_t* WcTh = (ushort_t*)BIG3;
    ushort_t* WcTl = WcTh + BIGSZ;
    ushort_t* Yh = (ushort_t*)BIG1;
    ushort_t* Yl = Yh + BIGSZ;
    ushort_t* Ghi = (ushort_t*)BIG3;
    ushort_t* Glo = Ghi + BIGSZ;
    ushort_t* Kg = (ushort_t*)BIG1;  // 64 MB spanning BIG1+BIG2 (both dead by then)
    const long BRoff = 128L * M2 + 128;

    // 1. preprocessing
    k_pre<<<145, 256, 0, stream>>>(theta, x, z, z_old, SF2v, XS, XN, ZS, ZN);
    // 2. kuu2
    k_kuu2<<<HO, 256, 0, stream>>>(ZS, ZN, SF2v, KUU2);
    // 3. chol TL -> L256 TL
    k_chol128<<<HO, 256, 0, stream>>>(KUU2, SO2, M2, L256, SO2, M2);
    // 4. Linv1
    k_trinv128<<<HO, 256, 0, stream>>>(L256, SO2, M2, Linv1);
    // 5. A1 = Linv1@kuf ; A3 = Linv1@L_old (merged)
    k_a1a3<<<dim3(HO, 2), 256, 0, stream>>>(Linv1, KUU2, L_old, A1, A3);
    // 6. m_joint
    k_stage1vec<<<HO, 128, 0, stream>>>(Linv1, A1, m_old, u_mean, MJ);
    // 7. BLW = A1^T A3 ; KUU2_BR -= A1^T A1 (merged)
    k_blwschur<<<dim3(HO, 2), 256, 0, stream>>>(A1, A3, BLW, KUU2);
    // 8. chol BR -> L256 BR
    k_chol128<<<HO, 256, 0, stream>>>(KUU2 + BRoff, SO2, M2, L256 + BRoff, SO2, M2);
    // 9. Linv2 (overwrites A3 slot)
    k_trinv128<<<HO, 256, 0, stream>>>(L256 + BRoff, SO2, M2, Linv2);
    // 10. T1 = A1^T @ Linv1 (into BIG0 — KUU2 dead)
    k_bmm<1, 0><<<HO, 256, 0, stream>>>(A1, SH1, SO1, M_, Linv1, SH1, SO1, M_,
                                        T1, SH1, SO1, M_, M_, 1.f, 0);
    // 11. BLi = -Linv2 @ T1 (into BIG0+MSZ)
    k_bmm<0, 0><<<HO, 256, 0, stream>>>(Linv2, SH1, SO1, M_, T1, SH1, SO1, M_,
                                        BLi, SH1, SO1, M_, M_, -1.f, 0);
    // 12. LINVT + WcT planes (merged; BLi in BIG0, WcT in BIG3 — disjoint now)
    k_split2<<<dim3(HO, 2), 256, 0, stream>>>(Linv1, BLi, Linv2, L_old, BLW, u_tril_vec,
                                              LINVTh, LINVTl, WcTh, WcTl);
    // 13. AINV = LINVT (.) LINVT -> fp32 (BIG0, T1/BLi dead) + planes (BIG2)
    k_bmmx<1><<<dim3(HO, 3), 256, 0, stream>>>(LINVTh, LINVTl, LINVTh, LINVTl,
                                               AINV, AINVh, AINVl, nullptr, 1, 1.f);
    // 14. CV = AINV @ MJ
    k_mv<<<HO, 256, 0, stream>>>(AINV, MJ, CV);
    // 15. Y = AINV @ Wc -> Y planes (BIG1; LINVT dead)
    k_bmmx<0><<<dim3(HO, 4), 256, 0, stream>>>(AINVh, AINVl, WcTh, WcTl,
                                               nullptr, Yh, Yl, nullptr, 2, 1.f);
    // 16. G = AINV - Y Y^T -> G planes (BIG3; WcT dead)
    k_bmmx<1><<<dim3(HO, 3), 256, 0, stream>>>(Yh, Yl, Yh, Yl,
                                               nullptr, Ghi, Glo, AINV, 0, -1.f);
    // 17. K build + mu (Kg over BIG1+BIG2 — Y and AINV planes dead)
    k_kbuild<<<dim3(16, HO), 256, 0, stream>>>(ZS, ZN, XS, XN, SF2v, CV, Kg, (float*)d_out);
    // 18. MFMA q/var
    k_kb4<<<2048, 256, 0, stream>>>(Kg, Ghi, Glo, SF2v, (float*)d_out);
}

// Round 10
// 760.418 us; speedup vs baseline: 1.4243x; 1.0414x over previous
//
#include <hip/hip_runtime.h>

#define H_ 4
#define O_ 32
#define HO 128
#define M_ 128
#define M2 256
#define D_ 16
#define B_ 1024
#define JIT 1e-4f

typedef unsigned short ushort_t;
typedef __bf16 v8bf __attribute__((ext_vector_type(8)));
typedef float v16f __attribute__((ext_vector_type(16)));
typedef unsigned short v8us __attribute__((ext_vector_type(8)));
typedef unsigned short v4us __attribute__((ext_vector_type(4)));

__device__ inline void splitbf(float v, ushort_t& hb, ushort_t& lb) {
    unsigned int u = __float_as_uint(v);
    hb = (ushort_t)(u >> 16);
    float hf = __uint_as_float((unsigned int)hb << 16);
    float r = v - hf;
    lb = (ushort_t)(__float_as_uint(r) >> 16);
}
__device__ inline float bf2f(ushort_t u) { return __uint_as_float((unsigned int)u << 16); }

// ---------------------------------------------------------------------------
// merged preprocessing + kuu2: blocks 0-127 scale_z AND kuu2 for their pair
// (zs already in LDS); 128-143 scale_x; 144 SF2
__global__ __launch_bounds__(256) void k_prekuu2(const float* __restrict__ theta,
                                                 const float* __restrict__ x,
                                                 const float* __restrict__ z,
                                                 const float* __restrict__ z_old,
                                                 float* __restrict__ SF2,
                                                 float* __restrict__ XS, float* __restrict__ XN,
                                                 float* __restrict__ ZS, float* __restrict__ ZN,
                                                 float* __restrict__ K2) {
    int bb = blockIdx.x, t = threadIdx.x;
    __shared__ float zs[M2][D_];
    __shared__ float zn[M2];
    __shared__ float ls[D_];
    if (bb == 144) {
        if (t < H_) SF2[t] = __expf(theta[t * (D_ + 1)]);
        return;
    }
    if (bb >= 128) {
        int j = (bb - 128) * 256 + t;
        int h = j >> 10, b = j & 1023;
        if (t < D_) ls[t] = __expf(-theta[h * (D_ + 1) + 1 + t]);
        __syncthreads();
        float s = 0.f;
#pragma unroll
        for (int d = 0; d < D_; d++) {
            float v = x[b * D_ + d] * ls[d];
            XS[(long)j * D_ + d] = v;
            s += v * v;
        }
        XN[j] = s;
        return;
    }
    // scale_z + kuu2
    int pair = bb, h = pair >> 5, o = pair & 31, i = t;
    if (t < D_) ls[t] = __expf(-theta[h * (D_ + 1) + 1 + t]);
    __syncthreads();
    const float* src = (i < M_) ? (z_old + ((long)o * M_ + i) * D_)
                                : (z + ((long)o * M_ + (i - M_)) * D_);
    float s = 0.f;
#pragma unroll
    for (int d = 0; d < D_; d++) {
        float v = src[d] * ls[d];
        zs[i][d] = v;
        ZS[((long)pair * M2 + i) * D_ + d] = v;
        s += v * v;
    }
    zn[i] = s;
    ZN[pair * M2 + i] = s;
    __syncthreads();
    float sf2 = __expf(theta[h * (D_ + 1)]);
    float my[D_];
#pragma unroll
    for (int d = 0; d < D_; d++) my[d] = zs[i][d];
    float myn = zn[i];
    for (int q = 0; q < M2; q++) {
        float dot = 0.f;
#pragma unroll
        for (int d = 0; d < D_; d++) dot += zs[q][d] * my[d];
        float d2 = fmaxf(zn[q] + myn - 2.f * dot, 0.f);
        float v = sf2 * __expf(-0.5f * d2);
        if (q == i) v += JIT;
        K2[(long)pair * M2 * M2 + (long)q * M2 + i] = v;
    }
}

// fused: blocked (BK=32) in-LDS Cholesky of a 128x128 block, then triangular
// inverse of the resulting L — all in LDS, writes full Linv (zero upper).
__global__ __launch_bounds__(256) void k_choltri(const float* __restrict__ src, long sps, int ldsrc,
                                                 float* __restrict__ Li) {
    int pair = blockIdx.x, t = threadIdx.x;
    __shared__ float Ap[M_ * (M_ + 1) / 2];
    __shared__ float rsq[32];
    __shared__ float Ld[2][64][66], Wd[2][64][66], LB[64][66], Tt[64][66];
    const float* S = src + (long)pair * sps;
    for (int e = t; e < M_ * (M_ + 1) / 2; e += 256) {
        int i = (int)((sqrtf(8.f * e + 1.f) - 1.f) * 0.5f);
        while ((i + 1) * (i + 2) / 2 <= e) i++;
        while (i * (i + 1) / 2 > e) i--;
        int j = e - i * (i + 1) / 2;
        Ap[e] = S[(long)i * ldsrc + j];
    }
    int pi[3], pj[3];
#pragma unroll
    for (int u = 0; u < 3; u++) {
        int p = t + u * 256;
        if (p < 528) {
            int i = (int)((sqrtf(8.f * p + 1.f) - 1.f) * 0.5f);
            while ((i + 1) * (i + 2) / 2 <= p) i++;
            while (i * (i + 1) / 2 > p) i--;
            pi[u] = i;
            pj[u] = p - i * (i + 1) / 2;
        } else {
            pi[u] = -1;
            pj[u] = 0;
        }
    }
    __syncthreads();

    for (int kb = 0; kb < 4; kb++) {
        int c0 = kb * 32;
        for (int k = 0; k < 32; k++) {
            int kc = c0 + k;
            float rd = 1.f / Ap[kc * (kc + 1) / 2 + kc];
#pragma unroll
            for (int u = 0; u < 3; u++) {
                int i = pi[u], j = pj[u];
                if (i > k && j > k) {
                    int gi = c0 + i, gj = c0 + j;
                    Ap[gi * (gi + 1) / 2 + gj] -=
                        Ap[gi * (gi + 1) / 2 + kc] * Ap[gj * (gj + 1) / 2 + kc] * rd;
                }
            }
            __syncthreads();
        }
        if (t < 32) {
            int g = c0 + t;
            rsq[t] = rsqrtf(Ap[g * (g + 1) / 2 + g]);
        }
        __syncthreads();
#pragma unroll
        for (int u = 0; u < 3; u++) {
            int i = pi[u], j = pj[u];
            if (i >= 0) {
                int gi = c0 + i, gj = c0 + j;
                Ap[gi * (gi + 1) / 2 + gj] *= rsq[j];
            }
        }
        __syncthreads();

        int R = M_ - c0 - 32;
        if (R > 0) {
            if (t < R) {
                int gi = c0 + 32 + t;
                int base = gi * (gi + 1) / 2 + c0;
                float xr[32];
#pragma unroll
                for (int j = 0; j < 32; j++) xr[j] = Ap[base + j];
#pragma unroll
                for (int q = 0; q < 32; q++) {
                    float xq = xr[q] * rsq[q];
                    xr[q] = xq;
#pragma unroll
                    for (int j = q + 1; j < 32; j++)
                        xr[j] -= xq * Ap[(c0 + j) * (c0 + j + 1) / 2 + c0 + q];
                }
#pragma unroll
                for (int j = 0; j < 32; j++) Ap[base + j] = xr[j];
            }
            __syncthreads();
            int nb = R >> 2;
            int ntile = nb * (nb + 1) / 2;
            for (int tp = t; tp < ntile; tp += 256) {
                int bi = (int)((sqrtf(8.f * tp + 1.f) - 1.f) * 0.5f);
                while ((bi + 1) * (bi + 2) / 2 <= tp) bi++;
                while (bi * (bi + 1) / 2 > tp) bi--;
                int bj = tp - bi * (bi + 1) / 2;
                int i0 = c0 + 32 + bi * 4, j0 = c0 + 32 + bj * 4;
                float acc[4][4] = {};
                for (int k = 0; k < 32; k++) {
                    float a[4], b[4];
#pragma unroll
                    for (int q = 0; q < 4; q++) a[q] = Ap[(i0 + q) * (i0 + q + 1) / 2 + c0 + k];
#pragma unroll
                    for (int r = 0; r < 4; r++) b[r] = Ap[(j0 + r) * (j0 + r + 1) / 2 + c0 + k];
#pragma unroll
                    for (int q = 0; q < 4; q++)
#pragma unroll
                        for (int r = 0; r < 4; r++) acc[q][r] += a[q] * b[r];
                }
#pragma unroll
                for (int q = 0; q < 4; q++)
#pragma unroll
                    for (int r = 0; r < 4; r++) {
                        int gi = i0 + q, gj = j0 + r;
                        if (gj <= gi) Ap[gi * (gi + 1) / 2 + gj] -= acc[q][r];
                    }
            }
            __syncthreads();
        }
    }

    // ---- trinv from packed L in Ap ----
    for (int e = t; e < 8192; e += 256) {
        int g = e >> 12, i = (e >> 6) & 63, j = e & 63;
        int gi = g * 64 + i, gj = g * 64 + j;
        Ld[g][i][j] = (j <= i) ? Ap[gi * (gi + 1) / 2 + gj] : 0.f;
    }
    for (int e = t; e < 4096; e += 256) {
        int i = e >> 6, j = e & 63;
        int gi = 64 + i;
        LB[i][j] = Ap[gi * (gi + 1) / 2 + j];
    }
    __syncthreads();
    if (t < 128) {
        int g = t >> 6, c = t & 63;
        for (int i = 0; i < 64; i++) {
            float acc = (i == c) ? 1.f : 0.f;
            for (int j = 0; j < i; j++) acc -= Ld[g][i][j] * Wd[g][j][c];
            Wd[g][i][c] = acc / Ld[g][i][i];
        }
    }
    __syncthreads();
    long b1 = (long)pair * 16384;
    int ti = t >> 4, tj = t & 15;
    float acc[4][4] = {};
    for (int kk = 0; kk < 64; kk++) {
        float a[4], b[4];
#pragma unroll
        for (int q = 0; q < 4; q++) a[q] = LB[ti * 4 + q][kk];
#pragma unroll
        for (int r = 0; r < 4; r++) b[r] = Wd[0][kk][tj * 4 + r];
#pragma unroll
        for (int q = 0; q < 4; q++)
#pragma unroll
            for (int r = 0; r < 4; r++) acc[q][r] += a[q] * b[r];
    }
#pragma unroll
    for (int q = 0; q < 4; q++)
#pragma unroll
        for (int r = 0; r < 4; r++) Tt[ti * 4 + q][tj * 4 + r] = acc[q][r];
    __syncthreads();
    float xo[4][4] = {};
    for (int kk = 0; kk < 64; kk++) {
        float a[4], b[4];
#pragma unroll
        for (int q = 0; q < 4; q++) a[q] = Wd[1][ti * 4 + q][kk];
#pragma unroll
        for (int r = 0; r < 4; r++) b[r] = Tt[kk][tj * 4 + r];
#pragma unroll
        for (int q = 0; q < 4; q++)
#pragma unroll
            for (int r = 0; r < 4; r++) xo[q][r] -= a[q] * b[r];
    }
#pragma unroll
    for (int q = 0; q < 4; q++)
#pragma unroll
        for (int r = 0; r < 4; r++)
            Li[b1 + (long)(64 + ti * 4 + q) * 128 + tj * 4 + r] = xo[q][r];
    for (int e = t; e < 4096; e += 256) {
        int i = e >> 6, j = e & 63;
        Li[b1 + (long)i * 128 + j] = Wd[0][i][j];
        Li[b1 + (long)(64 + i) * 128 + 64 + j] = Wd[1][i][j];
        Li[b1 + (long)i * 128 + 64 + j] = 0.f;
    }
}

// merged A1/A3: y=0: A1 = Linv1 @ kuf(KUU2 TR); y=1: A3 = Linv1 @ L_old
__global__ __launch_bounds__(256) void k_a1a3(const float* __restrict__ Linv1,
                                              const float* __restrict__ KUU2,
                                              const float* __restrict__ L_old,
                                              float* __restrict__ A1, float* __restrict__ A3) {
    int pair = blockIdx.x, y = blockIdx.y, o = pair & 31;
    const float* Ap = Linv1 + (long)pair * 16384;
    const float* Bp = y ? (L_old + (long)o * 16384) : (KUU2 + (long)pair * 65536 + 128);
    int ldb = y ? 128 : 256;
    float* Cp = (y ? A3 : A1) + (long)pair * 16384;
    int t = threadIdx.x, tx = t & 15, ty = t >> 4;
    __shared__ float As[16][132], Bs[16][132];
    float acc[8][8] = {};
    for (int kt = 0; kt < M_; kt += 16) {
#pragma unroll
        for (int q = 0; q < 8; q++) {
            int e = q * 256 + t;
            int m = e >> 4, kk = e & 15;
            As[kk][m] = Ap[(long)m * 128 + kt + kk];
            int kk2 = e >> 7, n = e & 127;
            Bs[kk2][n] = Bp[(long)(kt + kk2) * ldb + n];
        }
        __syncthreads();
#pragma unroll
        for (int kk = 0; kk < 16; kk++) {
            float a[8], b[8];
#pragma unroll
            for (int q = 0; q < 8; q++) { a[q] = As[kk][ty + 16 * q]; b[q] = Bs[kk][tx + 16 * q]; }
#pragma unroll
            for (int q = 0; q < 8; q++)
#pragma unroll
                for (int r = 0; r < 8; r++) acc[q][r] += a[q] * b[r];
        }
        __syncthreads();
    }
#pragma unroll
    for (int q = 0; q < 8; q++)
#pragma unroll
        for (int r = 0; r < 8; r++)
            Cp[(long)(ty + 16 * q) * 128 + tx + 16 * r] = acc[q][r];
}

// merged BLW/Schur: y=0: BLW = A1^T @ A3; y=1: KUU2_BR -= A1^T @ A1
__global__ __launch_bounds__(256) void k_blwschur(const float* __restrict__ A1,
                                                  const float* __restrict__ A3,
                                                  float* __restrict__ BLW,
                                                  float* __restrict__ KUU2) {
    int pair = blockIdx.x, y = blockIdx.y;
    const float* Ap = A1 + (long)pair * 16384;
    const float* Bp = (y ? A1 : A3) + (long)pair * 16384;
    float* Cp;
    int ldc;
    if (y) { Cp = KUU2 + (long)pair * 65536 + 128L * 256 + 128; ldc = 256; }
    else   { Cp = BLW + (long)pair * 16384; ldc = 128; }
    int t = threadIdx.x, tx = t & 15, ty = t >> 4;
    __shared__ float As[16][132], Bs[16][132];
    float acc[8][8] = {};
    for (int kt = 0; kt < M_; kt += 16) {
#pragma unroll
        for (int q = 0; q < 8; q++) {
            int e = q * 256 + t;
            int kk = e >> 7, m = e & 127;
            As[kk][m] = Ap[(long)(kt + kk) * 128 + m];
            Bs[kk][m] = Bp[(long)(kt + kk) * 128 + m];
        }
        __syncthreads();
#pragma unroll
        for (int kk = 0; kk < 16; kk++) {
            float a[8], b[8];
#pragma unroll
            for (int q = 0; q < 8; q++) { a[q] = As[kk][ty + 16 * q]; b[q] = Bs[kk][tx + 16 * q]; }
#pragma unroll
            for (int q = 0; q < 8; q++)
#pragma unroll
                for (int r = 0; r < 8; r++) acc[q][r] += a[q] * b[r];
        }
        __syncthreads();
    }
#pragma unroll
    for (int q = 0; q < 8; q++)
#pragma unroll
        for (int r = 0; r < 8; r++) {
            long idx = (long)(ty + 16 * q) * ldc + tx + 16 * r;
            if (y) Cp[idx] -= acc[q][r];
            else Cp[idx] = acc[q][r];
        }
}

// a2 = Linv128 * m_old ; m_new = A1^T a2 + u_mean ; write m_joint
__global__ __launch_bounds__(128) void k_stage1vec(const float* __restrict__ Linv128,
                                                   const float* __restrict__ A1,
                                                   const float* __restrict__ m_old,
                                                   const float* __restrict__ u_mean,
                                                   float* __restrict__ MJ) {
    int pair = blockIdx.x, o = pair & 31, t = threadIdx.x;
    __shared__ float mo[128], a2[128];
    mo[t] = m_old[o * 128 + t];
    __syncthreads();
    const float* Lr = Linv128 + (long)pair * 16384 + (long)t * 128;
    float acc = 0.f;
    for (int j = 0; j <= t; j++) acc += Lr[j] * mo[j];
    a2[t] = acc;
    __syncthreads();
    float m = 0.f;
    for (int i = 0; i < 128; i++) m += A1[(long)pair * 16384 + (long)i * 128 + t] * a2[i];
    MJ[pair * 256 + t] = mo[t];
    MJ[pair * 256 + 128 + t] = m + u_mean[o * 128 + t];
}

// generic batched fp32 SGEMM
template <int TA, int TB>
__global__ __launch_bounds__(256) void k_bmm(const float* __restrict__ A, long aSH, long aSO, int lda,
                                             const float* __restrict__ B, long bSH, long bSO, int ldb,
                                             float* __restrict__ C, long cSH, long cSO, int ldc,
                                             int Ksz, float alpha, int accum) {
    int pair = blockIdx.x;
    int h = pair >> 5, o = pair & 31;
    const float* Ap = A + (long)h * aSH + (long)o * aSO;
    const float* Bp = B + (long)h * bSH + (long)o * bSO;
    float* Cp = C + (long)h * cSH + (long)o * cSO;
    int t = threadIdx.x, tx = t & 15, ty = t >> 4;
    __shared__ float As[16][132], Bs[16][132];
    float acc[8][8] = {};
    for (int kt = 0; kt < Ksz; kt += 16) {
#pragma unroll
        for (int q = 0; q < 8; q++) {
            int e = q * 256 + t;
            if (TA) {
                int kk = e >> 7, m = e & 127;
                As[kk][m] = Ap[(long)(kt + kk) * lda + m];
            } else {
                int m = e >> 4, kk = e & 15;
                As[kk][m] = Ap[(long)m * lda + kt + kk];
            }
            if (TB) {
                int n = e >> 4, kk = e & 15;
                Bs[kk][n] = Bp[(long)n * ldb + kt + kk];
            } else {
                int kk = e >> 7, n = e & 127;
                Bs[kk][n] = Bp[(long)(kt + kk) * ldb + n];
            }
        }
        __syncthreads();
#pragma unroll
        for (int kk = 0; kk < 16; kk++) {
            float a[8], b[8];
#pragma unroll
            for (int q = 0; q < 8; q++) { a[q] = As[kk][ty + 16 * q]; b[q] = Bs[kk][tx + 16 * q]; }
#pragma unroll
            for (int q = 0; q < 8; q++)
#pragma unroll
                for (int r = 0; r < 8; r++) acc[q][r] += a[q] * b[r];
        }
        __syncthreads();
    }
#pragma unroll
    for (int q = 0; q < 8; q++)
#pragma unroll
        for (int r = 0; r < 8; r++) {
            long idx = (long)(ty + 16 * q) * ldc + tx + 16 * r;
            float v = alpha * acc[q][r];
            if (accum) v += Cp[idx];
            Cp[idx] = v;
        }
}

// merged split-planes kernel: y=0 -> LINVT from (Linv1,BLi,Linv2); y=1 -> WcT from (L_old,BLW,u_tril)
// NOTE: BLi must NOT alias the WcT output planes (caller places BLi in BIG0).
__global__ __launch_bounds__(256) void k_split2(const float* __restrict__ Linv1,
                                                const float* __restrict__ BLi,
                                                const float* __restrict__ Linv2,
                                                const float* __restrict__ L_old,
                                                const float* __restrict__ BLW,
                                                const float* __restrict__ vec,
                                                ushort_t* __restrict__ LTh, ushort_t* __restrict__ LTl,
                                                ushort_t* __restrict__ WTh, ushort_t* __restrict__ WTl) {
    int pair = blockIdx.x, y = blockIdx.y, o = pair & 31, t = threadIdx.x;
    long b2 = (long)pair * 65536, b1 = (long)pair * 16384;
    int tx = t & 31, ty = t >> 5;
    __shared__ float vs[M_ * (M_ + 1) / 2];
    __shared__ float tile[32][33];
    ushort_t* Th = y ? WTh : LTh;
    ushort_t* Tl = y ? WTl : LTl;
    if (y) {
        for (int e = t; e < M_ * (M_ + 1) / 2; e += 256) vs[e] = vec[(long)o * (M_ * (M_ + 1) / 2) + e];
        __syncthreads();
        for (int e = t; e < 16384; e += 256) {
            int n = e >> 7, k = e & 127;
            float v = (k >= n) ? vs[k * (k + 1) / 2 + n] : 0.f;
            ushort_t hb, lb;
            splitbf(v, hb, lb);
            long a = b2 + (long)(128 + n) * 256 + 128 + k;
            Th[a] = hb;
            Tl[a] = lb;
        }
    }
    for (int e = t; e < 16384; e += 256) {
        int n = e >> 7, k = e & 127;
        long a = b2 + (long)(128 + n) * 256 + k;
        Th[a] = 0;
        Tl[a] = 0;
    }
    for (int part = 0; part < 3; part++) {
        const float* src;
        int nofs, kofs;
        if (y) {
            if (part == 2) break;
            src = part ? (BLW + b1) : (L_old + (long)o * 16384);
            nofs = 0;
            kofs = part ? 128 : 0;
        } else {
            src = (part == 0) ? (Linv1 + b1) : (part == 1) ? (BLi + b1) : (Linv2 + b1);
            nofs = (part == 2) ? 128 : 0;
            kofs = (part == 0) ? 0 : 128;
        }
        for (int bi = 0; bi < 4; bi++)
            for (int bj = 0; bj < 4; bj++) {
                __syncthreads();
                for (int r = ty; r < 32; r += 8)
                    tile[r][tx] = src[(long)(bi * 32 + r) * 128 + bj * 32 + tx];
                __syncthreads();
                for (int r = ty; r < 32; r += 8) {
                    ushort_t hb, lb;
                    splitbf(tile[tx][r], hb, lb);
                    long a = b2 + (long)(nofs + bj * 32 + r) * 256 + kofs + bi * 32 + tx;
                    Th[a] = hb;
                    Tl[a] = lb;
                }
            }
    }
}

// split-bf16 MFMA batched GEMM: C = alpha*(Ah+Al)(Bh+Bl)^T [+ Dm]
// optional fused matvec: CVat += C @ MJv (per-row partials via in-wave reduce + atomicAdd)
#define BSTR 56
template <int TILES3>
__global__ __launch_bounds__(256) void k_bmmx(const ushort_t* __restrict__ Ah,
                                              const ushort_t* __restrict__ Al,
                                              const ushort_t* __restrict__ Bh,
                                              const ushort_t* __restrict__ Bl,
                                              float* __restrict__ Cf,
                                              ushort_t* __restrict__ Chi,
                                              ushort_t* __restrict__ Clo,
                                              const float* __restrict__ Dm,
                                              int kLoMode, float alpha,
                                              const float* __restrict__ MJv,
                                              float* __restrict__ CVat) {
    int pair = blockIdx.x;
    long base = (long)pair * 65536;
    int I0, J0, mir = 0;
    if (TILES3) {
        int qb = blockIdx.y;
        I0 = (qb == 0) ? 0 : 128;
        J0 = (qb == 2) ? 0 : I0;
        mir = (qb == 2);
    } else {
        I0 = (blockIdx.y >> 1) * 128;
        J0 = (blockIdx.y & 1) * 128;
    }
    int k0 = (kLoMode == 1) ? max(I0, J0) : (kLoMode == 2) ? J0 : 0;
    int t = threadIdx.x;
    int w = t >> 6, lane = t & 63;
    int l31 = lane & 31, lhalf = lane >> 5;
    int wy = w >> 1, wx = w & 1;

    __shared__ __align__(16) ushort_t AsH[128][BSTR], AsL[128][BSTR];
    __shared__ __align__(16) ushort_t BsH[128][BSTR], BsL[128][BSTR];

    v16f acc[2][2];
#pragma unroll
    for (int mt = 0; mt < 2; mt++)
#pragma unroll
        for (int nt = 0; nt < 2; nt++)
#pragma unroll
            for (int r = 0; r < 16; r++) acc[mt][nt][r] = 0.f;

    for (int kt = k0; kt < 256; kt += 32) {
        __syncthreads();
#pragma unroll
        for (int u = 0; u < 2; u++) {
            int idx = u * 256 + t;
            int m = idx >> 2, kc = (idx & 3) * 8;
            long arow = base + (long)(I0 + m) * 256 + kt + kc;
            long brow = base + (long)(J0 + m) * 256 + kt + kc;
            *(v8us*)&AsH[m][kc] = *(const v8us*)(Ah + arow);
            *(v8us*)&AsL[m][kc] = *(const v8us*)(Al + arow);
            *(v8us*)&BsH[m][kc] = *(const v8us*)(Bh + brow);
            *(v8us*)&BsL[m][kc] = *(const v8us*)(Bl + brow);
        }
        __syncthreads();
#pragma unroll
        for (int ks = 0; ks < 2; ks++) {
            int ko = ks * 16 + lhalf * 8;
            v8bf ah[2], al[2], bh[2], bl[2];
#pragma unroll
            for (int mt = 0; mt < 2; mt++) {
                int r = wy * 64 + mt * 32 + l31;
                ah[mt] = *(const v8bf*)&AsH[r][ko];
                al[mt] = *(const v8bf*)&AsL[r][ko];
            }
#pragma unroll
            for (int nt = 0; nt < 2; nt++) {
                int r = wx * 64 + nt * 32 + l31;
                bh[nt] = *(const v8bf*)&BsH[r][ko];
                bl[nt] = *(const v8bf*)&BsL[r][ko];
            }
#pragma unroll
            for (int mt = 0; mt < 2; mt++)
#pragma unroll
                for (int nt = 0; nt < 2; nt++) {
                    acc[mt][nt] = __builtin_amdgcn_mfma_f32_32x32x16_bf16(ah[mt], bh[nt], acc[mt][nt], 0, 0, 0);
                    acc[mt][nt] = __builtin_amdgcn_mfma_f32_32x32x16_bf16(ah[mt], bl[nt], acc[mt][nt], 0, 0, 0);
                    acc[mt][nt] = __builtin_amdgcn_mfma_f32_32x32x16_bf16(al[mt], bh[nt], acc[mt][nt], 0, 0, 0);
                }
        }
    }

    float mjc[2] = {0.f, 0.f};
    float cvmir[2] = {0.f, 0.f};
    if (MJv) {
#pragma unroll
        for (int nt = 0; nt < 2; nt++)
            mjc[nt] = MJv[(long)pair * 256 + J0 + wx * 64 + nt * 32 + l31];
    }
#pragma unroll
    for (int mt = 0; mt < 2; mt++) {
#pragma unroll
        for (int r = 0; r < 16; r++) {
            int row = I0 + wy * 64 + mt * 32 + 8 * (r >> 2) + 4 * lhalf + (r & 3);
            float rowsum = 0.f;
            float mjrow = 0.f;
            if (MJv && mir) mjrow = MJv[(long)pair * 256 + row];
#pragma unroll
            for (int nt = 0; nt < 2; nt++) {
                int col = J0 + wx * 64 + nt * 32 + l31;
                long idx = base + (long)row * 256 + col;
                float v = alpha * acc[mt][nt][r];
                if (Dm) v += Dm[idx];
                ushort_t hb, lb;
                splitbf(v, hb, lb);
                if (Cf) Cf[idx] = v;
                if (Chi) { Chi[idx] = hb; Clo[idx] = lb; }
                if (mir) {
                    long idxT = base + (long)col * 256 + row;
                    if (Cf) Cf[idxT] = v;
                    if (Chi) { Chi[idxT] = hb; Clo[idxT] = lb; }
                }
                if (MJv) {
                    rowsum += v * mjc[nt];
                    if (mir) cvmir[nt] += v * mjrow;
                }
            }
            if (MJv) {
#pragma unroll
                for (int m = 1; m < 32; m <<= 1) rowsum += __shfl_xor(rowsum, m, 64);
                if (l31 == 0) atomicAdd(&CVat[(long)pair * 256 + row], rowsum);
            }
        }
    }
    if (MJv && mir) {
#pragma unroll
        for (int nt = 0; nt < 2; nt++)
            atomicAdd(&CVat[(long)pair * 256 + J0 + wx * 64 + nt * 32 + l31], cvmir[nt]);
    }
}

#define KTP 280
// K build: per (bt, pair): compute K tile (fp32 kv), write bf16 K to global, fold mu
__global__ __launch_bounds__(256) void k_kbuild(const float* __restrict__ ZS, const float* __restrict__ ZN,
                                                const float* __restrict__ XS, const float* __restrict__ XN,
                                                const float* __restrict__ SF2, const float* __restrict__ CV,
                                                ushort_t* __restrict__ Kg, float* __restrict__ out) {
    int bt = blockIdx.x;    // 16
    int pair = blockIdx.y;  // 128
    int h = pair >> 5;
    int t = threadIdx.x;
    int w = t >> 6;
    int b = t & 63;

    __shared__ __align__(16) ushort_t KbT[64][KTP];
    __shared__ float mup[4][64];

    float sf2 = SF2[h];
    long bg = (long)h * B_ + bt * 64 + b;
    const float4* xrow = (const float4*)(XS + bg * 16);
    float4 x0 = xrow[0], x1 = xrow[1], x2 = xrow[2], x3 = xrow[3];
    float xn = XN[bg];
    float mupart = 0.f;
    const float* cvp = CV + pair * 256;
    const float* znp = ZN + pair * 256;
#pragma unroll 2
    for (int j8 = 0; j8 < 8; j8++) {
        v8us kb8;
#pragma unroll
        for (int e = 0; e < 8; e++) {
            int j = w * 64 + j8 * 8 + e;
            const float4* zrow = (const float4*)(ZS + ((long)pair * 256 + j) * 16);
            float4 z0 = zrow[0], z1 = zrow[1], z2 = zrow[2], z3 = zrow[3];
            float dot = z0.x * x0.x + z0.y * x0.y + z0.z * x0.z + z0.w * x0.w +
                        z1.x * x1.x + z1.y * x1.y + z1.z * x1.z + z1.w * x1.w +
                        z2.x * x2.x + z2.y * x2.y + z2.z * x2.z + z2.w * x2.w +
                        z3.x * x3.x + z3.y * x3.y + z3.z * x3.z + z3.w * x3.w;
            float d2 = fmaxf(znp[j] + xn - 2.f * dot, 0.f);
            float kv = sf2 * __expf(-0.5f * d2);
            mupart += cvp[j] * kv;
            unsigned int u = __float_as_uint(kv);
            u += 0x7fffu + ((u >> 16) & 1u);
            kb8[e] = (unsigned short)(u >> 16);
        }
        *(v8us*)&KbT[b][w * 64 + j8 * 8] = kb8;
    }
    mup[w][b] = mupart;
    __syncthreads();
    long kbase = ((long)pair * 1024 + bt * 64) * 256;
#pragma unroll
    for (int e = 0; e < 8; e++) {
        int c = e * 256 + t;
        int bb = c >> 5, cj = (c & 31) * 8;
        *(v8us*)(Kg + kbase + (long)bb * 256 + cj) = *(const v8us*)&KbT[bb][cj];
    }
    if (t < 64) {
        float mu = mup[0][t] + mup[1][t] + mup[2][t] + mup[3][t];
        out[(long)pair * 1024 + bt * 64 + t] = mu;
    }
}

// MFMA q kernel, 128-wide b-tiles: 1D grid, pair = idx&127 (XCD L2 locality for G)
#define KT2 264
__global__ __launch_bounds__(256) void k_kb4(const ushort_t* __restrict__ Kg,
                                             const ushort_t* __restrict__ Ghi,
                                             const ushort_t* __restrict__ Glo,
                                             const float* __restrict__ SF2, float* __restrict__ out) {
    int pair = blockIdx.x & 127;
    int bt = blockIdx.x >> 7;  // 0..7
    int h = pair >> 5;
    int t = threadIdx.x;
    int w = t >> 6;
    int lane = t & 63;
    int l31 = lane & 31, lhalf = lane >> 5;

    __shared__ __align__(16) ushort_t KbT[128][KT2];
    __shared__ float qpart[4][128];

    float sf2 = SF2[h];
    long kbase = ((long)pair * 1024 + bt * 128) * 256;
#pragma unroll
    for (int e = 0; e < 16; e++) {
        int c = e * 256 + t;
        int bb = c >> 5, cj = (c & 31) * 8;
        *(v8us*)&KbT[bb][cj] = *(const v8us*)(Kg + kbase + (long)bb * 256 + cj);
    }
    __syncthreads();

    v16f acc[2][4];
#pragma unroll
    for (int mt = 0; mt < 2; mt++)
#pragma unroll
        for (int nt = 0; nt < 4; nt++)
#pragma unroll
            for (int r = 0; r < 16; r++) acc[mt][nt][r] = 0.f;

    const ushort_t* GhiP = Ghi + (long)pair * 65536;
    const ushort_t* GloP = Glo + (long)pair * 65536;
#pragma unroll 2
    for (int k0 = 0; k0 < 256; k0 += 16) {
        v8bf bfr[4];
#pragma unroll
        for (int nt = 0; nt < 4; nt++)
            bfr[nt] = *(const v8bf*)&KbT[nt * 32 + l31][k0 + lhalf * 8];
#pragma unroll
        for (int mt = 0; mt < 2; mt++) {
            int i = w * 64 + mt * 32 + l31;
            v8bf ah = *(const v8bf*)(GhiP + (long)i * 256 + k0 + lhalf * 8);
            v8bf al = *(const v8bf*)(GloP + (long)i * 256 + k0 + lhalf * 8);
#pragma unroll
            for (int nt = 0; nt < 4; nt++) {
                acc[mt][nt] = __builtin_amdgcn_mfma_f32_32x32x16_bf16(ah, bfr[nt], acc[mt][nt], 0, 0, 0);
                acc[mt][nt] = __builtin_amdgcn_mfma_f32_32x32x16_bf16(al, bfr[nt], acc[mt][nt], 0, 0, 0);
            }
        }
    }

    float qp[4] = {0.f, 0.f, 0.f, 0.f};
#pragma unroll
    for (int mt = 0; mt < 2; mt++) {
#pragma unroll
        for (int nt = 0; nt < 4; nt++) {
            int b = nt * 32 + l31;
#pragma unroll
            for (int g = 0; g < 4; g++) {
                int ibase = w * 64 + mt * 32 + 8 * g + 4 * lhalf;
                v4us k4 = *(const v4us*)&KbT[b][ibase];
#pragma unroll
                for (int e = 0; e < 4; e++) {
                    float kv = bf2f(k4[e]);
                    qp[nt] += kv * acc[mt][nt][4 * g + e];
                }
            }
        }
    }
#pragma unroll
    for (int nt = 0; nt < 4; nt++) {
        qp[nt] += __shfl_down(qp[nt], 32, 64);
        if (lhalf == 0) qpart[w][nt * 32 + l31] = qp[nt];
    }
    __syncthreads();

    if (t < 128) {
        float q = qpart[0][t] + qpart[1][t] + qpart[2][t] + qpart[3][t];
        out[(long)H_ * O_ * B_ + (long)pair * 1024 + bt * 128 + t] = sf2 - q;
    }
}

// ---------------------------------------------------------------------------
extern "C" void kernel_launch(void* const* d_in, const int* in_sizes, int n_in,
                              void* d_out, int out_size, void* d_ws, size_t ws_size,
                              hipStream_t stream) {
    const float* x = (const float*)d_in[0];
    const float* z = (const float*)d_in[1];
    const float* u_mean = (const float*)d_in[2];
    const float* u_tril_vec = (const float*)d_in[3];
    const float* m_old = (const float*)d_in[4];
    const float* L_old = (const float*)d_in[5];
    const float* z_old = (const float*)d_in[6];
    const float* theta = (const float*)d_in[7];

    const long BIGSZ = (long)HO * M2 * M2;  // 8388608
    const long MSZ = (long)HO * M_ * M_;    // 2097152
    const long SH1 = (long)O_ * M_ * M_;
    const long SO1 = (long)M_ * M_;
    const long SO2 = (long)M2 * M2;

    float* ws = (float*)d_ws;
    long off = 0;
    float* BIG0 = ws + off; off += BIGSZ;  // KUU2 -> T1/BLi -> AINV fp32
    float* BIG1 = ws + off; off += BIGSZ;  // LINVT h/l -> Y h/l -> Kg (part 1)
    float* BIG2 = ws + off; off += BIGSZ;  // Linv1|A1|Linv2|BLW -> AINV h/l -> Kg (part 2)
    float* BIG3 = ws + off; off += BIGSZ;  // WcT h/l -> G h/l
    float* ZS = ws + off; off += (long)HO * M2 * D_;
    float* XS = ws + off; off += (long)H_ * B_ * D_;
    float* ZN = ws + off; off += (long)HO * M2;
    float* XN = ws + off; off += (long)H_ * B_;
    float* MJ = ws + off; off += (long)HO * M2;
    float* CV = ws + off; off += (long)HO * M2;
    float* SF2v = ws + off; off += H_;

    float* KUU2 = BIG0;
    float* AINV = BIG0;
    float* Linv1 = BIG2;
    float* A1 = BIG2 + MSZ;
    float* A3 = BIG2 + 2 * MSZ;
    float* Linv2 = BIG2 + 2 * MSZ;
    float* BLW = BIG2 + 3 * MSZ;
    float* T1 = BIG0;                // over KUU2 TL (dead after choltri BR)
    float* BLi = BIG0 + MSZ;         // over KUU2 (dead) — NOT in BIG3 (k_split2 aliasing)
    ushort_t* LINVTh = (ushort_t*)BIG1;
    ushort_t* LINVTl = LINVTh + BIGSZ;
    ushort_t* AINVh = (ushort_t*)BIG2;
    ushort_t* AINVl = AINVh + BIGSZ;
    ushort_t* WcTh = (ushort_t*)BIG3;
    ushort_t* WcTl = WcTh + BIGSZ;
    ushort_t* Yh = (ushort_t*)BIG1;
    ushort_t* Yl = Yh + BIGSZ;
    ushort_t* Ghi = (ushort_t*)BIG3;
    ushort_t* Glo = Ghi + BIGSZ;
    ushort_t* Kg = (ushort_t*)BIG1;  // 64 MB spanning BIG1+BIG2 (both dead by then)
    const long BRoff = 128L * M2 + 128;

    // 1. preprocessing + kuu2 (fused)
    k_prekuu2<<<145, 256, 0, stream>>>(theta, x, z, z_old, SF2v, XS, XN, ZS, ZN, KUU2);
    // 2. chol TL + trinv -> Linv1 (fused, no L256 round trip)
    k_choltri<<<HO, 256, 0, stream>>>(KUU2, SO2, M2, Linv1);
    // 3. A1 = Linv1@kuf ; A3 = Linv1@L_old (merged)
    k_a1a3<<<dim3(HO, 2), 256, 0, stream>>>(Linv1, KUU2, L_old, A1, A3);
    // 4. m_joint
    k_stage1vec<<<HO, 128, 0, stream>>>(Linv1, A1, m_old, u_mean, MJ);
    // 5. BLW = A1^T A3 ; KUU2_BR -= A1^T A1 (merged)
    k_blwschur<<<dim3(HO, 2), 256, 0, stream>>>(A1, A3, BLW, KUU2);
    // 6. chol BR + trinv -> Linv2 (over A3 slot — dead)
    k_choltri<<<HO, 256, 0, stream>>>(KUU2 + BRoff, SO2, M2, Linv2);
    // 7. T1 = A1^T @ Linv1 (into BIG0 — KUU2 dead)
    k_bmm<1, 0><<<HO, 256, 0, stream>>>(A1, SH1, SO1, M_, Linv1, SH1, SO1, M_,
                                        T1, SH1, SO1, M_, M_, 1.f, 0);
    // 8. BLi = -Linv2 @ T1 (into BIG0+MSZ)
    k_bmm<0, 0><<<HO, 256, 0, stream>>>(Linv2, SH1, SO1, M_, T1, SH1, SO1, M_,
                                        BLi, SH1, SO1, M_, M_, -1.f, 0);
    // 9. LINVT + WcT planes (merged; BLi in BIG0, WcT in BIG3 — disjoint)
    k_split2<<<dim3(HO, 2), 256, 0, stream>>>(Linv1, BLi, Linv2, L_old, BLW, u_tril_vec,
                                              LINVTh, LINVTl, WcTh, WcTl);
    // 10. zero CV for fused matvec
    hipMemsetAsync(CV, 0, (long)HO * M2 * sizeof(float), stream);
    // 11. AINV = LINVT (.) LINVT -> fp32 (BIG0; T1/BLi dead) + planes (BIG2) + CV fused
    k_bmmx<1><<<dim3(HO, 3), 256, 0, stream>>>(LINVTh, LINVTl, LINVTh, LINVTl,
                                               AINV, AINVh, AINVl, nullptr, 1, 1.f, MJ, CV);
    // 12. Y = AINV @ Wc -> Y planes (BIG1; LINVT dead)
    k_bmmx<0><<<dim3(HO, 4), 256, 0, stream>>>(AINVh, AINVl, WcTh, WcTl,
                                               nullptr, Yh, Yl, nullptr, 2, 1.f, nullptr, nullptr);
    // 13. G = AINV - Y Y^T -> G planes (BIG3; WcT dead)
    k_bmmx<1><<<dim3(HO, 3), 256, 0, stream>>>(Yh, Yl, Yh, Yl,
                                               nullptr, Ghi, Glo, AINV, 0, -1.f, nullptr, nullptr);
    // 14. K build + mu (Kg over BIG1+BIG2 — Y and AINV planes dead)
    k_kbuild<<<dim3(16, HO), 256, 0, stream>>>(ZS, ZN, XS, XN, SF2v, CV, Kg, (float*)d_out);
    // 15. MFMA q/var, 128-wide b-tiles
    k_kb4<<<1024, 256, 0, stream>>>(Kg, Ghi, Glo, SF2v, (float*)d_out);
}